// Round 16
// baseline (323.100 us; speedup 1.0000x reference)
//
#include <hip/hip_runtime.h>
#include <stdint.h>
#include <math.h>

typedef float f32x4 __attribute__((ext_vector_type(4)));
typedef short s16x8 __attribute__((ext_vector_type(8)));
typedef unsigned short bfu;

#define AS1q const __attribute__((address_space(1))) void*
#define AS3q __attribute__((address_space(3))) void*

static __device__ __forceinline__ float bf2f(bfu v) {
  return __uint_as_float(((unsigned int)v) << 16);
}
static __device__ __forceinline__ bfu f2bf(float f) {
  unsigned int u = __float_as_uint(f);
  return (bfu)((u + 0x7fffu + ((u >> 16) & 1u)) >> 16);
}

// ================= fused prologue: all weight converts + rope tables + rmsnorm =================
struct PreArgs {
  const float* w5[5];
  const float* Wffin;
  const float* Wffout;
  const float* Wo;
  const float* h;
  bfu* wt5; bfu* wtfi; bfu* wtfoc;
  bfu* cosb; bfu* sinb; bfu* inner;
};
__global__ __launch_bounds__(256) void prologue_k(PreArgs a) {
  __shared__ float shmem[32 * 33];
  int id = blockIdx.x;
  if (id < 18432) {
    const float* W; bfu* Wt; int K, N, dstride, dofs, mode, nb, kb;
    if (id < 5120) {
      int z = id >> 10, rem = id & 1023;
      W = a.w5[z]; Wt = a.wt5 + ((size_t)z << 20);
      K = 1024; N = 1024; dstride = 1024; dofs = 0; mode = 0;
      nb = (rem & 31) << 5; kb = (rem >> 5) << 5;
    } else if (id < 13312) {
      int id2 = id - 5120;
      W = a.Wffin; Wt = a.wtfi; K = 1024; N = 8192; dstride = 1024; dofs = 0; mode = 1;
      nb = (id2 & 255) << 5; kb = (id2 >> 8) << 5;
    } else if (id < 17408) {
      int id3 = id - 13312;
      W = a.Wffout; Wt = a.wtfoc; K = 4096; N = 1024; dstride = 5120; dofs = 0; mode = 2;
      nb = (id3 & 31) << 5; kb = (id3 >> 5) << 5;
    } else {
      int id4 = id - 17408;
      W = a.Wo; Wt = a.wtfoc; K = 1024; N = 1024; dstride = 5120; dofs = 4096; mode = 2;
      nb = (id4 & 31) << 5; kb = (id4 >> 5) << 5;
    }
    float (*t)[33] = reinterpret_cast<float(*)[33]>(shmem);
    int tx = threadIdx.x & 31, ty = threadIdx.x >> 5;
#pragma unroll
    for (int i = 0; i < 4; i++) {
      int r = ty + i * 8;
      t[r][tx] = W[(size_t)(kb + r) * N + nb + tx];
    }
    __syncthreads();
#pragma unroll
    for (int i = 0; i < 4; i++) {
      int r = ty + i * 8;
      int n = nb + r;
      int nd = n;
      if (mode == 1) { int j = n & 4095, isg = n >> 12; nd = ((j >> 4) << 5) | (isg << 4) | (j & 15); }
      int k = kb + tx;
      int kp = (mode == 2) ? (((k >> 5) << 5) | ((k & 15) << 1) | ((k >> 4) & 1)) : k;
      Wt[(size_t)nd * dstride + dofs + kp] = f2bf(t[tx][r]);
    }
  } else if (id < 18560) {
    int idx = (id - 18432) * 256 + threadIdx.x;
    int s = idx >> 5, i = idx & 31;
    float f = powf(1000.0f, -(float)i / 32.0f);
    float fr = (float)s * f;
    a.cosb[idx] = f2bf(cosf(fr));
    a.sinb[idx] = f2bf(sinf(fr));
  } else {
    int row = id - 18560;
    const float* hr = a.h + (size_t)row * 1024;
    f32x4 x = *reinterpret_cast<const f32x4*>(hr + threadIdx.x * 4);
    float ss = x[0] * x[0] + x[1] * x[1] + x[2] * x[2] + x[3] * x[3];
    for (int off = 32; off; off >>= 1) ss += __shfl_down(ss, off);
    int wave = threadIdx.x >> 6, lane = threadIdx.x & 63;
    if (lane == 0) shmem[wave] = ss;
    __syncthreads();
    float tot = shmem[0] + shmem[1] + shmem[2] + shmem[3];
    float r = rsqrtf(tot * (1.0f / 1024.0f) + 1.1920929e-07f);
    bfu* o = a.inner + (size_t)row * 1024 + threadIdx.x * 4;
    o[0] = f2bf(x[0] * r); o[1] = f2bf(x[1] * r);
    o[2] = f2bf(x[2] * r); o[3] = f2bf(x[3] * r);
  }
}

// ============ 8-phase 256x256 GEMM, BK=64, 2-dbuf LDS, counted vmcnt (R8 order, FF-in) ============
template <int EPI>
__global__ __launch_bounds__(512, 2) void gemm256p(const bfu* __restrict__ A, const bfu* __restrict__ Bt,
                                                   bfu* __restrict__ outB,
                                                   const float* __restrict__ bias,
                                                   int M, int N, int K, int rbm, int rbn) {
  __shared__ __align__(16) char lds[131072];
  int nbx = N >> 8;
  int c = blockIdx.x & 7, rr = blockIdx.x >> 3;
  int ca = nbx / rbn;
  int bn0 = (c % ca) * rbn, bm0 = (c / ca) * rbm;
  int bm = bm0 + rr / rbn, bn = bn0 + rr % rbn;
  int tid = threadIdx.x, w = tid >> 6, lane = tid & 63;
  int wm = w >> 2, wn = w & 3;
  int g = lane >> 4, l15 = lane & 15;
  int NT = K >> 6;
  int NI = NT >> 1;

  f32x4 acc[8][4];
#pragma unroll
  for (int m = 0; m < 8; m++)
#pragma unroll
    for (int n = 0; n < 4; n++) acc[m][n] = (f32x4){0.f, 0.f, 0.f, 0.f};

  s16x8 af[4][2];
  s16x8 bfr[4][2];

  auto stage = [&](int mat, int kt, int hf) {
    if (kt >= NT) return;
    int d = kt & 1;
    const bfu* s0 = (mat == 0) ? A : Bt;
    int rowbase = ((mat == 0) ? bm : bn) * 256 + hf * 128;
    int k0 = kt << 6;
    char* base = lds + d * 65536 + mat * 32768 + hf * 16384;
#pragma unroll
    for (int r = 0; r < 2; r++) {
      int L = r * 512 + tid;
      int row = L >> 3, cc = L & 7;
      int kc = cc ^ (row & 7);
      const bfu* src = s0 + (size_t)(rowbase + row) * K + k0 + kc * 8;
      char* dst = base + r * 8192 + w * 1024;
      __builtin_amdgcn_global_load_lds((AS1q)src, (AS3q)dst, 16, 0, 0);
    }
  };

  auto ldA = [&](int d, int mh) {
    const char* base = lds + d * 65536 + wm * 16384;
#pragma unroll
    for (int mm = 0; mm < 4; mm++) {
      int row = mh * 64 + mm * 16 + l15;
#pragma unroll
      for (int ks = 0; ks < 2; ks++)
        af[mm][ks] = *reinterpret_cast<const s16x8*>(
            base + row * 128 + (((ks * 4 + g) ^ (row & 7)) << 4));
    }
  };
  auto ldB2 = [&](int d, int nh) {
    const char* base = lds + d * 65536 + 32768 + (wn >> 1) * 16384;
#pragma unroll
    for (int nn = 0; nn < 2; nn++) {
      int row = (wn & 1) * 64 + (nh * 2 + nn) * 16 + l15;
#pragma unroll
      for (int ks = 0; ks < 2; ks++)
        bfr[nh * 2 + nn][ks] = *reinterpret_cast<const s16x8*>(
            base + row * 128 + (((ks * 4 + g) ^ (row & 7)) << 4));
    }
  };
  auto mfma_q = [&](int mh, int nh) {
    asm volatile("s_waitcnt lgkmcnt(0)" ::: "memory");
    __builtin_amdgcn_sched_barrier(0);
    __builtin_amdgcn_s_barrier();
    __builtin_amdgcn_s_setprio(1);
#pragma unroll
    for (int mm = 0; mm < 4; mm++)
#pragma unroll
      for (int nn = 0; nn < 2; nn++) {
        int n = nh * 2 + nn, m = mh * 4 + mm;
#pragma unroll
        for (int ks = 0; ks < 2; ks++)
          acc[m][n] = __builtin_amdgcn_mfma_f32_16x16x32_bf16(af[mm][ks], bfr[n][ks], acc[m][n], 0, 0, 0);
      }
    __builtin_amdgcn_s_setprio(0);
    __builtin_amdgcn_sched_barrier(0);
  };

  stage(1, 0, 0); stage(0, 0, 0); stage(0, 0, 1); stage(1, 0, 1);
  stage(1, 1, 0); stage(1, 1, 1);
  asm volatile("s_waitcnt vmcnt(4)" ::: "memory");
  __builtin_amdgcn_s_barrier();
  __builtin_amdgcn_sched_barrier(0);

  for (int i = 0; i < NI; i++) {
    int t0 = 2 * i, t1 = 2 * i + 1;
    bool last = (i == NI - 1);
    ldA(0, 0); ldB2(0, 0);
    stage(0, t1, 0);
    mfma_q(0, 0);
    ldB2(0, 1);
    stage(0, t1, 1);
    mfma_q(0, 1);
    ldA(0, 1);
    stage(1, t0 + 2, 0);
    mfma_q(1, 0);
    stage(1, t0 + 2, 1);
    mfma_q(1, 1);
    if (last) { asm volatile("s_waitcnt vmcnt(0)" ::: "memory"); }
    else      { asm volatile("s_waitcnt vmcnt(4)" ::: "memory"); }
    __builtin_amdgcn_s_barrier();
    __builtin_amdgcn_sched_barrier(0);
    ldA(1, 0); ldB2(1, 0);
    stage(0, t0 + 2, 0);
    mfma_q(0, 0);
    ldB2(1, 1);
    stage(0, t0 + 2, 1);
    mfma_q(0, 1);
    ldA(1, 1);
    stage(1, t1 + 2, 0);
    mfma_q(1, 0);
    stage(1, t1 + 2, 1);
    mfma_q(1, 1);
    asm volatile("s_waitcnt vmcnt(4)" ::: "memory");
    __builtin_amdgcn_s_barrier();
    __builtin_amdgcn_sched_barrier(0);
  }

  // epilogue (FF-in silu fused, packed)
  int j0 = (bn * 8 + wn * 2) * 16 + l15;
  float bx0 = bias[j0], bg0 = bias[j0 + 4096];
  float bx1 = bias[j0 + 16], bg1 = bias[j0 + 16 + 4096];
  int cb = (bn * 4 + wn) * 32 + 2 * l15;
#pragma unroll
  for (int m = 0; m < 8; m++) {
#pragma unroll
    for (int r = 0; r < 4; r++) {
      int row = bm * 256 + wm * 128 + m * 16 + g * 4 + r;
      float xh0 = acc[m][0][r] + bx0, gt0 = acc[m][1][r] + bg0;
      float xh1 = acc[m][2][r] + bx1, gt1 = acc[m][3][r] + bg1;
      float s0 = gt0 / (1.0f + __expf(-gt0)) * xh0;
      float s1 = gt1 / (1.0f + __expf(-gt1)) * xh1;
      unsigned int pk = (unsigned int)f2bf(s0) | ((unsigned int)f2bf(s1) << 16);
      *reinterpret_cast<unsigned int*>(outB + (size_t)row * 5120 + cb) = pk;
    }
  }
}

// ============ 128x128 GEMM, BK=32, 3-stage pipeline, 4 waves, 3 blocks/CU (proj) ============
// v (which==2) is transposed in-LDS and written directly to vT [bh][d][s]
__global__ __launch_bounds__(256, 3) void gemm128p(const bfu* __restrict__ A, const bfu* __restrict__ Bt,
                                                   bfu* __restrict__ qb, bfu* __restrict__ kb,
                                                   bfu* __restrict__ vT,
                                                   bfu* __restrict__ bqh, bfu* __restrict__ bkh,
                                                   const bfu* __restrict__ ct, const bfu* __restrict__ st,
                                                   int M, int N, int K, int rbm, int rbn) {
  __shared__ __align__(16) char lds[49152];
  int nbx = N >> 7;
  int c = blockIdx.x & 7, rr = blockIdx.x >> 3;
  int ca = nbx / rbn;
  int bn0 = (c % ca) * rbn, bm0 = (c / ca) * rbm;
  int bm = bm0 + rr / rbn, bn = bn0 + rr % rbn;
  int tid = threadIdx.x, w = tid >> 6, lane = tid & 63;
  int wm = w >> 1, wn = w & 1;
  int g = lane >> 4, l15 = lane & 15;
  int NT = K >> 5;

  f32x4 acc[4][4];
#pragma unroll
  for (int m = 0; m < 4; m++)
#pragma unroll
    for (int n = 0; n < 4; n++) acc[m][n] = (f32x4){0.f, 0.f, 0.f, 0.f};

  auto stage = [&](int buf, int t) {
    int k0 = t << 5;
#pragma unroll
    for (int r = 0; r < 2; r++) {
      int L = r * 256 + tid;
      int row = L >> 2, cc = L & 3;
      int kc = cc ^ (row & 3);
      const bfu* srcA = A + (size_t)(bm * 128 + row) * K + k0 + kc * 8;
      char* dstA = lds + buf * 16384 + r * 4096 + w * 1024;
      __builtin_amdgcn_global_load_lds((AS1q)srcA, (AS3q)dstA, 16, 0, 0);
      const bfu* srcB = Bt + (size_t)(bn * 128 + row) * K + k0 + kc * 8;
      char* dstB = lds + buf * 16384 + 8192 + r * 4096 + w * 1024;
      __builtin_amdgcn_global_load_lds((AS1q)srcB, (AS3q)dstB, 16, 0, 0);
    }
  };

  stage(0, 0); stage(1, 1);
  asm volatile("s_waitcnt vmcnt(4)" ::: "memory");
  __builtin_amdgcn_s_barrier();
  __builtin_amdgcn_sched_barrier(0);

  int bc = 0;
  for (int t = 0; t < NT; t++) {
    int bs = bc + 2; if (bs >= 3) bs -= 3;
    if (t + 2 < NT) stage(bs, t + 2);
    const char* la = lds + bc * 16384;
    const char* lb = la + 8192;
    s16x8 af[4], bfr[4];
#pragma unroll
    for (int m = 0; m < 4; m++) {
      int row = wm * 64 + m * 16 + l15;
      af[m] = *reinterpret_cast<const s16x8*>(la + row * 64 + ((g ^ (row & 3)) << 4));
    }
#pragma unroll
    for (int n = 0; n < 4; n++) {
      int row = wn * 64 + n * 16 + l15;
      bfr[n] = *reinterpret_cast<const s16x8*>(lb + row * 64 + ((g ^ (row & 3)) << 4));
    }
    asm volatile("s_waitcnt lgkmcnt(0)" ::: "memory");
    __builtin_amdgcn_sched_barrier(0);
    __builtin_amdgcn_s_setprio(1);
#pragma unroll
    for (int m = 0; m < 4; m++)
#pragma unroll
      for (int n = 0; n < 4; n++)
        acc[m][n] = __builtin_amdgcn_mfma_f32_16x16x32_bf16(af[m], bfr[n], acc[m][n], 0, 0, 0);
    __builtin_amdgcn_s_setprio(0);
    __builtin_amdgcn_sched_barrier(0);
    if (t < NT - 2) { asm volatile("s_waitcnt vmcnt(4)" ::: "memory"); }
    else            { asm volatile("s_waitcnt vmcnt(0)" ::: "memory"); }
    __builtin_amdgcn_s_barrier();
    __builtin_amdgcn_sched_barrier(0);
    bc++; if (bc == 3) bc = 0;
  }

  int which = bn >> 3;               // 0 q | 1 k | 2 v | 3 bq | 4 bk
  int hh = (bn & 7) * 2 + wn;
  if (which == 2) {
    bfu* lv = reinterpret_cast<bfu*>(lds);
#pragma unroll
    for (int m = 0; m < 4; m++) {
#pragma unroll
      for (int r = 0; r < 4; r++) {
        int sl = wm * 64 + m * 16 + g * 4 + r;
#pragma unroll
        for (int j = 0; j < 4; j++) {
          int d = j * 16 + l15;
          lv[(wn * 64 + d) * 136 + sl] = f2bf(acc[m][j][r]);
        }
      }
    }
    __syncthreads();
    int b = bm >> 3, h0 = (bn & 7) * 2;
#pragma unroll
    for (int i = 0; i < 8; i++) {
      int linear = i * 256 + tid;
      int hw = linear >> 10, rem = linear & 1023;
      int d = rem >> 4, sl8 = (rem & 15) << 3;
      s16x8 v8 = *reinterpret_cast<const s16x8*>(&lv[(hw * 64 + d) * 136 + sl8]);
      size_t dstofs = (((size_t)((b << 4) + h0 + hw) << 6) + d) * 1024 + (bm & 7) * 128 + sl8;
      *reinterpret_cast<s16x8*>(vT + dstofs) = v8;
    }
  } else {
#pragma unroll
    for (int m = 0; m < 4; m++) {
#pragma unroll
      for (int r = 0; r < 4; r++) {
        int row = bm * 128 + wm * 64 + m * 16 + g * 4 + r;
        int s = row & 1023, b = row >> 10;
        float a0 = acc[m][0][r], a1 = acc[m][1][r];
        float a2 = acc[m][2][r], a3 = acc[m][3][r];
        float ss = a0 * a0 + a1 * a1 + a2 * a2 + a3 * a3;
        ss += __shfl_xor(ss, 1); ss += __shfl_xor(ss, 2);
        ss += __shfl_xor(ss, 4); ss += __shfl_xor(ss, 8);
        float inv = 1.0f / fmaxf(sqrtf(ss), 1e-12f);
        float xn0 = a0 * inv, xn1 = a1 * inv, xn2 = a2 * inv, xn3 = a3 * inv;
        float c0 = bf2f(ct[(s << 5) + l15]),      s0v = bf2f(st[(s << 5) + l15]);
        float c1 = bf2f(ct[(s << 5) + 16 + l15]), s1v = bf2f(st[(s << 5) + 16 + l15]);
        float o0 = xn0 * c0 + xn2 * s0v;
        float o1 = xn1 * c1 + xn3 * s1v;
        float o2 = xn2 * c0 - xn0 * s0v;
        float o3 = xn3 * c1 - xn1 * s1v;
        unsigned long long pk =
            (unsigned long long)((unsigned int)f2bf(o0) | ((unsigned int)f2bf(o1) << 16)) |
            ((unsigned long long)((unsigned int)f2bf(o2) | ((unsigned int)f2bf(o3) << 16)) << 32);
        size_t base = ((((size_t)((b << 4) + hh) << 10) + s) << 6) + (l15 << 2);
        bfu* dst = (which == 0) ? qb : (which == 1) ? kb : (which == 3) ? bqh : bkh;
        *reinterpret_cast<unsigned long long*>(dst + base) = pk;
      }
    }
  }
}

// ============ final GEMM: 128x128 tile, BK=64, 4-stage pipeline (prefetch 3 ahead) ============
// 1 block/CU (grid 256); deeper ILP is the only latency-hiding lever here.
// RAW: boundary vmcnt(16) leaves tiles t+2,t+3 in flight -> tile t+1 resident.
// WAR: stage(t+3) overwrites buf (t-1)&3, whose ds_reads completed before prev barrier.
__global__ __launch_bounds__(256, 2) void gemm128f(const bfu* __restrict__ A, const bfu* __restrict__ Bt,
                                                   float* __restrict__ out,
                                                   const float* __restrict__ b1,
                                                   const float* __restrict__ b2,
                                                   const float* __restrict__ lam,
                                                   const float* __restrict__ h,
                                                   int M, int N, int K, int rbm, int rbn) {
  __shared__ __align__(16) char lds[131072];  // 4 x (A 16KB | B 16KB)
  int nbx = N >> 7;
  int c = blockIdx.x & 7, rr = blockIdx.x >> 3;
  int ca = nbx / rbn;
  int bn0 = (c % ca) * rbn, bm0 = (c / ca) * rbm;
  int bm = bm0 + rr / rbn, bn = bn0 + rr % rbn;
  int tid = threadIdx.x, w = tid >> 6, lane = tid & 63;
  int wm = w >> 1, wn = w & 1;
  int g = lane >> 4, l15 = lane & 15;
  int NT = K >> 6;   // BK=64 -> 80 iters

  f32x4 acc[4][4];
#pragma unroll
  for (int m = 0; m < 4; m++)
#pragma unroll
    for (int n = 0; n < 4; n++) acc[m][n] = (f32x4){0.f, 0.f, 0.f, 0.f};

  auto stage = [&](int buf, int t) {
    if (t >= NT) return;
    int k0 = t << 6;
#pragma unroll
    for (int r = 0; r < 4; r++) {
      int L = r * 256 + tid;
      int row = L >> 3, cc = L & 7;
      int kc = cc ^ (row & 7);
      const bfu* srcA = A + (size_t)(bm * 128 + row) * K + k0 + kc * 8;
      char* dstA = lds + buf * 32768 + r * 4096 + w * 1024;
      __builtin_amdgcn_global_load_lds((AS1q)srcA, (AS3q)dstA, 16, 0, 0);
    }
#pragma unroll
    for (int r = 0; r < 4; r++) {
      int L = r * 256 + tid;
      int row = L >> 3, cc = L & 7;
      int kc = cc ^ (row & 7);
      const bfu* srcB = Bt + (size_t)(bn * 128 + row) * K + k0 + kc * 8;
      char* dstB = lds + buf * 32768 + 16384 + r * 4096 + w * 1024;
      __builtin_amdgcn_global_load_lds((AS1q)srcB, (AS3q)dstB, 16, 0, 0);
    }
  };

  // prologue: tiles 0,1,2 staged (24 loads); wait tile0 -> vmcnt(16)
  stage(0, 0); stage(1, 1); stage(2, 2);
  asm volatile("s_waitcnt vmcnt(16)" ::: "memory");
  __builtin_amdgcn_s_barrier();
  __builtin_amdgcn_sched_barrier(0);

  for (int t = 0; t < NT; t++) {
    int bc = t & 3;
    stage((t + 3) & 3, t + 3);
    const char* la = lds + bc * 32768;
    const char* lb = la + 16384;
    s16x8 af[4][2], bfr[4][2];
#pragma unroll
    for (int m = 0; m < 4; m++) {
      int row = wm * 64 + m * 16 + l15;
#pragma unroll
      for (int ks = 0; ks < 2; ks++)
        af[m][ks] = *reinterpret_cast<const s16x8*>(
            la + row * 128 + (((ks * 4 + g) ^ (row & 7)) << 4));
    }
#pragma unroll
    for (int n = 0; n < 4; n++) {
      int row = wn * 64 + n * 16 + l15;
#pragma unroll
      for (int ks = 0; ks < 2; ks++)
        bfr[n][ks] = *reinterpret_cast<const s16x8*>(
            lb + row * 128 + (((ks * 4 + g) ^ (row & 7)) << 4));
    }
    asm volatile("s_waitcnt lgkmcnt(0)" ::: "memory");
    __builtin_amdgcn_sched_barrier(0);
    __builtin_amdgcn_s_setprio(1);
#pragma unroll
    for (int m = 0; m < 4; m++)
#pragma unroll
      for (int n = 0; n < 4; n++)
#pragma unroll
        for (int ks = 0; ks < 2; ks++)
          acc[m][n] = __builtin_amdgcn_mfma_f32_16x16x32_bf16(af[m][ks], bfr[n][ks], acc[m][n], 0, 0, 0);
    __builtin_amdgcn_s_setprio(0);
    __builtin_amdgcn_sched_barrier(0);
    if (t < NT - 3)       { asm volatile("s_waitcnt vmcnt(16)" ::: "memory"); }
    else if (t == NT - 3) { asm volatile("s_waitcnt vmcnt(8)"  ::: "memory"); }
    else                  { asm volatile("s_waitcnt vmcnt(0)"  ::: "memory"); }
    __builtin_amdgcn_s_barrier();
    __builtin_amdgcn_sched_barrier(0);
  }

  float lv = lam[0];
#pragma unroll
  for (int m = 0; m < 4; m++) {
    int row = bm * 128 + wm * 64 + m * 16 + g * 4;
#pragma unroll
    for (int n = 0; n < 4; n++) {
      int col = bn * 128 + wn * 64 + n * 16 + l15;
      float bb = b1[col] + b2[col];
#pragma unroll
      for (int r = 0; r < 4; r++) {
        size_t o = (size_t)(row + r) * 1024 + col;
        out[o] = acc[m][n][r] + bb + lv * h[o];
      }
    }
  }
}

// ---------------- fused brow ----------------
__global__ __launch_bounds__(512) void brow_all(const bfu* __restrict__ bq, const bfu* __restrict__ bk,
                                                float* __restrict__ brow) {
  __shared__ float csums[8][64];
  int bh = blockIdx.x;
  int wave = threadIdx.x >> 6, lane = threadIdx.x & 63;
  size_t base = ((size_t)bh * 1024 + wave * 128) * 64 + lane;
  float s = 0.f;
  for (int j = 0; j < 128; j++) s += bf2f(bk[base + (size_t)j * 64]);
  csums[wave][lane] = s;
  __syncthreads();
  float p = 0.f;
  for (int cc = 0; cc < wave; cc++) p += csums[cc][lane];
  for (int j = 0; j < 128; j++) {
    p += bf2f(bk[base + (size_t)j * 64]);
    float t = bf2f(bq[base + (size_t)j * 64]) * p;
#pragma unroll
    for (int m2 = 1; m2 < 64; m2 <<= 1) t += __shfl_xor(t, m2);
    if (lane == 0) brow[bh * 1024 + wave * 128 + j] = 0.125f * t;
  }
}

// ---------------- flash attention: QBLK=128/block, 2 m-tiles/wave (R13-proven) ----------------
__global__ __launch_bounds__(256) void flash_k(const bfu* __restrict__ q, const bfu* __restrict__ k,
                                               const bfu* __restrict__ vT,
                                               const float* __restrict__ brow,
                                               const float* __restrict__ l2p,
                                               bfu* __restrict__ y) {
  __shared__ __align__(16) bfu P[4][2][16][72];
  int id = blockIdx.x;  // 0..511
  int sub = id & 255;
  int qt = (id >> 8) ? 7 - (sub >> 6) : (sub >> 6);
  int bh = sub & 63;
  int wave = threadIdx.x >> 6, lane = threadIdx.x & 63;
  int g = lane >> 4, l15 = lane & 15;
  const size_t bhofs = (size_t)bh << 16;
  int rt0 = qt * 128 + wave * 32;

  s16x8 aq[2][2];
#pragma unroll
  for (int m = 0; m < 2; m++)
#pragma unroll
    for (int ks = 0; ks < 2; ks++)
      aq[m][ks] = *reinterpret_cast<const s16x8*>(
          q + bhofs + (size_t)(rt0 + m * 16 + l15) * 64 + ks * 32 + g * 8);

  f32x4 O[2][4];
  float mr[2][4], lr[2][4];
#pragma unroll
  for (int m = 0; m < 2; m++)
#pragma unroll
    for (int r = 0; r < 4; r++) { O[m][r] = (f32x4){0.f, 0.f, 0.f, 0.f}; mr[m][r] = -3.0e38f; lr[m][r] = 0.f; }

  s16x8 kA[4][2], kB[4][2];
  auto loadK = [&](s16x8 (&kd)[4][2], int jt) {
#pragma unroll
    for (int nt = 0; nt < 4; nt++)
#pragma unroll
      for (int ks = 0; ks < 2; ks++)
        kd[nt][ks] = *reinterpret_cast<const s16x8*>(
            k + bhofs + (size_t)(jt * 64 + nt * 16 + l15) * 64 + ks * 32 + g * 8);
  };

  int njt = 2 * qt + 2;
  loadK(kA, 0);

  auto body = [&](int jt, s16x8 (&kc)[4][2], s16x8 (&kn)[4][2], bool pf) {
    s16x8 vv[4][2];
#pragma unroll
    for (int nt = 0; nt < 4; nt++)
#pragma unroll
      for (int ks = 0; ks < 2; ks++)
        vv[nt][ks] = *reinterpret_cast<const s16x8*>(
            vT + ((size_t)(bh * 64 + nt * 16 + l15) << 10) + jt * 64 + ks * 32 + g * 8);

    bool act[2] = { jt * 64 <= rt0 + 15, jt * 64 <= rt0 + 31 };
    f32x4 sfr[2][4];
#pragma unroll
    for (int m = 0; m < 2; m++) {
      if (!act[m]) continue;
#pragma unroll
      for (int nt = 0; nt < 4; nt++) {
        sfr[m][nt] = (f32x4){0.f, 0.f, 0.f, 0.f};
#pragma unroll
        for (int ks = 0; ks < 2; ks++)
          sfr[m][nt] = __builtin_amdgcn_mfma_f32_16x16x32_bf16(aq[m][ks], kc[nt][ks], sfr[m][nt], 0, 0, 0);
      }
    }
    if (pf) loadK(kn, jt + 1);

#pragma unroll
    for (int m = 0; m < 2; m++) {
      if (!act[m]) continue;
      int rtm = rt0 + m * 16;
      if (jt * 64 + 63 > rtm) {
#pragma unroll
        for (int ntn = 0; ntn < 4; ntn++)
#pragma unroll
          for (int r = 0; r < 4; r++)
            if (jt * 64 + ntn * 16 + l15 > rtm + g * 4 + r) sfr[m][ntn][r] = -1e30f;
      }
      float alpha[4];
#pragma unroll
      for (int r = 0; r < 4; r++) {
        float v = fmaxf(fmaxf(sfr[m][0][r], sfr[m][1][r]), fmaxf(sfr[m][2][r], sfr[m][3][r]));
#pragma unroll
        for (int m2 = 1; m2 < 16; m2 <<= 1) v = fmaxf(v, __shfl_xor(v, m2));
        float mn = fmaxf(mr[m][r], v);
        alpha[r] = __expf(mr[m][r] - mn);
        mr[m][r] = mn;
      }
#pragma unroll
      for (int r = 0; r < 4; r++) {
        float rs = 0.f;
#pragma unroll
        for (int ntn = 0; ntn < 4; ntn++) {
          float e = __expf(sfr[m][ntn][r] - mr[m][r]);
          rs += e;
          P[wave][m][g * 4 + r][ntn * 16 + l15] = f2bf(e);
        }
#pragma unroll
        for (int m2 = 1; m2 < 16; m2 <<= 1) rs += __shfl_xor(rs, m2);
        lr[m][r] = lr[m][r] * alpha[r] + rs;
#pragma unroll
        for (int ntn = 0; ntn < 4; ntn++) O[m][ntn][r] *= alpha[r];
      }
    }
    asm volatile("s_waitcnt lgkmcnt(0)" ::: "memory");
    __builtin_amdgcn_sched_barrier(0);
#pragma unroll
    for (int m = 0; m < 2; m++) {
      if (!act[m]) continue;
      s16x8 pa[2];
#pragma unroll
      for (int ks = 0; ks < 2; ks++)
        pa[ks] = *reinterpret_cast<const s16x8*>(&P[wave][m][l15][ks * 32 + g * 8]);
#pragma unroll
      for (int nt = 0; nt < 4; nt++)
#pragma unroll
        for (int ks = 0; ks < 2; ks++)
          O[m][nt] = __builtin_amdgcn_mfma_f32_16x16x32_bf16(pa[ks], vv[nt][ks], O[m][nt], 0, 0, 0);
    }
  };

  for (int jt = 0; jt < njt; jt += 2) {
    body(jt, kA, kB, true);
    body(jt + 1, kB, kA, jt + 2 < njt);
  }

  float l2ns = l2p[0];
  int b = bh >> 4, hq = bh & 15;
#pragma unroll
  for (int m = 0; m < 2; m++)
#pragma unroll
    for (int r = 0; r < 4; r++) {
      int rowg = rt0 + m * 16 + g * 4 + r;
      float br = brow[bh * 1024 + rowg];
      float sc = l2ns / lr[m][r];
      float v0 = O[m][0][r] * sc + br;
      float v1 = O[m][1][r] * sc + br;
      float v2 = O[m][2][r] * sc + br;
      float v3 = O[m][3][r] * sc + br;
      unsigned int p01 = (unsigned int)f2bf(v0) | ((unsigned int)f2bf(v1) << 16);
      unsigned int p23 = (unsigned int)f2bf(v2) | ((unsigned int)f2bf(v3) << 16);
      size_t base = (size_t)(b * 1024 + rowg) * 5120 + 4096 + hq * 64;
      *reinterpret_cast<unsigned int*>(y + base + 2 * l15) = p01;
      *reinterpret_cast<unsigned int*>(y + base + 32 + 2 * l15) = p23;
    }
}

// ================= host =================
extern "C" void kernel_launch(void* const* d_in, const int* in_sizes, int n_in,
                              void* d_out, int out_size, void* d_ws, size_t ws_size,
                              hipStream_t stream) {
  const float* h      = (const float*)d_in[0];
  const float* Wq     = (const float*)d_in[2];
  const float* Wk     = (const float*)d_in[3];
  const float* Wv     = (const float*)d_in[4];
  const float* WqB    = (const float*)d_in[5];
  const float* WkB    = (const float*)d_in[6];
  const float* Wo     = (const float*)d_in[7];
  const float* bo     = (const float*)d_in[8];
  const float* Wffin  = (const float*)d_in[9];
  const float* bffin  = (const float*)d_in[10];
  const float* Wffout = (const float*)d_in[11];
  const float* bffout = (const float*)d_in[12];
  const float* lam    = (const float*)d_in[13];
  const float* l2ns   = (const float*)d_in[14];
  float* out = (float*)d_out;

  char* ws = (char*)d_ws;
  size_t off = 0;
  auto alloc = [&](size_t bytes) { void* p = ws + off; off += bytes; return p; };
  bfu* wt5   = (bfu*)alloc(5ull * 1024 * 1024 * 2);
  bfu* wtfi  = (bfu*)alloc(8192ull * 1024 * 2);
  bfu* wtfoc = (bfu*)alloc(1024ull * 5120 * 2);
  bfu* cosb  = (bfu*)alloc(1024ull * 32 * 2);
  bfu* sinb  = (bfu*)alloc(1024ull * 32 * 2);
  bfu* inner = (bfu*)alloc(4096ull * 1024 * 2);
  bfu* qb    = (bfu*)alloc(64ull * 1024 * 64 * 2);
  bfu* kb    = (bfu*)alloc(64ull * 1024 * 64 * 2);
  bfu* vtb   = (bfu*)alloc(64ull * 1024 * 64 * 2);
  bfu* bqh   = (bfu*)alloc(64ull * 1024 * 64 * 2);
  bfu* bkh   = (bfu*)alloc(64ull * 1024 * 64 * 2);
  float* browb = (float*)alloc(64ull * 1024 * 4);
  bfu* AB    = (bfu*)alloc(4096ull * 5120 * 2);

  // fused prologue
  PreArgs pa;
  pa.w5[0] = Wq; pa.w5[1] = Wk; pa.w5[2] = Wv; pa.w5[3] = WqB; pa.w5[4] = WkB;
  pa.Wffin = Wffin; pa.Wffout = Wffout; pa.Wo = Wo; pa.h = h;
  pa.wt5 = wt5; pa.wtfi = wtfi; pa.wtfoc = wtfoc;
  pa.cosb = cosb; pa.sinb = sinb; pa.inner = inner;
  prologue_k<<<dim3(22656), 256, 0, stream>>>(pa);

  // proj + l2norm/rope + in-LDS v-transpose epilogue
  gemm128p<<<dim3(1280), 256, 0, stream>>>(inner, wt5, qb, kb, vtb, bqh, bkh, cosb, sinb,
                                           4096, 5120, 1024, 32, 5);

  brow_all<<<dim3(64), 512, 0, stream>>>(bqh, bkh, browb);

  // flash (QBLK=128)
  flash_k<<<dim3(512), 256, 0, stream>>>(qb, kb, vtb, browb, l2ns, AB);

  // FF-in + silu fused
  gemm256p<1><<<dim3(512), 512, 0, stream>>>(inner, wtfi, AB, bffin,
                                             4096, 8192, 1024, 8, 8);

  // final merged GEMM (128^2, BK=64, 4-stage pipeline)
  gemm128f<<<dim3(256), 256, 0, stream>>>(AB, wtfoc, out, bffout, bo, lam, h,
                                          4096, 1024, 5120, 8, 4);
}

// Round 17
// 323.073 us; speedup vs baseline: 1.0001x; 1.0001x over previous
//
#include <hip/hip_runtime.h>
#include <stdint.h>
#include <math.h>

typedef float f32x4 __attribute__((ext_vector_type(4)));
typedef short s16x8 __attribute__((ext_vector_type(8)));
typedef unsigned short bfu;

#define AS1q const __attribute__((address_space(1))) void*
#define AS3q __attribute__((address_space(3))) void*

static __device__ __forceinline__ float bf2f(bfu v) {
  return __uint_as_float(((unsigned int)v) << 16);
}
static __device__ __forceinline__ bfu f2bf(float f) {
  unsigned int u = __float_as_uint(f);
  return (bfu)((u + 0x7fffu + ((u >> 16) & 1u)) >> 16);
}

// ================= fused prologue: all weight converts + rope tables + rmsnorm =================
struct PreArgs {
  const float* w5[5];
  const float* Wffin;
  const float* Wffout;
  const float* Wo;
  const float* h;
  bfu* wt5; bfu* wtfi; bfu* wtfoc;
  bfu* cosb; bfu* sinb; bfu* inner;
};
__global__ __launch_bounds__(256) void prologue_k(PreArgs a) {
  __shared__ float shmem[32 * 33];
  int id = blockIdx.x;
  if (id < 18432) {
    const float* W; bfu* Wt; int K, N, dstride, dofs, mode, nb, kb;
    if (id < 5120) {
      int z = id >> 10, rem = id & 1023;
      W = a.w5[z]; Wt = a.wt5 + ((size_t)z << 20);
      K = 1024; N = 1024; dstride = 1024; dofs = 0; mode = 0;
      nb = (rem & 31) << 5; kb = (rem >> 5) << 5;
    } else if (id < 13312) {
      int id2 = id - 5120;
      W = a.Wffin; Wt = a.wtfi; K = 1024; N = 8192; dstride = 1024; dofs = 0; mode = 1;
      nb = (id2 & 255) << 5; kb = (id2 >> 8) << 5;
    } else if (id < 17408) {
      int id3 = id - 13312;
      W = a.Wffout; Wt = a.wtfoc; K = 4096; N = 1024; dstride = 5120; dofs = 0; mode = 2;
      nb = (id3 & 31) << 5; kb = (id3 >> 5) << 5;
    } else {
      int id4 = id - 17408;
      W = a.Wo; Wt = a.wtfoc; K = 1024; N = 1024; dstride = 5120; dofs = 4096; mode = 2;
      nb = (id4 & 31) << 5; kb = (id4 >> 5) << 5;
    }
    float (*t)[33] = reinterpret_cast<float(*)[33]>(shmem);
    int tx = threadIdx.x & 31, ty = threadIdx.x >> 5;
#pragma unroll
    for (int i = 0; i < 4; i++) {
      int r = ty + i * 8;
      t[r][tx] = W[(size_t)(kb + r) * N + nb + tx];
    }
    __syncthreads();
#pragma unroll
    for (int i = 0; i < 4; i++) {
      int r = ty + i * 8;
      int n = nb + r;
      int nd = n;
      if (mode == 1) { int j = n & 4095, isg = n >> 12; nd = ((j >> 4) << 5) | (isg << 4) | (j & 15); }
      int k = kb + tx;
      int kp = (mode == 2) ? (((k >> 5) << 5) | ((k & 15) << 1) | ((k >> 4) & 1)) : k;
      Wt[(size_t)nd * dstride + dofs + kp] = f2bf(t[tx][r]);
    }
  } else if (id < 18560) {
    int idx = (id - 18432) * 256 + threadIdx.x;
    int s = idx >> 5, i = idx & 31;
    float f = powf(1000.0f, -(float)i / 32.0f);
    float fr = (float)s * f;
    a.cosb[idx] = f2bf(cosf(fr));
    a.sinb[idx] = f2bf(sinf(fr));
  } else {
    int row = id - 18560;
    const float* hr = a.h + (size_t)row * 1024;
    f32x4 x = *reinterpret_cast<const f32x4*>(hr + threadIdx.x * 4);
    float ss = x[0] * x[0] + x[1] * x[1] + x[2] * x[2] + x[3] * x[3];
    for (int off = 32; off; off >>= 1) ss += __shfl_down(ss, off);
    int wave = threadIdx.x >> 6, lane = threadIdx.x & 63;
    if (lane == 0) shmem[wave] = ss;
    __syncthreads();
    float tot = shmem[0] + shmem[1] + shmem[2] + shmem[3];
    float r = rsqrtf(tot * (1.0f / 1024.0f) + 1.1920929e-07f);
    bfu* o = a.inner + (size_t)row * 1024 + threadIdx.x * 4;
    o[0] = f2bf(x[0] * r); o[1] = f2bf(x[1] * r);
    o[2] = f2bf(x[2] * r); o[3] = f2bf(x[3] * r);
  }
}

// ============ 8-phase 256x256 GEMM, BK=64, 2-dbuf LDS, counted vmcnt (R8 order, FF-in) ============
template <int EPI>
__global__ __launch_bounds__(512, 2) void gemm256p(const bfu* __restrict__ A, const bfu* __restrict__ Bt,
                                                   bfu* __restrict__ outB,
                                                   const float* __restrict__ bias,
                                                   int M, int N, int K, int rbm, int rbn) {
  __shared__ __align__(16) char lds[131072];
  int nbx = N >> 8;
  int c = blockIdx.x & 7, rr = blockIdx.x >> 3;
  int ca = nbx / rbn;
  int bn0 = (c % ca) * rbn, bm0 = (c / ca) * rbm;
  int bm = bm0 + rr / rbn, bn = bn0 + rr % rbn;
  int tid = threadIdx.x, w = tid >> 6, lane = tid & 63;
  int wm = w >> 2, wn = w & 3;
  int g = lane >> 4, l15 = lane & 15;
  int NT = K >> 6;
  int NI = NT >> 1;

  f32x4 acc[8][4];
#pragma unroll
  for (int m = 0; m < 8; m++)
#pragma unroll
    for (int n = 0; n < 4; n++) acc[m][n] = (f32x4){0.f, 0.f, 0.f, 0.f};

  s16x8 af[4][2];
  s16x8 bfr[4][2];

  auto stage = [&](int mat, int kt, int hf) {
    if (kt >= NT) return;
    int d = kt & 1;
    const bfu* s0 = (mat == 0) ? A : Bt;
    int rowbase = ((mat == 0) ? bm : bn) * 256 + hf * 128;
    int k0 = kt << 6;
    char* base = lds + d * 65536 + mat * 32768 + hf * 16384;
#pragma unroll
    for (int r = 0; r < 2; r++) {
      int L = r * 512 + tid;
      int row = L >> 3, cc = L & 7;
      int kc = cc ^ (row & 7);
      const bfu* src = s0 + (size_t)(rowbase + row) * K + k0 + kc * 8;
      char* dst = base + r * 8192 + w * 1024;
      __builtin_amdgcn_global_load_lds((AS1q)src, (AS3q)dst, 16, 0, 0);
    }
  };

  auto ldA = [&](int d, int mh) {
    const char* base = lds + d * 65536 + wm * 16384;
#pragma unroll
    for (int mm = 0; mm < 4; mm++) {
      int row = mh * 64 + mm * 16 + l15;
#pragma unroll
      for (int ks = 0; ks < 2; ks++)
        af[mm][ks] = *reinterpret_cast<const s16x8*>(
            base + row * 128 + (((ks * 4 + g) ^ (row & 7)) << 4));
    }
  };
  auto ldB2 = [&](int d, int nh) {
    const char* base = lds + d * 65536 + 32768 + (wn >> 1) * 16384;
#pragma unroll
    for (int nn = 0; nn < 2; nn++) {
      int row = (wn & 1) * 64 + (nh * 2 + nn) * 16 + l15;
#pragma unroll
      for (int ks = 0; ks < 2; ks++)
        bfr[nh * 2 + nn][ks] = *reinterpret_cast<const s16x8*>(
            base + row * 128 + (((ks * 4 + g) ^ (row & 7)) << 4));
    }
  };
  auto mfma_q = [&](int mh, int nh) {
    asm volatile("s_waitcnt lgkmcnt(0)" ::: "memory");
    __builtin_amdgcn_sched_barrier(0);
    __builtin_amdgcn_s_barrier();
    __builtin_amdgcn_s_setprio(1);
#pragma unroll
    for (int mm = 0; mm < 4; mm++)
#pragma unroll
      for (int nn = 0; nn < 2; nn++) {
        int n = nh * 2 + nn, m = mh * 4 + mm;
#pragma unroll
        for (int ks = 0; ks < 2; ks++)
          acc[m][n] = __builtin_amdgcn_mfma_f32_16x16x32_bf16(af[mm][ks], bfr[n][ks], acc[m][n], 0, 0, 0);
      }
    __builtin_amdgcn_s_setprio(0);
    __builtin_amdgcn_sched_barrier(0);
  };

  stage(1, 0, 0); stage(0, 0, 0); stage(0, 0, 1); stage(1, 0, 1);
  stage(1, 1, 0); stage(1, 1, 1);
  asm volatile("s_waitcnt vmcnt(4)" ::: "memory");
  __builtin_amdgcn_s_barrier();
  __builtin_amdgcn_sched_barrier(0);

  for (int i = 0; i < NI; i++) {
    int t0 = 2 * i, t1 = 2 * i + 1;
    bool last = (i == NI - 1);
    ldA(0, 0); ldB2(0, 0);
    stage(0, t1, 0);
    mfma_q(0, 0);
    ldB2(0, 1);
    stage(0, t1, 1);
    mfma_q(0, 1);
    ldA(0, 1);
    stage(1, t0 + 2, 0);
    mfma_q(1, 0);
    stage(1, t0 + 2, 1);
    mfma_q(1, 1);
    if (last) { asm volatile("s_waitcnt vmcnt(0)" ::: "memory"); }
    else      { asm volatile("s_waitcnt vmcnt(4)" ::: "memory"); }
    __builtin_amdgcn_s_barrier();
    __builtin_amdgcn_sched_barrier(0);
    ldA(1, 0); ldB2(1, 0);
    stage(0, t0 + 2, 0);
    mfma_q(0, 0);
    ldB2(1, 1);
    stage(0, t0 + 2, 1);
    mfma_q(0, 1);
    ldA(1, 1);
    stage(1, t1 + 2, 0);
    mfma_q(1, 0);
    stage(1, t1 + 2, 1);
    mfma_q(1, 1);
    asm volatile("s_waitcnt vmcnt(4)" ::: "memory");
    __builtin_amdgcn_s_barrier();
    __builtin_amdgcn_sched_barrier(0);
  }

  // epilogue (FF-in silu fused, packed)
  int j0 = (bn * 8 + wn * 2) * 16 + l15;
  float bx0 = bias[j0], bg0 = bias[j0 + 4096];
  float bx1 = bias[j0 + 16], bg1 = bias[j0 + 16 + 4096];
  int cb = (bn * 4 + wn) * 32 + 2 * l15;
#pragma unroll
  for (int m = 0; m < 8; m++) {
#pragma unroll
    for (int r = 0; r < 4; r++) {
      int row = bm * 256 + wm * 128 + m * 16 + g * 4 + r;
      float xh0 = acc[m][0][r] + bx0, gt0 = acc[m][1][r] + bg0;
      float xh1 = acc[m][2][r] + bx1, gt1 = acc[m][3][r] + bg1;
      float s0 = gt0 / (1.0f + __expf(-gt0)) * xh0;
      float s1 = gt1 / (1.0f + __expf(-gt1)) * xh1;
      unsigned int pk = (unsigned int)f2bf(s0) | ((unsigned int)f2bf(s1) << 16);
      *reinterpret_cast<unsigned int*>(outB + (size_t)row * 5120 + cb) = pk;
    }
  }
}

// ============ 128x128 GEMM, BK=32, 3-stage pipeline, 4 waves, 3 blocks/CU (proj) ============
// v (which==2) is transposed in-LDS and written directly to vT [bh][d][s]
__global__ __launch_bounds__(256, 3) void gemm128p(const bfu* __restrict__ A, const bfu* __restrict__ Bt,
                                                   bfu* __restrict__ qb, bfu* __restrict__ kb,
                                                   bfu* __restrict__ vT,
                                                   bfu* __restrict__ bqh, bfu* __restrict__ bkh,
                                                   const bfu* __restrict__ ct, const bfu* __restrict__ st,
                                                   int M, int N, int K, int rbm, int rbn) {
  __shared__ __align__(16) char lds[49152];
  int nbx = N >> 7;
  int c = blockIdx.x & 7, rr = blockIdx.x >> 3;
  int ca = nbx / rbn;
  int bn0 = (c % ca) * rbn, bm0 = (c / ca) * rbm;
  int bm = bm0 + rr / rbn, bn = bn0 + rr % rbn;
  int tid = threadIdx.x, w = tid >> 6, lane = tid & 63;
  int wm = w >> 1, wn = w & 1;
  int g = lane >> 4, l15 = lane & 15;
  int NT = K >> 5;

  f32x4 acc[4][4];
#pragma unroll
  for (int m = 0; m < 4; m++)
#pragma unroll
    for (int n = 0; n < 4; n++) acc[m][n] = (f32x4){0.f, 0.f, 0.f, 0.f};

  auto stage = [&](int buf, int t) {
    int k0 = t << 5;
#pragma unroll
    for (int r = 0; r < 2; r++) {
      int L = r * 256 + tid;
      int row = L >> 2, cc = L & 3;
      int kc = cc ^ (row & 3);
      const bfu* srcA = A + (size_t)(bm * 128 + row) * K + k0 + kc * 8;
      char* dstA = lds + buf * 16384 + r * 4096 + w * 1024;
      __builtin_amdgcn_global_load_lds((AS1q)srcA, (AS3q)dstA, 16, 0, 0);
      const bfu* srcB = Bt + (size_t)(bn * 128 + row) * K + k0 + kc * 8;
      char* dstB = lds + buf * 16384 + 8192 + r * 4096 + w * 1024;
      __builtin_amdgcn_global_load_lds((AS1q)srcB, (AS3q)dstB, 16, 0, 0);
    }
  };

  stage(0, 0); stage(1, 1);
  asm volatile("s_waitcnt vmcnt(4)" ::: "memory");
  __builtin_amdgcn_s_barrier();
  __builtin_amdgcn_sched_barrier(0);

  int bc = 0;
  for (int t = 0; t < NT; t++) {
    int bs = bc + 2; if (bs >= 3) bs -= 3;
    if (t + 2 < NT) stage(bs, t + 2);
    const char* la = lds + bc * 16384;
    const char* lb = la + 8192;
    s16x8 af[4], bfr[4];
#pragma unroll
    for (int m = 0; m < 4; m++) {
      int row = wm * 64 + m * 16 + l15;
      af[m] = *reinterpret_cast<const s16x8*>(la + row * 64 + ((g ^ (row & 3)) << 4));
    }
#pragma unroll
    for (int n = 0; n < 4; n++) {
      int row = wn * 64 + n * 16 + l15;
      bfr[n] = *reinterpret_cast<const s16x8*>(lb + row * 64 + ((g ^ (row & 3)) << 4));
    }
    asm volatile("s_waitcnt lgkmcnt(0)" ::: "memory");
    __builtin_amdgcn_sched_barrier(0);
    __builtin_amdgcn_s_setprio(1);
#pragma unroll
    for (int m = 0; m < 4; m++)
#pragma unroll
      for (int n = 0; n < 4; n++)
        acc[m][n] = __builtin_amdgcn_mfma_f32_16x16x32_bf16(af[m], bfr[n], acc[m][n], 0, 0, 0);
    __builtin_amdgcn_s_setprio(0);
    __builtin_amdgcn_sched_barrier(0);
    if (t < NT - 2) { asm volatile("s_waitcnt vmcnt(4)" ::: "memory"); }
    else            { asm volatile("s_waitcnt vmcnt(0)" ::: "memory"); }
    __builtin_amdgcn_s_barrier();
    __builtin_amdgcn_sched_barrier(0);
    bc++; if (bc == 3) bc = 0;
  }

  int which = bn >> 3;               // 0 q | 1 k | 2 v | 3 bq | 4 bk
  int hh = (bn & 7) * 2 + wn;
  if (which == 2) {
    bfu* lv = reinterpret_cast<bfu*>(lds);
#pragma unroll
    for (int m = 0; m < 4; m++) {
#pragma unroll
      for (int r = 0; r < 4; r++) {
        int sl = wm * 64 + m * 16 + g * 4 + r;
#pragma unroll
        for (int j = 0; j < 4; j++) {
          int d = j * 16 + l15;
          lv[(wn * 64 + d) * 136 + sl] = f2bf(acc[m][j][r]);
        }
      }
    }
    __syncthreads();
    int b = bm >> 3, h0 = (bn & 7) * 2;
#pragma unroll
    for (int i = 0; i < 8; i++) {
      int linear = i * 256 + tid;
      int hw = linear >> 10, rem = linear & 1023;
      int d = rem >> 4, sl8 = (rem & 15) << 3;
      s16x8 v8 = *reinterpret_cast<const s16x8*>(&lv[(hw * 64 + d) * 136 + sl8]);
      size_t dstofs = (((size_t)((b << 4) + h0 + hw) << 6) + d) * 1024 + (bm & 7) * 128 + sl8;
      *reinterpret_cast<s16x8*>(vT + dstofs) = v8;
    }
  } else {
#pragma unroll
    for (int m = 0; m < 4; m++) {
#pragma unroll
      for (int r = 0; r < 4; r++) {
        int row = bm * 128 + wm * 64 + m * 16 + g * 4 + r;
        int s = row & 1023, b = row >> 10;
        float a0 = acc[m][0][r], a1 = acc[m][1][r];
        float a2 = acc[m][2][r], a3 = acc[m][3][r];
        float ss = a0 * a0 + a1 * a1 + a2 * a2 + a3 * a3;
        ss += __shfl_xor(ss, 1); ss += __shfl_xor(ss, 2);
        ss += __shfl_xor(ss, 4); ss += __shfl_xor(ss, 8);
        float inv = 1.0f / fmaxf(sqrtf(ss), 1e-12f);
        float xn0 = a0 * inv, xn1 = a1 * inv, xn2 = a2 * inv, xn3 = a3 * inv;
        float c0 = bf2f(ct[(s << 5) + l15]),      s0v = bf2f(st[(s << 5) + l15]);
        float c1 = bf2f(ct[(s << 5) + 16 + l15]), s1v = bf2f(st[(s << 5) + 16 + l15]);
        float o0 = xn0 * c0 + xn2 * s0v;
        float o1 = xn1 * c1 + xn3 * s1v;
        float o2 = xn2 * c0 - xn0 * s0v;
        float o3 = xn3 * c1 - xn1 * s1v;
        unsigned long long pk =
            (unsigned long long)((unsigned int)f2bf(o0) | ((unsigned int)f2bf(o1) << 16)) |
            ((unsigned long long)((unsigned int)f2bf(o2) | ((unsigned int)f2bf(o3) << 16)) << 32);
        size_t base = ((((size_t)((b << 4) + hh) << 10) + s) << 6) + (l15 << 2);
        bfu* dst = (which == 0) ? qb : (which == 1) ? kb : (which == 3) ? bqh : bkh;
        *reinterpret_cast<unsigned long long*>(dst + base) = pk;
      }
    }
  }
}

// ============ final GEMM: 128x128 tile, BK=64, 3-stage pipeline, 4 waves (R13-proven) ============
__global__ __launch_bounds__(256, 3) void gemm128f(const bfu* __restrict__ A, const bfu* __restrict__ Bt,
                                                   float* __restrict__ out,
                                                   const float* __restrict__ b1,
                                                   const float* __restrict__ b2,
                                                   const float* __restrict__ lam,
                                                   const float* __restrict__ h,
                                                   int M, int N, int K, int rbm, int rbn) {
  __shared__ __align__(16) char lds[98304];  // 3 x (A 16KB | B 16KB)
  int nbx = N >> 7;
  int c = blockIdx.x & 7, rr = blockIdx.x >> 3;
  int ca = nbx / rbn;
  int bn0 = (c % ca) * rbn, bm0 = (c / ca) * rbm;
  int bm = bm0 + rr / rbn, bn = bn0 + rr % rbn;
  int tid = threadIdx.x, w = tid >> 6, lane = tid & 63;
  int wm = w >> 1, wn = w & 1;
  int g = lane >> 4, l15 = lane & 15;
  int NT = K >> 6;   // BK=64 -> 80 iters

  f32x4 acc[4][4];
#pragma unroll
  for (int m = 0; m < 4; m++)
#pragma unroll
    for (int n = 0; n < 4; n++) acc[m][n] = (f32x4){0.f, 0.f, 0.f, 0.f};

  auto stage = [&](int buf, int t) {
    int k0 = t << 6;
#pragma unroll
    for (int r = 0; r < 4; r++) {
      int L = r * 256 + tid;
      int row = L >> 3, cc = L & 7;
      int kc = cc ^ (row & 7);
      const bfu* srcA = A + (size_t)(bm * 128 + row) * K + k0 + kc * 8;
      char* dstA = lds + buf * 32768 + r * 4096 + w * 1024;
      __builtin_amdgcn_global_load_lds((AS1q)srcA, (AS3q)dstA, 16, 0, 0);
    }
#pragma unroll
    for (int r = 0; r < 4; r++) {
      int L = r * 256 + tid;
      int row = L >> 3, cc = L & 7;
      int kc = cc ^ (row & 7);
      const bfu* srcB = Bt + (size_t)(bn * 128 + row) * K + k0 + kc * 8;
      char* dstB = lds + buf * 32768 + 16384 + r * 4096 + w * 1024;
      __builtin_amdgcn_global_load_lds((AS1q)srcB, (AS3q)dstB, 16, 0, 0);
    }
  };

  stage(0, 0); stage(1, 1);
  asm volatile("s_waitcnt vmcnt(8)" ::: "memory");
  __builtin_amdgcn_s_barrier();
  __builtin_amdgcn_sched_barrier(0);

  int bc = 0;
  for (int t = 0; t < NT; t++) {
    int bs = bc + 2; if (bs >= 3) bs -= 3;
    if (t + 2 < NT) stage(bs, t + 2);
    const char* la = lds + bc * 32768;
    const char* lb = la + 16384;
    s16x8 af[4][2], bfr[4][2];
#pragma unroll
    for (int m = 0; m < 4; m++) {
      int row = wm * 64 + m * 16 + l15;
#pragma unroll
      for (int ks = 0; ks < 2; ks++)
        af[m][ks] = *reinterpret_cast<const s16x8*>(
            la + row * 128 + (((ks * 4 + g) ^ (row & 7)) << 4));
    }
#pragma unroll
    for (int n = 0; n < 4; n++) {
      int row = wn * 64 + n * 16 + l15;
#pragma unroll
      for (int ks = 0; ks < 2; ks++)
        bfr[n][ks] = *reinterpret_cast<const s16x8*>(
            lb + row * 128 + (((ks * 4 + g) ^ (row & 7)) << 4));
    }
    asm volatile("s_waitcnt lgkmcnt(0)" ::: "memory");
    __builtin_amdgcn_sched_barrier(0);
    __builtin_amdgcn_s_setprio(1);
#pragma unroll
    for (int m = 0; m < 4; m++)
#pragma unroll
      for (int n = 0; n < 4; n++)
#pragma unroll
        for (int ks = 0; ks < 2; ks++)
          acc[m][n] = __builtin_amdgcn_mfma_f32_16x16x32_bf16(af[m][ks], bfr[n][ks], acc[m][n], 0, 0, 0);
    __builtin_amdgcn_s_setprio(0);
    __builtin_amdgcn_sched_barrier(0);
    if (t < NT - 2) { asm volatile("s_waitcnt vmcnt(8)" ::: "memory"); }
    else            { asm volatile("s_waitcnt vmcnt(0)" ::: "memory"); }
    __builtin_amdgcn_s_barrier();
    __builtin_amdgcn_sched_barrier(0);
    bc++; if (bc == 3) bc = 0;
  }

  float lv = lam[0];
#pragma unroll
  for (int m = 0; m < 4; m++) {
    int row = bm * 128 + wm * 64 + m * 16 + g * 4;
#pragma unroll
    for (int n = 0; n < 4; n++) {
      int col = bn * 128 + wn * 64 + n * 16 + l15;
      float bb = b1[col] + b2[col];
#pragma unroll
      for (int r = 0; r < 4; r++) {
        size_t o = (size_t)(row + r) * 1024 + col;
        out[o] = acc[m][n][r] + bb + lv * h[o];
      }
    }
  }
}

// ---------------- fused brow ----------------
__global__ __launch_bounds__(512) void brow_all(const bfu* __restrict__ bq, const bfu* __restrict__ bk,
                                                float* __restrict__ brow) {
  __shared__ float csums[8][64];
  int bh = blockIdx.x;
  int wave = threadIdx.x >> 6, lane = threadIdx.x & 63;
  size_t base = ((size_t)bh * 1024 + wave * 128) * 64 + lane;
  float s = 0.f;
  for (int j = 0; j < 128; j++) s += bf2f(bk[base + (size_t)j * 64]);
  csums[wave][lane] = s;
  __syncthreads();
  float p = 0.f;
  for (int cc = 0; cc < wave; cc++) p += csums[cc][lane];
  for (int j = 0; j < 128; j++) {
    p += bf2f(bk[base + (size_t)j * 64]);
    float t = bf2f(bq[base + (size_t)j * 64]) * p;
#pragma unroll
    for (int m2 = 1; m2 < 64; m2 <<= 1) t += __shfl_xor(t, m2);
    if (lane == 0) brow[bh * 1024 + wave * 128 + j] = 0.125f * t;
  }
}

// ---------------- flash attention: QBLK=128/block, 2 m-tiles/wave (R13-proven) ----------------
__global__ __launch_bounds__(256) void flash_k(const bfu* __restrict__ q, const bfu* __restrict__ k,
                                               const bfu* __restrict__ vT,
                                               const float* __restrict__ brow,
                                               const float* __restrict__ l2p,
                                               bfu* __restrict__ y) {
  __shared__ __align__(16) bfu P[4][2][16][72];
  int id = blockIdx.x;  // 0..511
  int sub = id & 255;
  int qt = (id >> 8) ? 7 - (sub >> 6) : (sub >> 6);
  int bh = sub & 63;
  int wave = threadIdx.x >> 6, lane = threadIdx.x & 63;
  int g = lane >> 4, l15 = lane & 15;
  const size_t bhofs = (size_t)bh << 16;
  int rt0 = qt * 128 + wave * 32;

  s16x8 aq[2][2];
#pragma unroll
  for (int m = 0; m < 2; m++)
#pragma unroll
    for (int ks = 0; ks < 2; ks++)
      aq[m][ks] = *reinterpret_cast<const s16x8*>(
          q + bhofs + (size_t)(rt0 + m * 16 + l15) * 64 + ks * 32 + g * 8);

  f32x4 O[2][4];
  float mr[2][4], lr[2][4];
#pragma unroll
  for (int m = 0; m < 2; m++)
#pragma unroll
    for (int r = 0; r < 4; r++) { O[m][r] = (f32x4){0.f, 0.f, 0.f, 0.f}; mr[m][r] = -3.0e38f; lr[m][r] = 0.f; }

  s16x8 kA[4][2], kB[4][2];
  auto loadK = [&](s16x8 (&kd)[4][2], int jt) {
#pragma unroll
    for (int nt = 0; nt < 4; nt++)
#pragma unroll
      for (int ks = 0; ks < 2; ks++)
        kd[nt][ks] = *reinterpret_cast<const s16x8*>(
            k + bhofs + (size_t)(jt * 64 + nt * 16 + l15) * 64 + ks * 32 + g * 8);
  };

  int njt = 2 * qt + 2;
  loadK(kA, 0);

  auto body = [&](int jt, s16x8 (&kc)[4][2], s16x8 (&kn)[4][2], bool pf) {
    s16x8 vv[4][2];
#pragma unroll
    for (int nt = 0; nt < 4; nt++)
#pragma unroll
      for (int ks = 0; ks < 2; ks++)
        vv[nt][ks] = *reinterpret_cast<const s16x8*>(
            vT + ((size_t)(bh * 64 + nt * 16 + l15) << 10) + jt * 64 + ks * 32 + g * 8);

    bool act[2] = { jt * 64 <= rt0 + 15, jt * 64 <= rt0 + 31 };
    f32x4 sfr[2][4];
#pragma unroll
    for (int m = 0; m < 2; m++) {
      if (!act[m]) continue;
#pragma unroll
      for (int nt = 0; nt < 4; nt++) {
        sfr[m][nt] = (f32x4){0.f, 0.f, 0.f, 0.f};
#pragma unroll
        for (int ks = 0; ks < 2; ks++)
          sfr[m][nt] = __builtin_amdgcn_mfma_f32_16x16x32_bf16(aq[m][ks], kc[nt][ks], sfr[m][nt], 0, 0, 0);
      }
    }
    if (pf) loadK(kn, jt + 1);

#pragma unroll
    for (int m = 0; m < 2; m++) {
      if (!act[m]) continue;
      int rtm = rt0 + m * 16;
      if (jt * 64 + 63 > rtm) {
#pragma unroll
        for (int ntn = 0; ntn < 4; ntn++)
#pragma unroll
          for (int r = 0; r < 4; r++)
            if (jt * 64 + ntn * 16 + l15 > rtm + g * 4 + r) sfr[m][ntn][r] = -1e30f;
      }
      float alpha[4];
#pragma unroll
      for (int r = 0; r < 4; r++) {
        float v = fmaxf(fmaxf(sfr[m][0][r], sfr[m][1][r]), fmaxf(sfr[m][2][r], sfr[m][3][r]));
#pragma unroll
        for (int m2 = 1; m2 < 16; m2 <<= 1) v = fmaxf(v, __shfl_xor(v, m2));
        float mn = fmaxf(mr[m][r], v);
        alpha[r] = __expf(mr[m][r] - mn);
        mr[m][r] = mn;
      }
#pragma unroll
      for (int r = 0; r < 4; r++) {
        float rs = 0.f;
#pragma unroll
        for (int ntn = 0; ntn < 4; ntn++) {
          float e = __expf(sfr[m][ntn][r] - mr[m][r]);
          rs += e;
          P[wave][m][g * 4 + r][ntn * 16 + l15] = f2bf(e);
        }
#pragma unroll
        for (int m2 = 1; m2 < 16; m2 <<= 1) rs += __shfl_xor(rs, m2);
        lr[m][r] = lr[m][r] * alpha[r] + rs;
#pragma unroll
        for (int ntn = 0; ntn < 4; ntn++) O[m][ntn][r] *= alpha[r];
      }
    }
    asm volatile("s_waitcnt lgkmcnt(0)" ::: "memory");
    __builtin_amdgcn_sched_barrier(0);
#pragma unroll
    for (int m = 0; m < 2; m++) {
      if (!act[m]) continue;
      s16x8 pa[2];
#pragma unroll
      for (int ks = 0; ks < 2; ks++)
        pa[ks] = *reinterpret_cast<const s16x8*>(&P[wave][m][l15][ks * 32 + g * 8]);
#pragma unroll
      for (int nt = 0; nt < 4; nt++)
#pragma unroll
        for (int ks = 0; ks < 2; ks++)
          O[m][nt] = __builtin_amdgcn_mfma_f32_16x16x32_bf16(pa[ks], vv[nt][ks], O[m][nt], 0, 0, 0);
    }
  };

  for (int jt = 0; jt < njt; jt += 2) {
    body(jt, kA, kB, true);
    body(jt + 1, kB, kA, jt + 2 < njt);
  }

  float l2ns = l2p[0];
  int b = bh >> 4, hq = bh & 15;
#pragma unroll
  for (int m = 0; m < 2; m++)
#pragma unroll
    for (int r = 0; r < 4; r++) {
      int rowg = rt0 + m * 16 + g * 4 + r;
      float br = brow[bh * 1024 + rowg];
      float sc = l2ns / lr[m][r];
      float v0 = O[m][0][r] * sc + br;
      float v1 = O[m][1][r] * sc + br;
      float v2 = O[m][2][r] * sc + br;
      float v3 = O[m][3][r] * sc + br;
      unsigned int p01 = (unsigned int)f2bf(v0) | ((unsigned int)f2bf(v1) << 16);
      unsigned int p23 = (unsigned int)f2bf(v2) | ((unsigned int)f2bf(v3) << 16);
      size_t base = (size_t)(b * 1024 + rowg) * 5120 + 4096 + hq * 64;
      *reinterpret_cast<unsigned int*>(y + base + 2 * l15) = p01;
      *reinterpret_cast<unsigned int*>(y + base + 32 + 2 * l15) = p23;
    }
}

// ================= host =================
extern "C" void kernel_launch(void* const* d_in, const int* in_sizes, int n_in,
                              void* d_out, int out_size, void* d_ws, size_t ws_size,
                              hipStream_t stream) {
  const float* h      = (const float*)d_in[0];
  const float* Wq     = (const float*)d_in[2];
  const float* Wk     = (const float*)d_in[3];
  const float* Wv     = (const float*)d_in[4];
  const float* WqB    = (const float*)d_in[5];
  const float* WkB    = (const float*)d_in[6];
  const float* Wo     = (const float*)d_in[7];
  const float* bo     = (const float*)d_in[8];
  const float* Wffin  = (const float*)d_in[9];
  const float* bffin  = (const float*)d_in[10];
  const float* Wffout = (const float*)d_in[11];
  const float* bffout = (const float*)d_in[12];
  const float* lam    = (const float*)d_in[13];
  const float* l2ns   = (const float*)d_in[14];
  float* out = (float*)d_out;

  char* ws = (char*)d_ws;
  size_t off = 0;
  auto alloc = [&](size_t bytes) { void* p = ws + off; off += bytes; return p; };
  bfu* wt5   = (bfu*)alloc(5ull * 1024 * 1024 * 2);
  bfu* wtfi  = (bfu*)alloc(8192ull * 1024 * 2);
  bfu* wtfoc = (bfu*)alloc(1024ull * 5120 * 2);
  bfu* cosb  = (bfu*)alloc(1024ull * 32 * 2);
  bfu* sinb  = (bfu*)alloc(1024ull * 32 * 2);
  bfu* inner = (bfu*)alloc(4096ull * 1024 * 2);
  bfu* qb    = (bfu*)alloc(64ull * 1024 * 64 * 2);
  bfu* kb    = (bfu*)alloc(64ull * 1024 * 64 * 2);
  bfu* vtb   = (bfu*)alloc(64ull * 1024 * 64 * 2);
  bfu* bqh   = (bfu*)alloc(64ull * 1024 * 64 * 2);
  bfu* bkh   = (bfu*)alloc(64ull * 1024 * 64 * 2);
  float* browb = (float*)alloc(64ull * 1024 * 4);
  bfu* AB    = (bfu*)alloc(4096ull * 5120 * 2);

  // fused prologue
  PreArgs pa;
  pa.w5[0] = Wq; pa.w5[1] = Wk; pa.w5[2] = Wv; pa.w5[3] = WqB; pa.w5[4] = WkB;
  pa.Wffin = Wffin; pa.Wffout = Wffout; pa.Wo = Wo; pa.h = h;
  pa.wt5 = wt5; pa.wtfi = wtfi; pa.wtfoc = wtfoc;
  pa.cosb = cosb; pa.sinb = sinb; pa.inner = inner;
  prologue_k<<<dim3(22656), 256, 0, stream>>>(pa);

  // proj + l2norm/rope + in-LDS v-transpose epilogue
  gemm128p<<<dim3(1280), 256, 0, stream>>>(inner, wt5, qb, kb, vtb, bqh, bkh, cosb, sinb,
                                           4096, 5120, 1024, 32, 5);

  brow_all<<<dim3(64), 512, 0, stream>>>(bqh, bkh, browb);

  // flash (QBLK=128)
  flash_k<<<dim3(512), 256, 0, stream>>>(qb, kb, vtb, browb, l2ns, AB);

  // FF-in + silu fused
  gemm256p<1><<<dim3(512), 512, 0, stream>>>(inner, wtfi, AB, bffin,
                                             4096, 8192, 1024, 8, 8);

  // final merged GEMM (128^2, BK=64, 3-stage)
  gemm128f<<<dim3(256), 256, 0, stream>>>(AB, wtfoc, out, bffout, bo, lam, h,
                                          4096, 1024, 5120, 8, 4);
}

// Round 18
// 305.748 us; speedup vs baseline: 1.0568x; 1.0567x over previous
//
#include <hip/hip_runtime.h>
#include <stdint.h>
#include <math.h>

typedef float f32x4 __attribute__((ext_vector_type(4)));
typedef short s16x8 __attribute__((ext_vector_type(8)));
typedef unsigned short bfu;

#define AS1q const __attribute__((address_space(1))) void*
#define AS3q __attribute__((address_space(3))) void*

static __device__ __forceinline__ float bf2f(bfu v) {
  return __uint_as_float(((unsigned int)v) << 16);
}
static __device__ __forceinline__ bfu f2bf(float f) {
  unsigned int u = __float_as_uint(f);
  return (bfu)((u + 0x7fffu + ((u >> 16) & 1u)) >> 16);
}

// ================= fused prologue: all weight converts + rope tables + rmsnorm =================
struct PreArgs {
  const float* w5[5];
  const float* Wffin;
  const float* Wffout;
  const float* Wo;
  const float* h;
  bfu* wt5; bfu* wtfi; bfu* wtfoc;
  bfu* cosb; bfu* sinb; bfu* inner;
};
__global__ __launch_bounds__(256) void prologue_k(PreArgs a) {
  __shared__ float shmem[32 * 33];
  int id = blockIdx.x;
  if (id < 18432) {
    const float* W; bfu* Wt; int K, N, dstride, dofs, mode, nb, kb;
    if (id < 5120) {
      int z = id >> 10, rem = id & 1023;
      W = a.w5[z]; Wt = a.wt5 + ((size_t)z << 20);
      K = 1024; N = 1024; dstride = 1024; dofs = 0; mode = 0;
      nb = (rem & 31) << 5; kb = (rem >> 5) << 5;
    } else if (id < 13312) {
      int id2 = id - 5120;
      W = a.Wffin; Wt = a.wtfi; K = 1024; N = 8192; dstride = 1024; dofs = 0; mode = 1;
      nb = (id2 & 255) << 5; kb = (id2 >> 8) << 5;
    } else if (id < 17408) {
      int id3 = id - 13312;
      W = a.Wffout; Wt = a.wtfoc; K = 4096; N = 1024; dstride = 5120; dofs = 0; mode = 2;
      nb = (id3 & 31) << 5; kb = (id3 >> 5) << 5;
    } else {
      int id4 = id - 17408;
      W = a.Wo; Wt = a.wtfoc; K = 1024; N = 1024; dstride = 5120; dofs = 4096; mode = 2;
      nb = (id4 & 31) << 5; kb = (id4 >> 5) << 5;
    }
    float (*t)[33] = reinterpret_cast<float(*)[33]>(shmem);
    int tx = threadIdx.x & 31, ty = threadIdx.x >> 5;
#pragma unroll
    for (int i = 0; i < 4; i++) {
      int r = ty + i * 8;
      t[r][tx] = W[(size_t)(kb + r) * N + nb + tx];
    }
    __syncthreads();
#pragma unroll
    for (int i = 0; i < 4; i++) {
      int r = ty + i * 8;
      int n = nb + r;
      int nd = n;
      if (mode == 1) { int j = n & 4095, isg = n >> 12; nd = ((j >> 4) << 5) | (isg << 4) | (j & 15); }
      int k = kb + tx;
      int kp = (mode == 2) ? (((k >> 5) << 5) | ((k & 15) << 1) | ((k >> 4) & 1)) : k;
      Wt[(size_t)nd * dstride + dofs + kp] = f2bf(t[tx][r]);
    }
  } else if (id < 18560) {
    int idx = (id - 18432) * 256 + threadIdx.x;
    int s = idx >> 5, i = idx & 31;
    float f = powf(1000.0f, -(float)i / 32.0f);
    float fr = (float)s * f;
    a.cosb[idx] = f2bf(cosf(fr));
    a.sinb[idx] = f2bf(sinf(fr));
  } else {
    int row = id - 18560;
    const float* hr = a.h + (size_t)row * 1024;
    f32x4 x = *reinterpret_cast<const f32x4*>(hr + threadIdx.x * 4);
    float ss = x[0] * x[0] + x[1] * x[1] + x[2] * x[2] + x[3] * x[3];
    for (int off = 32; off; off >>= 1) ss += __shfl_down(ss, off);
    int wave = threadIdx.x >> 6, lane = threadIdx.x & 63;
    if (lane == 0) shmem[wave] = ss;
    __syncthreads();
    float tot = shmem[0] + shmem[1] + shmem[2] + shmem[3];
    float r = rsqrtf(tot * (1.0f / 1024.0f) + 1.1920929e-07f);
    bfu* o = a.inner + (size_t)row * 1024 + threadIdx.x * 4;
    o[0] = f2bf(x[0] * r); o[1] = f2bf(x[1] * r);
    o[2] = f2bf(x[2] * r); o[3] = f2bf(x[3] * r);
  }
}

// ============ fused dispatch: flash (blocks 0..255, 2 sub-blocks/block) + FF-in (256..767) ============
__global__ __launch_bounds__(512, 2) void fused_k(const bfu* __restrict__ q, const bfu* __restrict__ k,
                                                  const bfu* __restrict__ vT,
                                                  const float* __restrict__ brow,
                                                  const float* __restrict__ l2p,
                                                  const bfu* __restrict__ A, const bfu* __restrict__ Bt,
                                                  bfu* __restrict__ AB,
                                                  const float* __restrict__ bias) {
  __shared__ __align__(16) char lds[131072];
  int tid = threadIdx.x, w = tid >> 6, lane = tid & 63;
  int g = lane >> 4, l15 = lane & 15;

  if (blockIdx.x < 256) {
    // ================== flash: waves 0-3 -> fid, waves 4-7 -> fid+256 (balanced pair) ==================
    int fid = blockIdx.x + ((w >> 2) << 8);
    int sub = fid & 255;
    int qt = (fid >> 8) ? 7 - (sub >> 6) : (sub >> 6);
    int bh = sub & 63;
    const size_t bhofs = (size_t)bh << 16;
    int rt0 = qt * 128 + (w & 3) * 32;
    bfu* P = reinterpret_cast<bfu*>(lds) + (size_t)w * (2 * 16 * 72);   // per-wave P slice

    s16x8 aq[2][2];
#pragma unroll
    for (int m = 0; m < 2; m++)
#pragma unroll
      for (int ks = 0; ks < 2; ks++)
        aq[m][ks] = *reinterpret_cast<const s16x8*>(
            q + bhofs + (size_t)(rt0 + m * 16 + l15) * 64 + ks * 32 + g * 8);

    f32x4 O[2][4];
    float mr[2][4], lr[2][4];
#pragma unroll
    for (int m = 0; m < 2; m++)
#pragma unroll
      for (int r = 0; r < 4; r++) { O[m][r] = (f32x4){0.f, 0.f, 0.f, 0.f}; mr[m][r] = -3.0e38f; lr[m][r] = 0.f; }

    s16x8 kA[4][2], kB[4][2];
    auto loadK = [&](s16x8 (&kd)[4][2], int jt) {
#pragma unroll
      for (int nt = 0; nt < 4; nt++)
#pragma unroll
        for (int ks = 0; ks < 2; ks++)
          kd[nt][ks] = *reinterpret_cast<const s16x8*>(
              k + bhofs + (size_t)(jt * 64 + nt * 16 + l15) * 64 + ks * 32 + g * 8);
    };

    int njt = 2 * qt + 2;
    loadK(kA, 0);

    auto body = [&](int jt, s16x8 (&kc)[4][2], s16x8 (&kn)[4][2], bool pf) {
      s16x8 vv[4][2];
#pragma unroll
      for (int nt = 0; nt < 4; nt++)
#pragma unroll
        for (int ks = 0; ks < 2; ks++)
          vv[nt][ks] = *reinterpret_cast<const s16x8*>(
              vT + ((size_t)(bh * 64 + nt * 16 + l15) << 10) + jt * 64 + ks * 32 + g * 8);

      bool act[2] = { jt * 64 <= rt0 + 15, jt * 64 <= rt0 + 31 };
      f32x4 sfr[2][4];
#pragma unroll
      for (int m = 0; m < 2; m++) {
        if (!act[m]) continue;
#pragma unroll
        for (int nt = 0; nt < 4; nt++) {
          sfr[m][nt] = (f32x4){0.f, 0.f, 0.f, 0.f};
#pragma unroll
          for (int ks = 0; ks < 2; ks++)
            sfr[m][nt] = __builtin_amdgcn_mfma_f32_16x16x32_bf16(aq[m][ks], kc[nt][ks], sfr[m][nt], 0, 0, 0);
        }
      }
      if (pf) loadK(kn, jt + 1);

#pragma unroll
      for (int m = 0; m < 2; m++) {
        if (!act[m]) continue;
        int rtm = rt0 + m * 16;
        if (jt * 64 + 63 > rtm) {
#pragma unroll
          for (int ntn = 0; ntn < 4; ntn++)
#pragma unroll
            for (int r = 0; r < 4; r++)
              if (jt * 64 + ntn * 16 + l15 > rtm + g * 4 + r) sfr[m][ntn][r] = -1e30f;
        }
        float alpha[4];
#pragma unroll
        for (int r = 0; r < 4; r++) {
          float v = fmaxf(fmaxf(sfr[m][0][r], sfr[m][1][r]), fmaxf(sfr[m][2][r], sfr[m][3][r]));
#pragma unroll
          for (int m2 = 1; m2 < 16; m2 <<= 1) v = fmaxf(v, __shfl_xor(v, m2));
          float mn = fmaxf(mr[m][r], v);
          alpha[r] = __expf(mr[m][r] - mn);
          mr[m][r] = mn;
        }
#pragma unroll
        for (int r = 0; r < 4; r++) {
          float rs = 0.f;
#pragma unroll
          for (int ntn = 0; ntn < 4; ntn++) {
            float e = __expf(sfr[m][ntn][r] - mr[m][r]);
            rs += e;
            P[(m * 16 + g * 4 + r) * 72 + ntn * 16 + l15] = f2bf(e);
          }
#pragma unroll
          for (int m2 = 1; m2 < 16; m2 <<= 1) rs += __shfl_xor(rs, m2);
          lr[m][r] = lr[m][r] * alpha[r] + rs;
#pragma unroll
          for (int ntn = 0; ntn < 4; ntn++) O[m][ntn][r] *= alpha[r];
        }
      }
      asm volatile("s_waitcnt lgkmcnt(0)" ::: "memory");
      __builtin_amdgcn_sched_barrier(0);
#pragma unroll
      for (int m = 0; m < 2; m++) {
        if (!act[m]) continue;
        s16x8 pa[2];
#pragma unroll
        for (int ks = 0; ks < 2; ks++)
          pa[ks] = *reinterpret_cast<const s16x8*>(&P[(m * 16 + l15) * 72 + ks * 32 + g * 8]);
#pragma unroll
        for (int nt = 0; nt < 4; nt++)
#pragma unroll
          for (int ks = 0; ks < 2; ks++)
            O[m][nt] = __builtin_amdgcn_mfma_f32_16x16x32_bf16(pa[ks], vv[nt][ks], O[m][nt], 0, 0, 0);
      }
    };

    for (int jt = 0; jt < njt; jt += 2) {
      body(jt, kA, kB, true);
      body(jt + 1, kB, kA, jt + 2 < njt);
    }

    float l2ns = l2p[0];
    int b = bh >> 4, hq = bh & 15;
#pragma unroll
    for (int m = 0; m < 2; m++)
#pragma unroll
      for (int r = 0; r < 4; r++) {
        int rowg = rt0 + m * 16 + g * 4 + r;
        float br = brow[bh * 1024 + rowg];
        float sc = l2ns / lr[m][r];
        float v0 = O[m][0][r] * sc + br;
        float v1 = O[m][1][r] * sc + br;
        float v2 = O[m][2][r] * sc + br;
        float v3 = O[m][3][r] * sc + br;
        unsigned int p01 = (unsigned int)f2bf(v0) | ((unsigned int)f2bf(v1) << 16);
        unsigned int p23 = (unsigned int)f2bf(v2) | ((unsigned int)f2bf(v3) << 16);
        size_t base = (size_t)(b * 1024 + rowg) * 5120 + 4096 + hq * 64;
        *reinterpret_cast<unsigned int*>(AB + base + 2 * l15) = p01;
        *reinterpret_cast<unsigned int*>(AB + base + 32 + 2 * l15) = p23;
      }
    return;
  }

  // ================== FF-in: 256x256, BK=64, 2-dbuf, counted vmcnt (R8 order) ==================
  int id0 = blockIdx.x - 256;
  int c = id0 & 7, rr = id0 >> 3;
  int bn0 = (c & 3) * 8, bm0 = (c >> 2) * 8;   // ca = 32/8 = 4
  int bm = bm0 + rr / 8, bn = bn0 + rr % 8;
  int wm = w >> 2, wn = w & 3;
  const int K = 1024;
  const int NT = 16, NI = 8;

  f32x4 acc[8][4];
#pragma unroll
  for (int m = 0; m < 8; m++)
#pragma unroll
    for (int n = 0; n < 4; n++) acc[m][n] = (f32x4){0.f, 0.f, 0.f, 0.f};

  s16x8 af[4][2];
  s16x8 bfr[4][2];

  auto stage = [&](int mat, int kt, int hf) {
    if (kt >= NT) return;
    int d = kt & 1;
    const bfu* s0 = (mat == 0) ? A : Bt;
    int rowbase = ((mat == 0) ? bm : bn) * 256 + hf * 128;
    int k0 = kt << 6;
    char* base = lds + d * 65536 + mat * 32768 + hf * 16384;
#pragma unroll
    for (int r = 0; r < 2; r++) {
      int L = r * 512 + tid;
      int row = L >> 3, cc = L & 7;
      int kc = cc ^ (row & 7);
      const bfu* src = s0 + (size_t)(rowbase + row) * K + k0 + kc * 8;
      char* dst = base + r * 8192 + w * 1024;
      __builtin_amdgcn_global_load_lds((AS1q)src, (AS3q)dst, 16, 0, 0);
    }
  };

  auto ldA = [&](int d, int mh) {
    const char* base = lds + d * 65536 + wm * 16384;
#pragma unroll
    for (int mm = 0; mm < 4; mm++) {
      int row = mh * 64 + mm * 16 + l15;
#pragma unroll
      for (int ks = 0; ks < 2; ks++)
        af[mm][ks] = *reinterpret_cast<const s16x8*>(
            base + row * 128 + (((ks * 4 + g) ^ (row & 7)) << 4));
    }
  };
  auto ldB2 = [&](int d, int nh) {
    const char* base = lds + d * 65536 + 32768 + (wn >> 1) * 16384;
#pragma unroll
    for (int nn = 0; nn < 2; nn++) {
      int row = (wn & 1) * 64 + (nh * 2 + nn) * 16 + l15;
#pragma unroll
      for (int ks = 0; ks < 2; ks++)
        bfr[nh * 2 + nn][ks] = *reinterpret_cast<const s16x8*>(
            base + row * 128 + (((ks * 4 + g) ^ (row & 7)) << 4));
    }
  };
  auto mfma_q = [&](int mh, int nh) {
    asm volatile("s_waitcnt lgkmcnt(0)" ::: "memory");
    __builtin_amdgcn_sched_barrier(0);
    __builtin_amdgcn_s_barrier();
    __builtin_amdgcn_s_setprio(1);
#pragma unroll
    for (int mm = 0; mm < 4; mm++)
#pragma unroll
      for (int nn = 0; nn < 2; nn++) {
        int n = nh * 2 + nn, m = mh * 4 + mm;
#pragma unroll
        for (int ks = 0; ks < 2; ks++)
          acc[m][n] = __builtin_amdgcn_mfma_f32_16x16x32_bf16(af[mm][ks], bfr[n][ks], acc[m][n], 0, 0, 0);
      }
    __builtin_amdgcn_s_setprio(0);
    __builtin_amdgcn_sched_barrier(0);
  };

  stage(1, 0, 0); stage(0, 0, 0); stage(0, 0, 1); stage(1, 0, 1);
  stage(1, 1, 0); stage(1, 1, 1);
  asm volatile("s_waitcnt vmcnt(4)" ::: "memory");
  __builtin_amdgcn_s_barrier();
  __builtin_amdgcn_sched_barrier(0);

  for (int i = 0; i < NI; i++) {
    int t0 = 2 * i, t1 = 2 * i + 1;
    bool last = (i == NI - 1);
    ldA(0, 0); ldB2(0, 0);
    stage(0, t1, 0);
    mfma_q(0, 0);
    ldB2(0, 1);
    stage(0, t1, 1);
    mfma_q(0, 1);
    ldA(0, 1);
    stage(1, t0 + 2, 0);
    mfma_q(1, 0);
    stage(1, t0 + 2, 1);
    mfma_q(1, 1);
    if (last) { asm volatile("s_waitcnt vmcnt(0)" ::: "memory"); }
    else      { asm volatile("s_waitcnt vmcnt(4)" ::: "memory"); }
    __builtin_amdgcn_s_barrier();
    __builtin_amdgcn_sched_barrier(0);
    ldA(1, 0); ldB2(1, 0);
    stage(0, t0 + 2, 0);
    mfma_q(0, 0);
    ldB2(1, 1);
    stage(0, t0 + 2, 1);
    mfma_q(0, 1);
    ldA(1, 1);
    stage(1, t1 + 2, 0);
    mfma_q(1, 0);
    stage(1, t1 + 2, 1);
    mfma_q(1, 1);
    asm volatile("s_waitcnt vmcnt(4)" ::: "memory");
    __builtin_amdgcn_s_barrier();
    __builtin_amdgcn_sched_barrier(0);
  }

  // epilogue (silu fused, packed)
  int j0 = (bn * 8 + wn * 2) * 16 + l15;
  float bx0 = bias[j0], bg0 = bias[j0 + 4096];
  float bx1 = bias[j0 + 16], bg1 = bias[j0 + 16 + 4096];
  int cb = (bn * 4 + wn) * 32 + 2 * l15;
#pragma unroll
  for (int m = 0; m < 8; m++) {
#pragma unroll
    for (int r = 0; r < 4; r++) {
      int row = bm * 256 + wm * 128 + m * 16 + g * 4 + r;
      float xh0 = acc[m][0][r] + bx0, gt0 = acc[m][1][r] + bg0;
      float xh1 = acc[m][2][r] + bx1, gt1 = acc[m][3][r] + bg1;
      float s0 = gt0 / (1.0f + __expf(-gt0)) * xh0;
      float s1 = gt1 / (1.0f + __expf(-gt1)) * xh1;
      unsigned int pk = (unsigned int)f2bf(s0) | ((unsigned int)f2bf(s1) << 16);
      *reinterpret_cast<unsigned int*>(AB + (size_t)row * 5120 + cb) = pk;
    }
  }
}

// ============ 128x128 GEMM, BK=32, 3-stage pipeline, 4 waves, 3 blocks/CU (proj) ============
__global__ __launch_bounds__(256, 3) void gemm128p(const bfu* __restrict__ A, const bfu* __restrict__ Bt,
                                                   bfu* __restrict__ qb, bfu* __restrict__ kb,
                                                   bfu* __restrict__ vT,
                                                   bfu* __restrict__ bqh, bfu* __restrict__ bkh,
                                                   const bfu* __restrict__ ct, const bfu* __restrict__ st,
                                                   int M, int N, int K, int rbm, int rbn) {
  __shared__ __align__(16) char lds[49152];
  int nbx = N >> 7;
  int c = blockIdx.x & 7, rr = blockIdx.x >> 3;
  int ca = nbx / rbn;
  int bn0 = (c % ca) * rbn, bm0 = (c / ca) * rbm;
  int bm = bm0 + rr / rbn, bn = bn0 + rr % rbn;
  int tid = threadIdx.x, w = tid >> 6, lane = tid & 63;
  int wm = w >> 1, wn = w & 1;
  int g = lane >> 4, l15 = lane & 15;
  int NT = K >> 5;

  f32x4 acc[4][4];
#pragma unroll
  for (int m = 0; m < 4; m++)
#pragma unroll
    for (int n = 0; n < 4; n++) acc[m][n] = (f32x4){0.f, 0.f, 0.f, 0.f};

  auto stage = [&](int buf, int t) {
    int k0 = t << 5;
#pragma unroll
    for (int r = 0; r < 2; r++) {
      int L = r * 256 + tid;
      int row = L >> 2, cc = L & 3;
      int kc = cc ^ (row & 3);
      const bfu* srcA = A + (size_t)(bm * 128 + row) * K + k0 + kc * 8;
      char* dstA = lds + buf * 16384 + r * 4096 + w * 1024;
      __builtin_amdgcn_global_load_lds((AS1q)srcA, (AS3q)dstA, 16, 0, 0);
      const bfu* srcB = Bt + (size_t)(bn * 128 + row) * K + k0 + kc * 8;
      char* dstB = lds + buf * 16384 + 8192 + r * 4096 + w * 1024;
      __builtin_amdgcn_global_load_lds((AS1q)srcB, (AS3q)dstB, 16, 0, 0);
    }
  };

  stage(0, 0); stage(1, 1);
  asm volatile("s_waitcnt vmcnt(4)" ::: "memory");
  __builtin_amdgcn_s_barrier();
  __builtin_amdgcn_sched_barrier(0);

  int bc = 0;
  for (int t = 0; t < NT; t++) {
    int bs = bc + 2; if (bs >= 3) bs -= 3;
    if (t + 2 < NT) stage(bs, t + 2);
    const char* la = lds + bc * 16384;
    const char* lb = la + 8192;
    s16x8 af[4], bfr[4];
#pragma unroll
    for (int m = 0; m < 4; m++) {
      int row = wm * 64 + m * 16 + l15;
      af[m] = *reinterpret_cast<const s16x8*>(la + row * 64 + ((g ^ (row & 3)) << 4));
    }
#pragma unroll
    for (int n = 0; n < 4; n++) {
      int row = wn * 64 + n * 16 + l15;
      bfr[n] = *reinterpret_cast<const s16x8*>(lb + row * 64 + ((g ^ (row & 3)) << 4));
    }
    asm volatile("s_waitcnt lgkmcnt(0)" ::: "memory");
    __builtin_amdgcn_sched_barrier(0);
    __builtin_amdgcn_s_setprio(1);
#pragma unroll
    for (int m = 0; m < 4; m++)
#pragma unroll
      for (int n = 0; n < 4; n++)
        acc[m][n] = __builtin_amdgcn_mfma_f32_16x16x32_bf16(af[m], bfr[n], acc[m][n], 0, 0, 0);
    __builtin_amdgcn_s_setprio(0);
    __builtin_amdgcn_sched_barrier(0);
    if (t < NT - 2) { asm volatile("s_waitcnt vmcnt(4)" ::: "memory"); }
    else            { asm volatile("s_waitcnt vmcnt(0)" ::: "memory"); }
    __builtin_amdgcn_s_barrier();
    __builtin_amdgcn_sched_barrier(0);
    bc++; if (bc == 3) bc = 0;
  }

  int which = bn >> 3;               // 0 q | 1 k | 2 v | 3 bq | 4 bk
  int hh = (bn & 7) * 2 + wn;
  if (which == 2) {
    bfu* lv = reinterpret_cast<bfu*>(lds);
#pragma unroll
    for (int m = 0; m < 4; m++) {
#pragma unroll
      for (int r = 0; r < 4; r++) {
        int sl = wm * 64 + m * 16 + g * 4 + r;
#pragma unroll
        for (int j = 0; j < 4; j++) {
          int d = j * 16 + l15;
          lv[(wn * 64 + d) * 136 + sl] = f2bf(acc[m][j][r]);
        }
      }
    }
    __syncthreads();
    int b = bm >> 3, h0 = (bn & 7) * 2;
#pragma unroll
    for (int i = 0; i < 8; i++) {
      int linear = i * 256 + tid;
      int hw = linear >> 10, rem = linear & 1023;
      int d = rem >> 4, sl8 = (rem & 15) << 3;
      s16x8 v8 = *reinterpret_cast<const s16x8*>(&lv[(hw * 64 + d) * 136 + sl8]);
      size_t dstofs = (((size_t)((b << 4) + h0 + hw) << 6) + d) * 1024 + (bm & 7) * 128 + sl8;
      *reinterpret_cast<s16x8*>(vT + dstofs) = v8;
    }
  } else {
#pragma unroll
    for (int m = 0; m < 4; m++) {
#pragma unroll
      for (int r = 0; r < 4; r++) {
        int row = bm * 128 + wm * 64 + m * 16 + g * 4 + r;
        int s = row & 1023, b = row >> 10;
        float a0 = acc[m][0][r], a1 = acc[m][1][r];
        float a2 = acc[m][2][r], a3 = acc[m][3][r];
        float ss = a0 * a0 + a1 * a1 + a2 * a2 + a3 * a3;
        ss += __shfl_xor(ss, 1); ss += __shfl_xor(ss, 2);
        ss += __shfl_xor(ss, 4); ss += __shfl_xor(ss, 8);
        float inv = 1.0f / fmaxf(sqrtf(ss), 1e-12f);
        float xn0 = a0 * inv, xn1 = a1 * inv, xn2 = a2 * inv, xn3 = a3 * inv;
        float c0 = bf2f(ct[(s << 5) + l15]),      s0v = bf2f(st[(s << 5) + l15]);
        float c1 = bf2f(ct[(s << 5) + 16 + l15]), s1v = bf2f(st[(s << 5) + 16 + l15]);
        float o0 = xn0 * c0 + xn2 * s0v;
        float o1 = xn1 * c1 + xn3 * s1v;
        float o2 = xn2 * c0 - xn0 * s0v;
        float o3 = xn3 * c1 - xn1 * s1v;
        unsigned long long pk =
            (unsigned long long)((unsigned int)f2bf(o0) | ((unsigned int)f2bf(o1) << 16)) |
            ((unsigned long long)((unsigned int)f2bf(o2) | ((unsigned int)f2bf(o3) << 16)) << 32);
        size_t base = ((((size_t)((b << 4) + hh) << 10) + s) << 6) + (l15 << 2);
        bfu* dst = (which == 0) ? qb : (which == 1) ? kb : (which == 3) ? bqh : bkh;
        *reinterpret_cast<unsigned long long*>(dst + base) = pk;
      }
    }
  }
}

// ============ final GEMM: 128x128 tile, BK=64, 3-stage pipeline, 4 waves (R13-proven) ============
__global__ __launch_bounds__(256, 3) void gemm128f(const bfu* __restrict__ A, const bfu* __restrict__ Bt,
                                                   float* __restrict__ out,
                                                   const float* __restrict__ b1,
                                                   const float* __restrict__ b2,
                                                   const float* __restrict__ lam,
                                                   const float* __restrict__ h,
                                                   int M, int N, int K, int rbm, int rbn) {
  __shared__ __align__(16) char lds[98304];  // 3 x (A 16KB | B 16KB)
  int nbx = N >> 7;
  int c = blockIdx.x & 7, rr = blockIdx.x >> 3;
  int ca = nbx / rbn;
  int bn0 = (c % ca) * rbn, bm0 = (c / ca) * rbm;
  int bm = bm0 + rr / rbn, bn = bn0 + rr % rbn;
  int tid = threadIdx.x, w = tid >> 6, lane = tid & 63;
  int wm = w >> 1, wn = w & 1;
  int g = lane >> 4, l15 = lane & 15;
  int NT = K >> 6;   // BK=64 -> 80 iters

  f32x4 acc[4][4];
#pragma unroll
  for (int m = 0; m < 4; m++)
#pragma unroll
    for (int n = 0; n < 4; n++) acc[m][n] = (f32x4){0.f, 0.f, 0.f, 0.f};

  auto stage = [&](int buf, int t) {
    int k0 = t << 6;
#pragma unroll
    for (int r = 0; r < 4; r++) {
      int L = r * 256 + tid;
      int row = L >> 3, cc = L & 7;
      int kc = cc ^ (row & 7);
      const bfu* srcA = A + (size_t)(bm * 128 + row) * K + k0 + kc * 8;
      char* dstA = lds + buf * 32768 + r * 4096 + w * 1024;
      __builtin_amdgcn_global_load_lds((AS1q)srcA, (AS3q)dstA, 16, 0, 0);
    }
#pragma unroll
    for (int r = 0; r < 4; r++) {
      int L = r * 256 + tid;
      int row = L >> 3, cc = L & 7;
      int kc = cc ^ (row & 7);
      const bfu* srcB = Bt + (size_t)(bn * 128 + row) * K + k0 + kc * 8;
      char* dstB = lds + buf * 32768 + 16384 + r * 4096 + w * 1024;
      __builtin_amdgcn_global_load_lds((AS1q)srcB, (AS3q)dstB, 16, 0, 0);
    }
  };

  stage(0, 0); stage(1, 1);
  asm volatile("s_waitcnt vmcnt(8)" ::: "memory");
  __builtin_amdgcn_s_barrier();
  __builtin_amdgcn_sched_barrier(0);

  int bc = 0;
  for (int t = 0; t < NT; t++) {
    int bs = bc + 2; if (bs >= 3) bs -= 3;
    if (t + 2 < NT) stage(bs, t + 2);
    const char* la = lds + bc * 32768;
    const char* lb = la + 16384;
    s16x8 af[4][2], bfr[4][2];
#pragma unroll
    for (int m = 0; m < 4; m++) {
      int row = wm * 64 + m * 16 + l15;
#pragma unroll
      for (int ks = 0; ks < 2; ks++)
        af[m][ks] = *reinterpret_cast<const s16x8*>(
            la + row * 128 + (((ks * 4 + g) ^ (row & 7)) << 4));
    }
#pragma unroll
    for (int n = 0; n < 4; n++) {
      int row = wn * 64 + n * 16 + l15;
#pragma unroll
      for (int ks = 0; ks < 2; ks++)
        bfr[n][ks] = *reinterpret_cast<const s16x8*>(
            lb + row * 128 + (((ks * 4 + g) ^ (row & 7)) << 4));
    }
    asm volatile("s_waitcnt lgkmcnt(0)" ::: "memory");
    __builtin_amdgcn_sched_barrier(0);
    __builtin_amdgcn_s_setprio(1);
#pragma unroll
    for (int m = 0; m < 4; m++)
#pragma unroll
      for (int n = 0; n < 4; n++)
#pragma unroll
        for (int ks = 0; ks < 2; ks++)
          acc[m][n] = __builtin_amdgcn_mfma_f32_16x16x32_bf16(af[m][ks], bfr[n][ks], acc[m][n], 0, 0, 0);
    __builtin_amdgcn_s_setprio(0);
    __builtin_amdgcn_sched_barrier(0);
    if (t < NT - 2) { asm volatile("s_waitcnt vmcnt(8)" ::: "memory"); }
    else            { asm volatile("s_waitcnt vmcnt(0)" ::: "memory"); }
    __builtin_amdgcn_s_barrier();
    __builtin_amdgcn_sched_barrier(0);
    bc++; if (bc == 3) bc = 0;
  }

  float lv = lam[0];
#pragma unroll
  for (int m = 0; m < 4; m++) {
    int row = bm * 128 + wm * 64 + m * 16 + g * 4;
#pragma unroll
    for (int n = 0; n < 4; n++) {
      int col = bn * 128 + wn * 64 + n * 16 + l15;
      float bb = b1[col] + b2[col];
#pragma unroll
      for (int r = 0; r < 4; r++) {
        size_t o = (size_t)(row + r) * 1024 + col;
        out[o] = acc[m][n][r] + bb + lv * h[o];
      }
    }
  }
}

// ---------------- fused brow ----------------
__global__ __launch_bounds__(512) void brow_all(const bfu* __restrict__ bq, const bfu* __restrict__ bk,
                                                float* __restrict__ brow) {
  __shared__ float csums[8][64];
  int bh = blockIdx.x;
  int wave = threadIdx.x >> 6, lane = threadIdx.x & 63;
  size_t base = ((size_t)bh * 1024 + wave * 128) * 64 + lane;
  float s = 0.f;
  for (int j = 0; j < 128; j++) s += bf2f(bk[base + (size_t)j * 64]);
  csums[wave][lane] = s;
  __syncthreads();
  float p = 0.f;
  for (int cc = 0; cc < wave; cc++) p += csums[cc][lane];
  for (int j = 0; j < 128; j++) {
    p += bf2f(bk[base + (size_t)j * 64]);
    float t = bf2f(bq[base + (size_t)j * 64]) * p;
#pragma unroll
    for (int m2 = 1; m2 < 64; m2 <<= 1) t += __shfl_xor(t, m2);
    if (lane == 0) brow[bh * 1024 + wave * 128 + j] = 0.125f * t;
  }
}

// ================= host =================
extern "C" void kernel_launch(void* const* d_in, const int* in_sizes, int n_in,
                              void* d_out, int out_size, void* d_ws, size_t ws_size,
                              hipStream_t stream) {
  const float* h      = (const float*)d_in[0];
  const float* Wq     = (const float*)d_in[2];
  const float* Wk     = (const float*)d_in[3];
  const float* Wv     = (const float*)d_in[4];
  const float* WqB    = (const float*)d_in[5];
  const float* WkB    = (const float*)d_in[6];
  const float* Wo     = (const float*)d_in[7];
  const float* bo     = (const float*)d_in[8];
  const float* Wffin  = (const float*)d_in[9];
  const float* bffin  = (const float*)d_in[10];
  const float* Wffout = (const float*)d_in[11];
  const float* bffout = (const float*)d_in[12];
  const float* lam    = (const float*)d_in[13];
  const float* l2ns   = (const float*)d_in[14];
  float* out = (float*)d_out;

  char* ws = (char*)d_ws;
  size_t off = 0;
  auto alloc = [&](size_t bytes) { void* p = ws + off; off += bytes; return p; };
  bfu* wt5   = (bfu*)alloc(5ull * 1024 * 1024 * 2);
  bfu* wtfi  = (bfu*)alloc(8192ull * 1024 * 2);
  bfu* wtfoc = (bfu*)alloc(1024ull * 5120 * 2);
  bfu* cosb  = (bfu*)alloc(1024ull * 32 * 2);
  bfu* sinb  = (bfu*)alloc(1024ull * 32 * 2);
  bfu* inner = (bfu*)alloc(4096ull * 1024 * 2);
  bfu* qb    = (bfu*)alloc(64ull * 1024 * 64 * 2);
  bfu* kb    = (bfu*)alloc(64ull * 1024 * 64 * 2);
  bfu* vtb   = (bfu*)alloc(64ull * 1024 * 64 * 2);
  bfu* bqh   = (bfu*)alloc(64ull * 1024 * 64 * 2);
  bfu* bkh   = (bfu*)alloc(64ull * 1024 * 64 * 2);
  float* browb = (float*)alloc(64ull * 1024 * 4);
  bfu* AB    = (bfu*)alloc(4096ull * 5120 * 2);

  // fused prologue
  PreArgs pa;
  pa.w5[0] = Wq; pa.w5[1] = Wk; pa.w5[2] = Wv; pa.w5[3] = WqB; pa.w5[4] = WkB;
  pa.Wffin = Wffin; pa.Wffout = Wffout; pa.Wo = Wo; pa.h = h;
  pa.wt5 = wt5; pa.wtfi = wtfi; pa.wtfoc = wtfoc;
  pa.cosb = cosb; pa.sinb = sinb; pa.inner = inner;
  prologue_k<<<dim3(22656), 256, 0, stream>>>(pa);

  // proj + l2norm/rope + in-LDS v-transpose epilogue
  gemm128p<<<dim3(1280), 256, 0, stream>>>(inner, wt5, qb, kb, vtb, bqh, bkh, cosb, sinb,
                                           4096, 5120, 1024, 32, 5);

  brow_all<<<dim3(64), 512, 0, stream>>>(bqh, bkh, browb);

  // fused flash (blocks 0..255) + FF-in (blocks 256..767)
  fused_k<<<dim3(768), 512, 0, stream>>>(qb, kb, vtb, browb, l2ns,
                                         inner, wtfi, AB, bffin);

  // final merged GEMM (128^2, BK=64, 3-stage)
  gemm128f<<<dim3(256), 256, 0, stream>>>(AB, wtfoc, out, bffout, bo, lam, h,
                                          4096, 1024, 5120, 8, 4);
}

// Round 19
// 303.552 us; speedup vs baseline: 1.0644x; 1.0072x over previous
//
#include <hip/hip_runtime.h>
#include <stdint.h>
#include <math.h>

typedef float f32x4 __attribute__((ext_vector_type(4)));
typedef short s16x8 __attribute__((ext_vector_type(8)));
typedef unsigned short bfu;

#define AS1q const __attribute__((address_space(1))) void*
#define AS3q __attribute__((address_space(3))) void*

static __device__ __forceinline__ float bf2f(bfu v) {
  return __uint_as_float(((unsigned int)v) << 16);
}
static __device__ __forceinline__ bfu f2bf(float f) {
  unsigned int u = __float_as_uint(f);
  return (bfu)((u + 0x7fffu + ((u >> 16) & 1u)) >> 16);
}

// ================= fused prologue: all weight converts + rope tables + rmsnorm =================
struct PreArgs {
  const float* w5[5];
  const float* Wffin;
  const float* Wffout;
  const float* Wo;
  const float* h;
  bfu* wt5; bfu* wtfi; bfu* wtfoc;
  bfu* cosb; bfu* sinb; bfu* inner;
};
__global__ __launch_bounds__(256) void prologue_k(PreArgs a) {
  __shared__ float shmem[32 * 33];
  int id = blockIdx.x;
  if (id < 18432) {
    const float* W; bfu* Wt; int K, N, dstride, dofs, mode, nb, kb;
    if (id < 5120) {
      int z = id >> 10, rem = id & 1023;
      W = a.w5[z]; Wt = a.wt5 + ((size_t)z << 20);
      K = 1024; N = 1024; dstride = 1024; dofs = 0; mode = 0;
      nb = (rem & 31) << 5; kb = (rem >> 5) << 5;
    } else if (id < 13312) {
      int id2 = id - 5120;
      W = a.Wffin; Wt = a.wtfi; K = 1024; N = 8192; dstride = 1024; dofs = 0; mode = 1;
      nb = (id2 & 255) << 5; kb = (id2 >> 8) << 5;
    } else if (id < 17408) {
      int id3 = id - 13312;
      W = a.Wffout; Wt = a.wtfoc; K = 4096; N = 1024; dstride = 5120; dofs = 0; mode = 2;
      nb = (id3 & 31) << 5; kb = (id3 >> 5) << 5;
    } else {
      int id4 = id - 17408;
      W = a.Wo; Wt = a.wtfoc; K = 1024; N = 1024; dstride = 5120; dofs = 4096; mode = 2;
      nb = (id4 & 31) << 5; kb = (id4 >> 5) << 5;
    }
    float (*t)[33] = reinterpret_cast<float(*)[33]>(shmem);
    int tx = threadIdx.x & 31, ty = threadIdx.x >> 5;
#pragma unroll
    for (int i = 0; i < 4; i++) {
      int r = ty + i * 8;
      t[r][tx] = W[(size_t)(kb + r) * N + nb + tx];
    }
    __syncthreads();
#pragma unroll
    for (int i = 0; i < 4; i++) {
      int r = ty + i * 8;
      int n = nb + r;
      int nd = n;
      if (mode == 1) { int j = n & 4095, isg = n >> 12; nd = ((j >> 4) << 5) | (isg << 4) | (j & 15); }
      int k = kb + tx;
      int kp = (mode == 2) ? (((k >> 5) << 5) | ((k & 15) << 1) | ((k >> 4) & 1)) : k;
      Wt[(size_t)nd * dstride + dofs + kp] = f2bf(t[tx][r]);
    }
  } else if (id < 18560) {
    int idx = (id - 18432) * 256 + threadIdx.x;
    int s = idx >> 5, i = idx & 31;
    float f = powf(1000.0f, -(float)i / 32.0f);
    float fr = (float)s * f;
    a.cosb[idx] = f2bf(cosf(fr));
    a.sinb[idx] = f2bf(sinf(fr));
  } else {
    int row = id - 18560;
    const float* hr = a.h + (size_t)row * 1024;
    f32x4 x = *reinterpret_cast<const f32x4*>(hr + threadIdx.x * 4);
    float ss = x[0] * x[0] + x[1] * x[1] + x[2] * x[2] + x[3] * x[3];
    for (int off = 32; off; off >>= 1) ss += __shfl_down(ss, off);
    int wave = threadIdx.x >> 6, lane = threadIdx.x & 63;
    if (lane == 0) shmem[wave] = ss;
    __syncthreads();
    float tot = shmem[0] + shmem[1] + shmem[2] + shmem[3];
    float r = rsqrtf(tot * (1.0f / 1024.0f) + 1.1920929e-07f);
    bfu* o = a.inner + (size_t)row * 1024 + threadIdx.x * 4;
    o[0] = f2bf(x[0] * r); o[1] = f2bf(x[1] * r);
    o[2] = f2bf(x[2] * r); o[3] = f2bf(x[3] * r);
  }
}

// ============ fused dispatch: flash (blocks 0..255, 2 sub-blocks/block) + FF-in (256..767) ============
__global__ __launch_bounds__(512, 2) void fused_k(const bfu* __restrict__ q, const bfu* __restrict__ k,
                                                  const bfu* __restrict__ vT,
                                                  const float* __restrict__ brow,
                                                  const float* __restrict__ l2p,
                                                  const bfu* __restrict__ A, const bfu* __restrict__ Bt,
                                                  bfu* __restrict__ AB,
                                                  const float* __restrict__ bias) {
  __shared__ __align__(16) char lds[131072];
  int tid = threadIdx.x, w = tid >> 6, lane = tid & 63;
  int g = lane >> 4, l15 = lane & 15;

  if (blockIdx.x < 256) {
    // ================== flash: waves 0-3 -> fid, waves 4-7 -> fid+256 (balanced pair) ==================
    int fid = blockIdx.x + ((w >> 2) << 8);
    int sub = fid & 255;
    int qt = (fid >> 8) ? 7 - (sub >> 6) : (sub >> 6);
    int bh = sub & 63;
    const size_t bhofs = (size_t)bh << 16;
    int rt0 = qt * 128 + (w & 3) * 32;
    bfu* P = reinterpret_cast<bfu*>(lds) + (size_t)w * (2 * 16 * 72);   // per-wave P slice

    s16x8 aq[2][2];
#pragma unroll
    for (int m = 0; m < 2; m++)
#pragma unroll
      for (int ks = 0; ks < 2; ks++)
        aq[m][ks] = *reinterpret_cast<const s16x8*>(
            q + bhofs + (size_t)(rt0 + m * 16 + l15) * 64 + ks * 32 + g * 8);

    f32x4 O[2][4];
    float mr[2][4], lr[2][4];
#pragma unroll
    for (int m = 0; m < 2; m++)
#pragma unroll
      for (int r = 0; r < 4; r++) { O[m][r] = (f32x4){0.f, 0.f, 0.f, 0.f}; mr[m][r] = -3.0e38f; lr[m][r] = 0.f; }

    s16x8 kA[4][2], kB[4][2];
    auto loadK = [&](s16x8 (&kd)[4][2], int jt) {
#pragma unroll
      for (int nt = 0; nt < 4; nt++)
#pragma unroll
        for (int ks = 0; ks < 2; ks++)
          kd[nt][ks] = *reinterpret_cast<const s16x8*>(
              k + bhofs + (size_t)(jt * 64 + nt * 16 + l15) * 64 + ks * 32 + g * 8);
    };

    int njt = 2 * qt + 2;
    loadK(kA, 0);

    auto body = [&](int jt, s16x8 (&kc)[4][2], s16x8 (&kn)[4][2], bool pf) {
      s16x8 vv[4][2];
#pragma unroll
      for (int nt = 0; nt < 4; nt++)
#pragma unroll
        for (int ks = 0; ks < 2; ks++)
          vv[nt][ks] = *reinterpret_cast<const s16x8*>(
              vT + ((size_t)(bh * 64 + nt * 16 + l15) << 10) + jt * 64 + ks * 32 + g * 8);

      bool act[2] = { jt * 64 <= rt0 + 15, jt * 64 <= rt0 + 31 };
      f32x4 sfr[2][4];
#pragma unroll
      for (int m = 0; m < 2; m++) {
        if (!act[m]) continue;
#pragma unroll
        for (int nt = 0; nt < 4; nt++) {
          sfr[m][nt] = (f32x4){0.f, 0.f, 0.f, 0.f};
#pragma unroll
          for (int ks = 0; ks < 2; ks++)
            sfr[m][nt] = __builtin_amdgcn_mfma_f32_16x16x32_bf16(aq[m][ks], kc[nt][ks], sfr[m][nt], 0, 0, 0);
        }
      }
      if (pf) loadK(kn, jt + 1);

#pragma unroll
      for (int m = 0; m < 2; m++) {
        if (!act[m]) continue;
        int rtm = rt0 + m * 16;
        if (jt * 64 + 63 > rtm) {
#pragma unroll
          for (int ntn = 0; ntn < 4; ntn++)
#pragma unroll
            for (int r = 0; r < 4; r++)
              if (jt * 64 + ntn * 16 + l15 > rtm + g * 4 + r) sfr[m][ntn][r] = -1e30f;
        }
        float alpha[4];
#pragma unroll
        for (int r = 0; r < 4; r++) {
          float v = fmaxf(fmaxf(sfr[m][0][r], sfr[m][1][r]), fmaxf(sfr[m][2][r], sfr[m][3][r]));
#pragma unroll
          for (int m2 = 1; m2 < 16; m2 <<= 1) v = fmaxf(v, __shfl_xor(v, m2));
          float mn = fmaxf(mr[m][r], v);
          alpha[r] = __expf(mr[m][r] - mn);
          mr[m][r] = mn;
        }
#pragma unroll
        for (int r = 0; r < 4; r++) {
          float rs = 0.f;
#pragma unroll
          for (int ntn = 0; ntn < 4; ntn++) {
            float e = __expf(sfr[m][ntn][r] - mr[m][r]);
            rs += e;
            P[(m * 16 + g * 4 + r) * 72 + ntn * 16 + l15] = f2bf(e);
          }
#pragma unroll
          for (int m2 = 1; m2 < 16; m2 <<= 1) rs += __shfl_xor(rs, m2);
          lr[m][r] = lr[m][r] * alpha[r] + rs;
#pragma unroll
          for (int ntn = 0; ntn < 4; ntn++) O[m][ntn][r] *= alpha[r];
        }
      }
      asm volatile("s_waitcnt lgkmcnt(0)" ::: "memory");
      __builtin_amdgcn_sched_barrier(0);
#pragma unroll
      for (int m = 0; m < 2; m++) {
        if (!act[m]) continue;
        s16x8 pa[2];
#pragma unroll
        for (int ks = 0; ks < 2; ks++)
          pa[ks] = *reinterpret_cast<const s16x8*>(&P[(m * 16 + l15) * 72 + ks * 32 + g * 8]);
#pragma unroll
        for (int nt = 0; nt < 4; nt++)
#pragma unroll
          for (int ks = 0; ks < 2; ks++)
            O[m][nt] = __builtin_amdgcn_mfma_f32_16x16x32_bf16(pa[ks], vv[nt][ks], O[m][nt], 0, 0, 0);
      }
    };

    for (int jt = 0; jt < njt; jt += 2) {
      body(jt, kA, kB, true);
      body(jt + 1, kB, kA, jt + 2 < njt);
    }

    float l2ns = l2p[0];
    int b = bh >> 4, hq = bh & 15;
#pragma unroll
    for (int m = 0; m < 2; m++)
#pragma unroll
      for (int r = 0; r < 4; r++) {
        int rowg = rt0 + m * 16 + g * 4 + r;
        float br = brow[bh * 1024 + rowg];
        float sc = l2ns / lr[m][r];
        float v0 = O[m][0][r] * sc + br;
        float v1 = O[m][1][r] * sc + br;
        float v2 = O[m][2][r] * sc + br;
        float v3 = O[m][3][r] * sc + br;
        unsigned int p01 = (unsigned int)f2bf(v0) | ((unsigned int)f2bf(v1) << 16);
        unsigned int p23 = (unsigned int)f2bf(v2) | ((unsigned int)f2bf(v3) << 16);
        size_t base = (size_t)(b * 1024 + rowg) * 5120 + 4096 + hq * 64;
        *reinterpret_cast<unsigned int*>(AB + base + 2 * l15) = p01;
        *reinterpret_cast<unsigned int*>(AB + base + 32 + 2 * l15) = p23;
      }
    return;
  }

  // ================== FF-in: 256x256, BK=64, 2-dbuf, counted vmcnt (R8 order) ==================
  int id0 = blockIdx.x - 256;
  int c = id0 & 7, rr = id0 >> 3;
  int bn0 = (c & 3) * 8, bm0 = (c >> 2) * 8;   // ca = 32/8 = 4
  int bm = bm0 + rr / 8, bn = bn0 + rr % 8;
  int wm = w >> 2, wn = w & 3;
  const int K = 1024;
  const int NT = 16, NI = 8;

  f32x4 acc[8][4];
#pragma unroll
  for (int m = 0; m < 8; m++)
#pragma unroll
    for (int n = 0; n < 4; n++) acc[m][n] = (f32x4){0.f, 0.f, 0.f, 0.f};

  s16x8 af[4][2];
  s16x8 bfr[4][2];

  auto stage = [&](int mat, int kt, int hf) {
    if (kt >= NT) return;
    int d = kt & 1;
    const bfu* s0 = (mat == 0) ? A : Bt;
    int rowbase = ((mat == 0) ? bm : bn) * 256 + hf * 128;
    int k0 = kt << 6;
    char* base = lds + d * 65536 + mat * 32768 + hf * 16384;
#pragma unroll
    for (int r = 0; r < 2; r++) {
      int L = r * 512 + tid;
      int row = L >> 3, cc = L & 7;
      int kc = cc ^ (row & 7);
      const bfu* src = s0 + (size_t)(rowbase + row) * K + k0 + kc * 8;
      char* dst = base + r * 8192 + w * 1024;
      __builtin_amdgcn_global_load_lds((AS1q)src, (AS3q)dst, 16, 0, 0);
    }
  };

  auto ldA = [&](int d, int mh) {
    const char* base = lds + d * 65536 + wm * 16384;
#pragma unroll
    for (int mm = 0; mm < 4; mm++) {
      int row = mh * 64 + mm * 16 + l15;
#pragma unroll
      for (int ks = 0; ks < 2; ks++)
        af[mm][ks] = *reinterpret_cast<const s16x8*>(
            base + row * 128 + (((ks * 4 + g) ^ (row & 7)) << 4));
    }
  };
  auto ldB2 = [&](int d, int nh) {
    const char* base = lds + d * 65536 + 32768 + (wn >> 1) * 16384;
#pragma unroll
    for (int nn = 0; nn < 2; nn++) {
      int row = (wn & 1) * 64 + (nh * 2 + nn) * 16 + l15;
#pragma unroll
      for (int ks = 0; ks < 2; ks++)
        bfr[nh * 2 + nn][ks] = *reinterpret_cast<const s16x8*>(
            base + row * 128 + (((ks * 4 + g) ^ (row & 7)) << 4));
    }
  };
  auto mfma_q = [&](int mh, int nh) {
    asm volatile("s_waitcnt lgkmcnt(0)" ::: "memory");
    __builtin_amdgcn_sched_barrier(0);
    __builtin_amdgcn_s_barrier();
    __builtin_amdgcn_s_setprio(1);
#pragma unroll
    for (int mm = 0; mm < 4; mm++)
#pragma unroll
      for (int nn = 0; nn < 2; nn++) {
        int n = nh * 2 + nn, m = mh * 4 + mm;
#pragma unroll
        for (int ks = 0; ks < 2; ks++)
          acc[m][n] = __builtin_amdgcn_mfma_f32_16x16x32_bf16(af[mm][ks], bfr[n][ks], acc[m][n], 0, 0, 0);
      }
    __builtin_amdgcn_s_setprio(0);
    __builtin_amdgcn_sched_barrier(0);
  };

  stage(1, 0, 0); stage(0, 0, 0); stage(0, 0, 1); stage(1, 0, 1);
  stage(1, 1, 0); stage(1, 1, 1);
  asm volatile("s_waitcnt vmcnt(4)" ::: "memory");
  __builtin_amdgcn_s_barrier();
  __builtin_amdgcn_sched_barrier(0);

  for (int i = 0; i < NI; i++) {
    int t0 = 2 * i, t1 = 2 * i + 1;
    bool last = (i == NI - 1);
    ldA(0, 0); ldB2(0, 0);
    stage(0, t1, 0);
    mfma_q(0, 0);
    ldB2(0, 1);
    stage(0, t1, 1);
    mfma_q(0, 1);
    ldA(0, 1);
    stage(1, t0 + 2, 0);
    mfma_q(1, 0);
    stage(1, t0 + 2, 1);
    mfma_q(1, 1);
    if (last) { asm volatile("s_waitcnt vmcnt(0)" ::: "memory"); }
    else      { asm volatile("s_waitcnt vmcnt(4)" ::: "memory"); }
    __builtin_amdgcn_s_barrier();
    __builtin_amdgcn_sched_barrier(0);
    ldA(1, 0); ldB2(1, 0);
    stage(0, t0 + 2, 0);
    mfma_q(0, 0);
    ldB2(1, 1);
    stage(0, t0 + 2, 1);
    mfma_q(0, 1);
    ldA(1, 1);
    stage(1, t1 + 2, 0);
    mfma_q(1, 0);
    stage(1, t1 + 2, 1);
    mfma_q(1, 1);
    asm volatile("s_waitcnt vmcnt(4)" ::: "memory");
    __builtin_amdgcn_s_barrier();
    __builtin_amdgcn_sched_barrier(0);
  }

  // epilogue (silu fused, packed)
  int j0 = (bn * 8 + wn * 2) * 16 + l15;
  float bx0 = bias[j0], bg0 = bias[j0 + 4096];
  float bx1 = bias[j0 + 16], bg1 = bias[j0 + 16 + 4096];
  int cb = (bn * 4 + wn) * 32 + 2 * l15;
#pragma unroll
  for (int m = 0; m < 8; m++) {
#pragma unroll
    for (int r = 0; r < 4; r++) {
      int row = bm * 256 + wm * 128 + m * 16 + g * 4 + r;
      float xh0 = acc[m][0][r] + bx0, gt0 = acc[m][1][r] + bg0;
      float xh1 = acc[m][2][r] + bx1, gt1 = acc[m][3][r] + bg1;
      float s0 = gt0 / (1.0f + __expf(-gt0)) * xh0;
      float s1 = gt1 / (1.0f + __expf(-gt1)) * xh1;
      unsigned int pk = (unsigned int)f2bf(s0) | ((unsigned int)f2bf(s1) << 16);
      *reinterpret_cast<unsigned int*>(AB + (size_t)row * 5120 + cb) = pk;
    }
  }
}

// ============ 128x128 GEMM, BK=32, 3-stage pipeline, 4 waves, 3 blocks/CU (proj) ============
__global__ __launch_bounds__(256, 3) void gemm128p(const bfu* __restrict__ A, const bfu* __restrict__ Bt,
                                                   bfu* __restrict__ qb, bfu* __restrict__ kb,
                                                   bfu* __restrict__ vT,
                                                   bfu* __restrict__ bqh, bfu* __restrict__ bkh,
                                                   const bfu* __restrict__ ct, const bfu* __restrict__ st,
                                                   int M, int N, int K, int rbm, int rbn) {
  __shared__ __align__(16) char lds[49152];
  int nbx = N >> 7;
  int c = blockIdx.x & 7, rr = blockIdx.x >> 3;
  int ca = nbx / rbn;
  int bn0 = (c % ca) * rbn, bm0 = (c / ca) * rbm;
  int bm = bm0 + rr / rbn, bn = bn0 + rr % rbn;
  int tid = threadIdx.x, w = tid >> 6, lane = tid & 63;
  int wm = w >> 1, wn = w & 1;
  int g = lane >> 4, l15 = lane & 15;
  int NT = K >> 5;

  f32x4 acc[4][4];
#pragma unroll
  for (int m = 0; m < 4; m++)
#pragma unroll
    for (int n = 0; n < 4; n++) acc[m][n] = (f32x4){0.f, 0.f, 0.f, 0.f};

  auto stage = [&](int buf, int t) {
    int k0 = t << 5;
#pragma unroll
    for (int r = 0; r < 2; r++) {
      int L = r * 256 + tid;
      int row = L >> 2, cc = L & 3;
      int kc = cc ^ (row & 3);
      const bfu* srcA = A + (size_t)(bm * 128 + row) * K + k0 + kc * 8;
      char* dstA = lds + buf * 16384 + r * 4096 + w * 1024;
      __builtin_amdgcn_global_load_lds((AS1q)srcA, (AS3q)dstA, 16, 0, 0);
      const bfu* srcB = Bt + (size_t)(bn * 128 + row) * K + k0 + kc * 8;
      char* dstB = lds + buf * 16384 + 8192 + r * 4096 + w * 1024;
      __builtin_amdgcn_global_load_lds((AS1q)srcB, (AS3q)dstB, 16, 0, 0);
    }
  };

  stage(0, 0); stage(1, 1);
  asm volatile("s_waitcnt vmcnt(4)" ::: "memory");
  __builtin_amdgcn_s_barrier();
  __builtin_amdgcn_sched_barrier(0);

  int bc = 0;
  for (int t = 0; t < NT; t++) {
    int bs = bc + 2; if (bs >= 3) bs -= 3;
    if (t + 2 < NT) stage(bs, t + 2);
    const char* la = lds + bc * 16384;
    const char* lb = la + 8192;
    s16x8 af[4], bfr[4];
#pragma unroll
    for (int m = 0; m < 4; m++) {
      int row = wm * 64 + m * 16 + l15;
      af[m] = *reinterpret_cast<const s16x8*>(la + row * 64 + ((g ^ (row & 3)) << 4));
    }
#pragma unroll
    for (int n = 0; n < 4; n++) {
      int row = wn * 64 + n * 16 + l15;
      bfr[n] = *reinterpret_cast<const s16x8*>(lb + row * 64 + ((g ^ (row & 3)) << 4));
    }
    asm volatile("s_waitcnt lgkmcnt(0)" ::: "memory");
    __builtin_amdgcn_sched_barrier(0);
    __builtin_amdgcn_s_setprio(1);
#pragma unroll
    for (int m = 0; m < 4; m++)
#pragma unroll
      for (int n = 0; n < 4; n++)
        acc[m][n] = __builtin_amdgcn_mfma_f32_16x16x32_bf16(af[m], bfr[n], acc[m][n], 0, 0, 0);
    __builtin_amdgcn_s_setprio(0);
    __builtin_amdgcn_sched_barrier(0);
    if (t < NT - 2) { asm volatile("s_waitcnt vmcnt(4)" ::: "memory"); }
    else            { asm volatile("s_waitcnt vmcnt(0)" ::: "memory"); }
    __builtin_amdgcn_s_barrier();
    __builtin_amdgcn_sched_barrier(0);
    bc++; if (bc == 3) bc = 0;
  }

  int which = bn >> 3;               // 0 q | 1 k | 2 v | 3 bq | 4 bk
  int hh = (bn & 7) * 2 + wn;
  if (which == 2) {
    bfu* lv = reinterpret_cast<bfu*>(lds);
#pragma unroll
    for (int m = 0; m < 4; m++) {
#pragma unroll
      for (int r = 0; r < 4; r++) {
        int sl = wm * 64 + m * 16 + g * 4 + r;
#pragma unroll
        for (int j = 0; j < 4; j++) {
          int d = j * 16 + l15;
          lv[(wn * 64 + d) * 136 + sl] = f2bf(acc[m][j][r]);
        }
      }
    }
    __syncthreads();
    int b = bm >> 3, h0 = (bn & 7) * 2;
#pragma unroll
    for (int i = 0; i < 8; i++) {
      int linear = i * 256 + tid;
      int hw = linear >> 10, rem = linear & 1023;
      int d = rem >> 4, sl8 = (rem & 15) << 3;
      s16x8 v8 = *reinterpret_cast<const s16x8*>(&lv[(hw * 64 + d) * 136 + sl8]);
      size_t dstofs = (((size_t)((b << 4) + h0 + hw) << 6) + d) * 1024 + (bm & 7) * 128 + sl8;
      *reinterpret_cast<s16x8*>(vT + dstofs) = v8;
    }
  } else {
#pragma unroll
    for (int m = 0; m < 4; m++) {
#pragma unroll
      for (int r = 0; r < 4; r++) {
        int row = bm * 128 + wm * 64 + m * 16 + g * 4 + r;
        int s = row & 1023, b = row >> 10;
        float a0 = acc[m][0][r], a1 = acc[m][1][r];
        float a2 = acc[m][2][r], a3 = acc[m][3][r];
        float ss = a0 * a0 + a1 * a1 + a2 * a2 + a3 * a3;
        ss += __shfl_xor(ss, 1); ss += __shfl_xor(ss, 2);
        ss += __shfl_xor(ss, 4); ss += __shfl_xor(ss, 8);
        float inv = 1.0f / fmaxf(sqrtf(ss), 1e-12f);
        float xn0 = a0 * inv, xn1 = a1 * inv, xn2 = a2 * inv, xn3 = a3 * inv;
        float c0 = bf2f(ct[(s << 5) + l15]),      s0v = bf2f(st[(s << 5) + l15]);
        float c1 = bf2f(ct[(s << 5) + 16 + l15]), s1v = bf2f(st[(s << 5) + 16 + l15]);
        float o0 = xn0 * c0 + xn2 * s0v;
        float o1 = xn1 * c1 + xn3 * s1v;
        float o2 = xn2 * c0 - xn0 * s0v;
        float o3 = xn3 * c1 - xn1 * s1v;
        unsigned long long pk =
            (unsigned long long)((unsigned int)f2bf(o0) | ((unsigned int)f2bf(o1) << 16)) |
            ((unsigned long long)((unsigned int)f2bf(o2) | ((unsigned int)f2bf(o3) << 16)) << 32);
        size_t base = ((((size_t)((b << 4) + hh) << 10) + s) << 6) + (l15 << 2);
        bfu* dst = (which == 0) ? qb : (which == 1) ? kb : (which == 3) ? bqh : bkh;
        *reinterpret_cast<unsigned long long*>(dst + base) = pk;
      }
    }
  }
}

// ============ final GEMM: 128x128 tile, BK=64, 3-stage pipeline, 4 waves (R13-proven) ============
__global__ __launch_bounds__(256, 3) void gemm128f(const bfu* __restrict__ A, const bfu* __restrict__ Bt,
                                                   float* __restrict__ out,
                                                   const float* __restrict__ b1,
                                                   const float* __restrict__ b2,
                                                   const float* __restrict__ lam,
                                                   const float* __restrict__ h,
                                                   int M, int N, int K, int rbm, int rbn) {
  __shared__ __align__(16) char lds[98304];  // 3 x (A 16KB | B 16KB)
  int nbx = N >> 7;
  int c = blockIdx.x & 7, rr = blockIdx.x >> 3;
  int ca = nbx / rbn;
  int bn0 = (c % ca) * rbn, bm0 = (c / ca) * rbm;
  int bm = bm0 + rr / rbn, bn = bn0 + rr % rbn;
  int tid = threadIdx.x, w = tid >> 6, lane = tid & 63;
  int wm = w >> 1, wn = w & 1;
  int g = lane >> 4, l15 = lane & 15;
  int NT = K >> 6;   // BK=64 -> 80 iters

  f32x4 acc[4][4];
#pragma unroll
  for (int m = 0; m < 4; m++)
#pragma unroll
    for (int n = 0; n < 4; n++) acc[m][n] = (f32x4){0.f, 0.f, 0.f, 0.f};

  auto stage = [&](int buf, int t) {
    int k0 = t << 6;
#pragma unroll
    for (int r = 0; r < 4; r++) {
      int L = r * 256 + tid;
      int row = L >> 3, cc = L & 7;
      int kc = cc ^ (row & 7);
      const bfu* srcA = A + (size_t)(bm * 128 + row) * K + k0 + kc * 8;
      char* dstA = lds + buf * 32768 + r * 4096 + w * 1024;
      __builtin_amdgcn_global_load_lds((AS1q)srcA, (AS3q)dstA, 16, 0, 0);
    }
#pragma unroll
    for (int r = 0; r < 4; r++) {
      int L = r * 256 + tid;
      int row = L >> 3, cc = L & 7;
      int kc = cc ^ (row & 7);
      const bfu* srcB = Bt + (size_t)(bn * 128 + row) * K + k0 + kc * 8;
      char* dstB = lds + buf * 32768 + 16384 + r * 4096 + w * 1024;
      __builtin_amdgcn_global_load_lds((AS1q)srcB, (AS3q)dstB, 16, 0, 0);
    }
  };

  stage(0, 0); stage(1, 1);
  asm volatile("s_waitcnt vmcnt(8)" ::: "memory");
  __builtin_amdgcn_s_barrier();
  __builtin_amdgcn_sched_barrier(0);

  int bc = 0;
  for (int t = 0; t < NT; t++) {
    int bs = bc + 2; if (bs >= 3) bs -= 3;
    if (t + 2 < NT) stage(bs, t + 2);
    const char* la = lds + bc * 32768;
    const char* lb = la + 16384;
    s16x8 af[4][2], bfr[4][2];
#pragma unroll
    for (int m = 0; m < 4; m++) {
      int row = wm * 64 + m * 16 + l15;
#pragma unroll
      for (int ks = 0; ks < 2; ks++)
        af[m][ks] = *reinterpret_cast<const s16x8*>(
            la + row * 128 + (((ks * 4 + g) ^ (row & 7)) << 4));
    }
#pragma unroll
    for (int n = 0; n < 4; n++) {
      int row = wn * 64 + n * 16 + l15;
#pragma unroll
      for (int ks = 0; ks < 2; ks++)
        bfr[n][ks] = *reinterpret_cast<const s16x8*>(
            lb + row * 128 + (((ks * 4 + g) ^ (row & 7)) << 4));
    }
    asm volatile("s_waitcnt lgkmcnt(0)" ::: "memory");
    __builtin_amdgcn_sched_barrier(0);
    __builtin_amdgcn_s_setprio(1);
#pragma unroll
    for (int m = 0; m < 4; m++)
#pragma unroll
      for (int n = 0; n < 4; n++)
#pragma unroll
        for (int ks = 0; ks < 2; ks++)
          acc[m][n] = __builtin_amdgcn_mfma_f32_16x16x32_bf16(af[m][ks], bfr[n][ks], acc[m][n], 0, 0, 0);
    __builtin_amdgcn_s_setprio(0);
    __builtin_amdgcn_sched_barrier(0);
    if (t < NT - 2) { asm volatile("s_waitcnt vmcnt(8)" ::: "memory"); }
    else            { asm volatile("s_waitcnt vmcnt(0)" ::: "memory"); }
    __builtin_amdgcn_s_barrier();
    __builtin_amdgcn_sched_barrier(0);
    bc++; if (bc == 3) bc = 0;
  }

  float lv = lam[0];
#pragma unroll
  for (int m = 0; m < 4; m++) {
    int row = bm * 128 + wm * 64 + m * 16 + g * 4;
#pragma unroll
    for (int n = 0; n < 4; n++) {
      int col = bn * 128 + wn * 64 + n * 16 + l15;
      float bb = b1[col] + b2[col];
#pragma unroll
      for (int r = 0; r < 4; r++) {
        size_t o = (size_t)(row + r) * 1024 + col;
        out[o] = acc[m][n][r] + bb + lv * h[o];
      }
    }
  }
}

// ---------------- fused brow ----------------
__global__ __launch_bounds__(512) void brow_all(const bfu* __restrict__ bq, const bfu* __restrict__ bk,
                                                float* __restrict__ brow) {
  __shared__ float csums[8][64];
  int bh = blockIdx.x;
  int wave = threadIdx.x >> 6, lane = threadIdx.x & 63;
  size_t base = ((size_t)bh * 1024 + wave * 128) * 64 + lane;
  float s = 0.f;
  for (int j = 0; j < 128; j++) s += bf2f(bk[base + (size_t)j * 64]);
  csums[wave][lane] = s;
  __syncthreads();
  float p = 0.f;
  for (int cc = 0; cc < wave; cc++) p += csums[cc][lane];
  for (int j = 0; j < 128; j++) {
    p += bf2f(bk[base + (size_t)j * 64]);
    float t = bf2f(bq[base + (size_t)j * 64]) * p;
#pragma unroll
    for (int m2 = 1; m2 < 64; m2 <<= 1) t += __shfl_xor(t, m2);
    if (lane == 0) brow[bh * 1024 + wave * 128 + j] = 0.125f * t;
  }
}

// ================= host =================
extern "C" void kernel_launch(void* const* d_in, const int* in_sizes, int n_in,
                              void* d_out, int out_size, void* d_ws, size_t ws_size,
                              hipStream_t stream) {
  const float* h      = (const float*)d_in[0];
  const float* Wq     = (const float*)d_in[2];
  const float* Wk     = (const float*)d_in[3];
  const float* Wv     = (const float*)d_in[4];
  const float* WqB    = (const float*)d_in[5];
  const float* WkB    = (const float*)d_in[6];
  const float* Wo     = (const float*)d_in[7];
  const float* bo     = (const float*)d_in[8];
  const float* Wffin  = (const float*)d_in[9];
  const float* bffin  = (const float*)d_in[10];
  const float* Wffout = (const float*)d_in[11];
  const float* bffout = (const float*)d_in[12];
  const float* lam    = (const float*)d_in[13];
  const float* l2ns   = (const float*)d_in[14];
  float* out = (float*)d_out;

  char* ws = (char*)d_ws;
  size_t off = 0;
  auto alloc = [&](size_t bytes) { void* p = ws + off; off += bytes; return p; };
  bfu* wt5   = (bfu*)alloc(5ull * 1024 * 1024 * 2);
  bfu* wtfi  = (bfu*)alloc(8192ull * 1024 * 2);
  bfu* wtfoc = (bfu*)alloc(1024ull * 5120 * 2);
  bfu* cosb  = (bfu*)alloc(1024ull * 32 * 2);
  bfu* sinb  = (bfu*)alloc(1024ull * 32 * 2);
  bfu* inner = (bfu*)alloc(4096ull * 1024 * 2);
  bfu* qb    = (bfu*)alloc(64ull * 1024 * 64 * 2);
  bfu* kb    = (bfu*)alloc(64ull * 1024 * 64 * 2);
  bfu* vtb   = (bfu*)alloc(64ull * 1024 * 64 * 2);
  bfu* bqh   = (bfu*)alloc(64ull * 1024 * 64 * 2);
  bfu* bkh   = (bfu*)alloc(64ull * 1024 * 64 * 2);
  float* browb = (float*)alloc(64ull * 1024 * 4);
  bfu* AB    = (bfu*)alloc(4096ull * 5120 * 2);

  // fused prologue
  PreArgs pa;
  pa.w5[0] = Wq; pa.w5[1] = Wk; pa.w5[2] = Wv; pa.w5[3] = WqB; pa.w5[4] = WkB;
  pa.Wffin = Wffin; pa.Wffout = Wffout; pa.Wo = Wo; pa.h = h;
  pa.wt5 = wt5; pa.wtfi = wtfi; pa.wtfoc = wtfoc;
  pa.cosb = cosb; pa.sinb = sinb; pa.inner = inner;
  prologue_k<<<dim3(22656), 256, 0, stream>>>(pa);

  // proj + l2norm/rope + in-LDS v-transpose epilogue
  gemm128p<<<dim3(1280), 256, 0, stream>>>(inner, wt5, qb, kb, vtb, bqh, bkh, cosb, sinb,
                                           4096, 5120, 1024, 32, 5);

  brow_all<<<dim3(64), 512, 0, stream>>>(bqh, bkh, browb);

  // fused flash (blocks 0..255) + FF-in (blocks 256..767)
  fused_k<<<dim3(768), 512, 0, stream>>>(qb, kb, vtb, browb, l2ns,
                                         inner, wtfi, AB, bffin);

  // final merged GEMM (128^2, BK=64, 3-stage)
  gemm128f<<<dim3(256), 256, 0, stream>>>(AB, wtfoc, out, bffout, bo, lam, h,
                                          4096, 1024, 5120, 8, 4);
}

// Round 20
// 300.640 us; speedup vs baseline: 1.0747x; 1.0097x over previous
//
#include <hip/hip_runtime.h>
#include <stdint.h>
#include <math.h>

typedef float f32x4 __attribute__((ext_vector_type(4)));
typedef short s16x8 __attribute__((ext_vector_type(8)));
typedef unsigned short bfu;

#define AS1q const __attribute__((address_space(1))) void*
#define AS3q __attribute__((address_space(3))) void*

static __device__ __forceinline__ float bf2f(bfu v) {
  return __uint_as_float(((unsigned int)v) << 16);
}
static __device__ __forceinline__ bfu f2bf(float f) {
  unsigned int u = __float_as_uint(f);
  return (bfu)((u + 0x7fffu + ((u >> 16) & 1u)) >> 16);
}

// ================= prologue (reduced): w5 converts + rope tables + rmsnorm =================
// blocks [0,5120): 5x QKV 1024^2 wconv | [5120,5248): rope | [5248,9344): rmsnorm
struct PreArgs {
  const float* w5[5];
  const float* h;
  bfu* wt5;
  bfu* cosb; bfu* sinb; bfu* inner;
};
__global__ __launch_bounds__(256) void prologue_k(PreArgs a) {
  __shared__ float shmem[32 * 33];
  int id = blockIdx.x;
  if (id < 5120) {
    int z = id >> 10, rem = id & 1023;
    const float* W = a.w5[z];
    bfu* Wt = a.wt5 + ((size_t)z << 20);
    int nb = (rem & 31) << 5, kb = (rem >> 5) << 5;
    float (*t)[33] = reinterpret_cast<float(*)[33]>(shmem);
    int tx = threadIdx.x & 31, ty = threadIdx.x >> 5;
#pragma unroll
    for (int i = 0; i < 4; i++) {
      int r = ty + i * 8;
      t[r][tx] = W[(size_t)(kb + r) * 1024 + nb + tx];
    }
    __syncthreads();
#pragma unroll
    for (int i = 0; i < 4; i++) {
      int r = ty + i * 8;
      Wt[(size_t)(nb + r) * 1024 + kb + tx] = f2bf(t[tx][r]);
    }
  } else if (id < 5248) {
    int idx = (id - 5120) * 256 + threadIdx.x;
    int s = idx >> 5, i = idx & 31;
    float f = powf(1000.0f, -(float)i / 32.0f);
    float fr = (float)s * f;
    a.cosb[idx] = f2bf(cosf(fr));
    a.sinb[idx] = f2bf(sinf(fr));
  } else {
    int row = id - 5248;
    const float* hr = a.h + (size_t)row * 1024;
    f32x4 x = *reinterpret_cast<const f32x4*>(hr + threadIdx.x * 4);
    float ss = x[0] * x[0] + x[1] * x[1] + x[2] * x[2] + x[3] * x[3];
    for (int off = 32; off; off >>= 1) ss += __shfl_down(ss, off);
    int wave = threadIdx.x >> 6, lane = threadIdx.x & 63;
    if (lane == 0) shmem[wave] = ss;
    __syncthreads();
    float tot = shmem[0] + shmem[1] + shmem[2] + shmem[3];
    float r = rsqrtf(tot * (1.0f / 1024.0f) + 1.1920929e-07f);
    bfu* o = a.inner + (size_t)row * 1024 + threadIdx.x * 4;
    o[0] = f2bf(x[0] * r); o[1] = f2bf(x[1] * r);
    o[2] = f2bf(x[2] * r); o[3] = f2bf(x[3] * r);
  }
}

// ============ fused: proj GEMM (blocks 0..1279) + FF/Wo weight converts (1280..14591) ============
// proj: 128x128, BK=32, 3-stage pipeline, 4 waves, 3 blocks/CU; epilogues write qb/kb/vT/bqh/bkh
// converters: [0,8192) Wffin MODE1 -> wtfi | [8192,12288) Wffout MODE2 -> wtfoc | [12288,13312) Wo MODE2
__global__ __launch_bounds__(256, 3) void projconv_k(const bfu* __restrict__ A, const bfu* __restrict__ Bt,
                                                     bfu* __restrict__ qb, bfu* __restrict__ kb,
                                                     bfu* __restrict__ vT,
                                                     bfu* __restrict__ bqh, bfu* __restrict__ bkh,
                                                     const bfu* __restrict__ ct, const bfu* __restrict__ st,
                                                     const float* __restrict__ Wffin,
                                                     const float* __restrict__ Wffout,
                                                     const float* __restrict__ Wo,
                                                     bfu* __restrict__ wtfi, bfu* __restrict__ wtfoc) {
  __shared__ __align__(16) char lds[49152];
  int tid = threadIdx.x, w = tid >> 6, lane = tid & 63;
  int g = lane >> 4, l15 = lane & 15;

  if (blockIdx.x >= 1280) {
    // ---------------- weight converters ----------------
    int cid = blockIdx.x - 1280;
    const float* W; bfu* Wt; int N, dstride, dofs, mode, nb, kb2;
    if (cid < 8192) {
      W = Wffin; Wt = wtfi; N = 8192; dstride = 1024; dofs = 0; mode = 1;
      nb = (cid & 255) << 5; kb2 = (cid >> 8) << 5;
    } else if (cid < 12288) {
      int id3 = cid - 8192;
      W = Wffout; Wt = wtfoc; N = 1024; dstride = 5120; dofs = 0; mode = 2;
      nb = (id3 & 31) << 5; kb2 = (id3 >> 5) << 5;
    } else {
      int id4 = cid - 12288;
      W = Wo; Wt = wtfoc; N = 1024; dstride = 5120; dofs = 4096; mode = 2;
      nb = (id4 & 31) << 5; kb2 = (id4 >> 5) << 5;
    }
    float (*t)[33] = reinterpret_cast<float(*)[33]>(lds);
    int tx = tid & 31, ty = tid >> 5;
#pragma unroll
    for (int i = 0; i < 4; i++) {
      int r = ty + i * 8;
      t[r][tx] = W[(size_t)(kb2 + r) * N + nb + tx];
    }
    __syncthreads();
#pragma unroll
    for (int i = 0; i < 4; i++) {
      int r = ty + i * 8;
      int n = nb + r;
      int nd = n;
      if (mode == 1) { int j = n & 4095, isg = n >> 12; nd = ((j >> 4) << 5) | (isg << 4) | (j & 15); }
      int k = kb2 + tx;
      int kp = (mode == 2) ? (((k >> 5) << 5) | ((k & 15) << 1) | ((k >> 4) & 1)) : k;
      Wt[(size_t)nd * dstride + dofs + kp] = f2bf(t[tx][r]);
    }
    return;
  }

  // ---------------- proj GEMM: N=5120, K=1024, rbm=32, rbn=5 ----------------
  const int K = 1024;
  int c = blockIdx.x & 7, rr = blockIdx.x >> 3;
  int bn0 = c * 5;                    // ca = 40/5 = 8, bm0 = 0
  int bm = rr / 5, bn = bn0 + rr % 5;
  int wm = w >> 1, wn = w & 1;
  const int NT = 32;

  f32x4 acc[4][4];
#pragma unroll
  for (int m = 0; m < 4; m++)
#pragma unroll
    for (int n = 0; n < 4; n++) acc[m][n] = (f32x4){0.f, 0.f, 0.f, 0.f};

  auto stage = [&](int buf, int t) {
    int k0 = t << 5;
#pragma unroll
    for (int r = 0; r < 2; r++) {
      int L = r * 256 + tid;
      int row = L >> 2, cc = L & 3;
      int kc = cc ^ (row & 3);
      const bfu* srcA = A + (size_t)(bm * 128 + row) * K + k0 + kc * 8;
      char* dstA = lds + buf * 16384 + r * 4096 + w * 1024;
      __builtin_amdgcn_global_load_lds((AS1q)srcA, (AS3q)dstA, 16, 0, 0);
      const bfu* srcB = Bt + (size_t)(bn * 128 + row) * K + k0 + kc * 8;
      char* dstB = lds + buf * 16384 + 8192 + r * 4096 + w * 1024;
      __builtin_amdgcn_global_load_lds((AS1q)srcB, (AS3q)dstB, 16, 0, 0);
    }
  };

  stage(0, 0); stage(1, 1);
  asm volatile("s_waitcnt vmcnt(4)" ::: "memory");
  __builtin_amdgcn_s_barrier();
  __builtin_amdgcn_sched_barrier(0);

  int bc = 0;
  for (int t = 0; t < NT; t++) {
    int bs = bc + 2; if (bs >= 3) bs -= 3;
    if (t + 2 < NT) stage(bs, t + 2);
    const char* la = lds + bc * 16384;
    const char* lb = la + 8192;
    s16x8 af[4], bfr[4];
#pragma unroll
    for (int m = 0; m < 4; m++) {
      int row = wm * 64 + m * 16 + l15;
      af[m] = *reinterpret_cast<const s16x8*>(la + row * 64 + ((g ^ (row & 3)) << 4));
    }
#pragma unroll
    for (int n = 0; n < 4; n++) {
      int row = wn * 64 + n * 16 + l15;
      bfr[n] = *reinterpret_cast<const s16x8*>(lb + row * 64 + ((g ^ (row & 3)) << 4));
    }
    asm volatile("s_waitcnt lgkmcnt(0)" ::: "memory");
    __builtin_amdgcn_sched_barrier(0);
    __builtin_amdgcn_s_setprio(1);
#pragma unroll
    for (int m = 0; m < 4; m++)
#pragma unroll
      for (int n = 0; n < 4; n++)
        acc[m][n] = __builtin_amdgcn_mfma_f32_16x16x32_bf16(af[m], bfr[n], acc[m][n], 0, 0, 0);
    __builtin_amdgcn_s_setprio(0);
    __builtin_amdgcn_sched_barrier(0);
    if (t < NT - 2) { asm volatile("s_waitcnt vmcnt(4)" ::: "memory"); }
    else            { asm volatile("s_waitcnt vmcnt(0)" ::: "memory"); }
    __builtin_amdgcn_s_barrier();
    __builtin_amdgcn_sched_barrier(0);
    bc++; if (bc == 3) bc = 0;
  }

  int which = bn >> 3;               // 0 q | 1 k | 2 v | 3 bq | 4 bk
  int hh = (bn & 7) * 2 + wn;
  if (which == 2) {
    bfu* lv = reinterpret_cast<bfu*>(lds);
#pragma unroll
    for (int m = 0; m < 4; m++) {
#pragma unroll
      for (int r = 0; r < 4; r++) {
        int sl = wm * 64 + m * 16 + g * 4 + r;
#pragma unroll
        for (int j = 0; j < 4; j++) {
          int d = j * 16 + l15;
          lv[(wn * 64 + d) * 136 + sl] = f2bf(acc[m][j][r]);
        }
      }
    }
    __syncthreads();
    int b = bm >> 3, h0 = (bn & 7) * 2;
#pragma unroll
    for (int i = 0; i < 8; i++) {
      int linear = i * 256 + tid;
      int hw = linear >> 10, rem = linear & 1023;
      int d = rem >> 4, sl8 = (rem & 15) << 3;
      s16x8 v8 = *reinterpret_cast<const s16x8*>(&lv[(hw * 64 + d) * 136 + sl8]);
      size_t dstofs = (((size_t)((b << 4) + h0 + hw) << 6) + d) * 1024 + (bm & 7) * 128 + sl8;
      *reinterpret_cast<s16x8*>(vT + dstofs) = v8;
    }
  } else {
#pragma unroll
    for (int m = 0; m < 4; m++) {
#pragma unroll
      for (int r = 0; r < 4; r++) {
        int row = bm * 128 + wm * 64 + m * 16 + g * 4 + r;
        int s = row & 1023, b = row >> 10;
        float a0 = acc[m][0][r], a1 = acc[m][1][r];
        float a2 = acc[m][2][r], a3 = acc[m][3][r];
        float ss = a0 * a0 + a1 * a1 + a2 * a2 + a3 * a3;
        ss += __shfl_xor(ss, 1); ss += __shfl_xor(ss, 2);
        ss += __shfl_xor(ss, 4); ss += __shfl_xor(ss, 8);
        float inv = 1.0f / fmaxf(sqrtf(ss), 1e-12f);
        float xn0 = a0 * inv, xn1 = a1 * inv, xn2 = a2 * inv, xn3 = a3 * inv;
        float c0 = bf2f(ct[(s << 5) + l15]),      s0v = bf2f(st[(s << 5) + l15]);
        float c1 = bf2f(ct[(s << 5) + 16 + l15]), s1v = bf2f(st[(s << 5) + 16 + l15]);
        float o0 = xn0 * c0 + xn2 * s0v;
        float o1 = xn1 * c1 + xn3 * s1v;
        float o2 = xn2 * c0 - xn0 * s0v;
        float o3 = xn3 * c1 - xn1 * s1v;
        unsigned long long pk =
            (unsigned long long)((unsigned int)f2bf(o0) | ((unsigned int)f2bf(o1) << 16)) |
            ((unsigned long long)((unsigned int)f2bf(o2) | ((unsigned int)f2bf(o3) << 16)) << 32);
        size_t base = ((((size_t)((b << 4) + hh) << 10) + s) << 6) + (l15 << 2);
        bfu* dst = (which == 0) ? qb : (which == 1) ? kb : (which == 3) ? bqh : bkh;
        *reinterpret_cast<unsigned long long*>(dst + base) = pk;
      }
    }
  }
}

// ============ fused dispatch: flash (blocks 0..255, 2 sub-blocks/block) + FF-in (256..767) ============
__global__ __launch_bounds__(512, 2) void fused_k(const bfu* __restrict__ q, const bfu* __restrict__ k,
                                                  const bfu* __restrict__ vT,
                                                  const float* __restrict__ brow,
                                                  const float* __restrict__ l2p,
                                                  const bfu* __restrict__ A, const bfu* __restrict__ Bt,
                                                  bfu* __restrict__ AB,
                                                  const float* __restrict__ bias) {
  __shared__ __align__(16) char lds[131072];
  int tid = threadIdx.x, w = tid >> 6, lane = tid & 63;
  int g = lane >> 4, l15 = lane & 15;

  if (blockIdx.x < 256) {
    int fid = blockIdx.x + ((w >> 2) << 8);
    int sub = fid & 255;
    int qt = (fid >> 8) ? 7 - (sub >> 6) : (sub >> 6);
    int bh = sub & 63;
    const size_t bhofs = (size_t)bh << 16;
    int rt0 = qt * 128 + (w & 3) * 32;
    bfu* P = reinterpret_cast<bfu*>(lds) + (size_t)w * (2 * 16 * 72);

    s16x8 aq[2][2];
#pragma unroll
    for (int m = 0; m < 2; m++)
#pragma unroll
      for (int ks = 0; ks < 2; ks++)
        aq[m][ks] = *reinterpret_cast<const s16x8*>(
            q + bhofs + (size_t)(rt0 + m * 16 + l15) * 64 + ks * 32 + g * 8);

    f32x4 O[2][4];
    float mr[2][4], lr[2][4];
#pragma unroll
    for (int m = 0; m < 2; m++)
#pragma unroll
      for (int r = 0; r < 4; r++) { O[m][r] = (f32x4){0.f, 0.f, 0.f, 0.f}; mr[m][r] = -3.0e38f; lr[m][r] = 0.f; }

    s16x8 kA[4][2], kB[4][2];
    auto loadK = [&](s16x8 (&kd)[4][2], int jt) {
#pragma unroll
      for (int nt = 0; nt < 4; nt++)
#pragma unroll
        for (int ks = 0; ks < 2; ks++)
          kd[nt][ks] = *reinterpret_cast<const s16x8*>(
              k + bhofs + (size_t)(jt * 64 + nt * 16 + l15) * 64 + ks * 32 + g * 8);
    };

    int njt = 2 * qt + 2;
    loadK(kA, 0);

    auto body = [&](int jt, s16x8 (&kc)[4][2], s16x8 (&kn)[4][2], bool pf) {
      s16x8 vv[4][2];
#pragma unroll
      for (int nt = 0; nt < 4; nt++)
#pragma unroll
        for (int ks = 0; ks < 2; ks++)
          vv[nt][ks] = *reinterpret_cast<const s16x8*>(
              vT + ((size_t)(bh * 64 + nt * 16 + l15) << 10) + jt * 64 + ks * 32 + g * 8);

      bool act[2] = { jt * 64 <= rt0 + 15, jt * 64 <= rt0 + 31 };
      f32x4 sfr[2][4];
#pragma unroll
      for (int m = 0; m < 2; m++) {
        if (!act[m]) continue;
#pragma unroll
        for (int nt = 0; nt < 4; nt++) {
          sfr[m][nt] = (f32x4){0.f, 0.f, 0.f, 0.f};
#pragma unroll
          for (int ks = 0; ks < 2; ks++)
            sfr[m][nt] = __builtin_amdgcn_mfma_f32_16x16x32_bf16(aq[m][ks], kc[nt][ks], sfr[m][nt], 0, 0, 0);
        }
      }
      if (pf) loadK(kn, jt + 1);

#pragma unroll
      for (int m = 0; m < 2; m++) {
        if (!act[m]) continue;
        int rtm = rt0 + m * 16;
        if (jt * 64 + 63 > rtm) {
#pragma unroll
          for (int ntn = 0; ntn < 4; ntn++)
#pragma unroll
            for (int r = 0; r < 4; r++)
              if (jt * 64 + ntn * 16 + l15 > rtm + g * 4 + r) sfr[m][ntn][r] = -1e30f;
        }
        float alpha[4];
#pragma unroll
        for (int r = 0; r < 4; r++) {
          float v = fmaxf(fmaxf(sfr[m][0][r], sfr[m][1][r]), fmaxf(sfr[m][2][r], sfr[m][3][r]));
#pragma unroll
          for (int m2 = 1; m2 < 16; m2 <<= 1) v = fmaxf(v, __shfl_xor(v, m2));
          float mn = fmaxf(mr[m][r], v);
          alpha[r] = __expf(mr[m][r] - mn);
          mr[m][r] = mn;
        }
#pragma unroll
        for (int r = 0; r < 4; r++) {
          float rs = 0.f;
#pragma unroll
          for (int ntn = 0; ntn < 4; ntn++) {
            float e = __expf(sfr[m][ntn][r] - mr[m][r]);
            rs += e;
            P[(m * 16 + g * 4 + r) * 72 + ntn * 16 + l15] = f2bf(e);
          }
#pragma unroll
          for (int m2 = 1; m2 < 16; m2 <<= 1) rs += __shfl_xor(rs, m2);
          lr[m][r] = lr[m][r] * alpha[r] + rs;
#pragma unroll
          for (int ntn = 0; ntn < 4; ntn++) O[m][ntn][r] *= alpha[r];
        }
      }
      asm volatile("s_waitcnt lgkmcnt(0)" ::: "memory");
      __builtin_amdgcn_sched_barrier(0);
#pragma unroll
      for (int m = 0; m < 2; m++) {
        if (!act[m]) continue;
        s16x8 pa[2];
#pragma unroll
        for (int ks = 0; ks < 2; ks++)
          pa[ks] = *reinterpret_cast<const s16x8*>(&P[(m * 16 + l15) * 72 + ks * 32 + g * 8]);
#pragma unroll
        for (int nt = 0; nt < 4; nt++)
#pragma unroll
          for (int ks = 0; ks < 2; ks++)
            O[m][nt] = __builtin_amdgcn_mfma_f32_16x16x32_bf16(pa[ks], vv[nt][ks], O[m][nt], 0, 0, 0);
      }
    };

    for (int jt = 0; jt < njt; jt += 2) {
      body(jt, kA, kB, true);
      body(jt + 1, kB, kA, jt + 2 < njt);
    }

    float l2ns = l2p[0];
    int b = bh >> 4, hq = bh & 15;
#pragma unroll
    for (int m = 0; m < 2; m++)
#pragma unroll
      for (int r = 0; r < 4; r++) {
        int rowg = rt0 + m * 16 + g * 4 + r;
        float br = brow[bh * 1024 + rowg];
        float sc = l2ns / lr[m][r];
        float v0 = O[m][0][r] * sc + br;
        float v1 = O[m][1][r] * sc + br;
        float v2 = O[m][2][r] * sc + br;
        float v3 = O[m][3][r] * sc + br;
        unsigned int p01 = (unsigned int)f2bf(v0) | ((unsigned int)f2bf(v1) << 16);
        unsigned int p23 = (unsigned int)f2bf(v2) | ((unsigned int)f2bf(v3) << 16);
        size_t base = (size_t)(b * 1024 + rowg) * 5120 + 4096 + hq * 64;
        *reinterpret_cast<unsigned int*>(AB + base + 2 * l15) = p01;
        *reinterpret_cast<unsigned int*>(AB + base + 32 + 2 * l15) = p23;
      }
    return;
  }

  // ================== FF-in: 256x256, BK=64, 2-dbuf, counted vmcnt ==================
  int id0 = blockIdx.x - 256;
  int c = id0 & 7, rr = id0 >> 3;
  int bn0 = (c & 3) * 8, bm0 = (c >> 2) * 8;
  int bm = bm0 + rr / 8, bn = bn0 + rr % 8;
  int wm = w >> 2, wn = w & 3;
  const int K = 1024;
  const int NT = 16, NI = 8;

  f32x4 acc[8][4];
#pragma unroll
  for (int m = 0; m < 8; m++)
#pragma unroll
    for (int n = 0; n < 4; n++) acc[m][n] = (f32x4){0.f, 0.f, 0.f, 0.f};

  s16x8 af[4][2];
  s16x8 bfr[4][2];

  auto stage = [&](int mat, int kt, int hf) {
    if (kt >= NT) return;
    int d = kt & 1;
    const bfu* s0 = (mat == 0) ? A : Bt;
    int rowbase = ((mat == 0) ? bm : bn) * 256 + hf * 128;
    int k0 = kt << 6;
    char* base = lds + d * 65536 + mat * 32768 + hf * 16384;
#pragma unroll
    for (int r = 0; r < 2; r++) {
      int L = r * 512 + tid;
      int row = L >> 3, cc = L & 7;
      int kc = cc ^ (row & 7);
      const bfu* src = s0 + (size_t)(rowbase + row) * K + k0 + kc * 8;
      char* dst = base + r * 8192 + w * 1024;
      __builtin_amdgcn_global_load_lds((AS1q)src, (AS3q)dst, 16, 0, 0);
    }
  };

  auto ldA = [&](int d, int mh) {
    const char* base = lds + d * 65536 + wm * 16384;
#pragma unroll
    for (int mm = 0; mm < 4; mm++) {
      int row = mh * 64 + mm * 16 + l15;
#pragma unroll
      for (int ks = 0; ks < 2; ks++)
        af[mm][ks] = *reinterpret_cast<const s16x8*>(
            base + row * 128 + (((ks * 4 + g) ^ (row & 7)) << 4));
    }
  };
  auto ldB2 = [&](int d, int nh) {
    const char* base = lds + d * 65536 + 32768 + (wn >> 1) * 16384;
#pragma unroll
    for (int nn = 0; nn < 2; nn++) {
      int row = (wn & 1) * 64 + (nh * 2 + nn) * 16 + l15;
#pragma unroll
      for (int ks = 0; ks < 2; ks++)
        bfr[nh * 2 + nn][ks] = *reinterpret_cast<const s16x8*>(
            base + row * 128 + (((ks * 4 + g) ^ (row & 7)) << 4));
    }
  };
  auto mfma_q = [&](int mh, int nh) {
    asm volatile("s_waitcnt lgkmcnt(0)" ::: "memory");
    __builtin_amdgcn_sched_barrier(0);
    __builtin_amdgcn_s_barrier();
    __builtin_amdgcn_s_setprio(1);
#pragma unroll
    for (int mm = 0; mm < 4; mm++)
#pragma unroll
      for (int nn = 0; nn < 2; nn++) {
        int n = nh * 2 + nn, m = mh * 4 + mm;
#pragma unroll
        for (int ks = 0; ks < 2; ks++)
          acc[m][n] = __builtin_amdgcn_mfma_f32_16x16x32_bf16(af[mm][ks], bfr[n][ks], acc[m][n], 0, 0, 0);
      }
    __builtin_amdgcn_s_setprio(0);
    __builtin_amdgcn_sched_barrier(0);
  };

  stage(1, 0, 0); stage(0, 0, 0); stage(0, 0, 1); stage(1, 0, 1);
  stage(1, 1, 0); stage(1, 1, 1);
  asm volatile("s_waitcnt vmcnt(4)" ::: "memory");
  __builtin_amdgcn_s_barrier();
  __builtin_amdgcn_sched_barrier(0);

  for (int i = 0; i < NI; i++) {
    int t0 = 2 * i, t1 = 2 * i + 1;
    bool last = (i == NI - 1);
    ldA(0, 0); ldB2(0, 0);
    stage(0, t1, 0);
    mfma_q(0, 0);
    ldB2(0, 1);
    stage(0, t1, 1);
    mfma_q(0, 1);
    ldA(0, 1);
    stage(1, t0 + 2, 0);
    mfma_q(1, 0);
    stage(1, t0 + 2, 1);
    mfma_q(1, 1);
    if (last) { asm volatile("s_waitcnt vmcnt(0)" ::: "memory"); }
    else      { asm volatile("s_waitcnt vmcnt(4)" ::: "memory"); }
    __builtin_amdgcn_s_barrier();
    __builtin_amdgcn_sched_barrier(0);
    ldA(1, 0); ldB2(1, 0);
    stage(0, t0 + 2, 0);
    mfma_q(0, 0);
    ldB2(1, 1);
    stage(0, t0 + 2, 1);
    mfma_q(0, 1);
    ldA(1, 1);
    stage(1, t1 + 2, 0);
    mfma_q(1, 0);
    stage(1, t1 + 2, 1);
    mfma_q(1, 1);
    asm volatile("s_waitcnt vmcnt(4)" ::: "memory");
    __builtin_amdgcn_s_barrier();
    __builtin_amdgcn_sched_barrier(0);
  }

  int j0 = (bn * 8 + wn * 2) * 16 + l15;
  float bx0 = bias[j0], bg0 = bias[j0 + 4096];
  float bx1 = bias[j0 + 16], bg1 = bias[j0 + 16 + 4096];
  int cb = (bn * 4 + wn) * 32 + 2 * l15;
#pragma unroll
  for (int m = 0; m < 8; m++) {
#pragma unroll
    for (int r = 0; r < 4; r++) {
      int row = bm * 256 + wm * 128 + m * 16 + g * 4 + r;
      float xh0 = acc[m][0][r] + bx0, gt0 = acc[m][1][r] + bg0;
      float xh1 = acc[m][2][r] + bx1, gt1 = acc[m][3][r] + bg1;
      float s0 = gt0 / (1.0f + __expf(-gt0)) * xh0;
      float s1 = gt1 / (1.0f + __expf(-gt1)) * xh1;
      unsigned int pk = (unsigned int)f2bf(s0) | ((unsigned int)f2bf(s1) << 16);
      *reinterpret_cast<unsigned int*>(AB + (size_t)row * 5120 + cb) = pk;
    }
  }
}

// ============ final GEMM: 128x128 tile, BK=64, 3-stage pipeline, 4 waves (R13-proven) ============
__global__ __launch_bounds__(256, 3) void gemm128f(const bfu* __restrict__ A, const bfu* __restrict__ Bt,
                                                   float* __restrict__ out,
                                                   const float* __restrict__ b1,
                                                   const float* __restrict__ b2,
                                                   const float* __restrict__ lam,
                                                   const float* __restrict__ h,
                                                   int M, int N, int K, int rbm, int rbn) {
  __shared__ __align__(16) char lds[98304];
  int nbx = N >> 7;
  int c = blockIdx.x & 7, rr = blockIdx.x >> 3;
  int ca = nbx / rbn;
  int bn0 = (c % ca) * rbn, bm0 = (c / ca) * rbm;
  int bm = bm0 + rr / rbn, bn = bn0 + rr % rbn;
  int tid = threadIdx.x, w = tid >> 6, lane = tid & 63;
  int wm = w >> 1, wn = w & 1;
  int g = lane >> 4, l15 = lane & 15;
  int NT = K >> 6;

  f32x4 acc[4][4];
#pragma unroll
  for (int m = 0; m < 4; m++)
#pragma unroll
    for (int n = 0; n < 4; n++) acc[m][n] = (f32x4){0.f, 0.f, 0.f, 0.f};

  auto stage = [&](int buf, int t) {
    int k0 = t << 6;
#pragma unroll
    for (int r = 0; r < 4; r++) {
      int L = r * 256 + tid;
      int row = L >> 3, cc = L & 7;
      int kc = cc ^ (row & 7);
      const bfu* srcA = A + (size_t)(bm * 128 + row) * K + k0 + kc * 8;
      char* dstA = lds + buf * 32768 + r * 4096 + w * 1024;
      __builtin_amdgcn_global_load_lds((AS1q)srcA, (AS3q)dstA, 16, 0, 0);
    }
#pragma unroll
    for (int r = 0; r < 4; r++) {
      int L = r * 256 + tid;
      int row = L >> 3, cc = L & 7;
      int kc = cc ^ (row & 7);
      const bfu* srcB = Bt + (size_t)(bn * 128 + row) * K + k0 + kc * 8;
      char* dstB = lds + buf * 32768 + 16384 + r * 4096 + w * 1024;
      __builtin_amdgcn_global_load_lds((AS1q)srcB, (AS3q)dstB, 16, 0, 0);
    }
  };

  stage(0, 0); stage(1, 1);
  asm volatile("s_waitcnt vmcnt(8)" ::: "memory");
  __builtin_amdgcn_s_barrier();
  __builtin_amdgcn_sched_barrier(0);

  int bc = 0;
  for (int t = 0; t < NT; t++) {
    int bs = bc + 2; if (bs >= 3) bs -= 3;
    if (t + 2 < NT) stage(bs, t + 2);
    const char* la = lds + bc * 32768;
    const char* lb = la + 16384;
    s16x8 af[4][2], bfr[4][2];
#pragma unroll
    for (int m = 0; m < 4; m++) {
      int row = wm * 64 + m * 16 + l15;
#pragma unroll
      for (int ks = 0; ks < 2; ks++)
        af[m][ks] = *reinterpret_cast<const s16x8*>(
            la + row * 128 + (((ks * 4 + g) ^ (row & 7)) << 4));
    }
#pragma unroll
    for (int n = 0; n < 4; n++) {
      int row = wn * 64 + n * 16 + l15;
#pragma unroll
      for (int ks = 0; ks < 2; ks++)
        bfr[n][ks] = *reinterpret_cast<const s16x8*>(
            lb + row * 128 + (((ks * 4 + g) ^ (row & 7)) << 4));
    }
    asm volatile("s_waitcnt lgkmcnt(0)" ::: "memory");
    __builtin_amdgcn_sched_barrier(0);
    __builtin_amdgcn_s_setprio(1);
#pragma unroll
    for (int m = 0; m < 4; m++)
#pragma unroll
      for (int n = 0; n < 4; n++)
#pragma unroll
        for (int ks = 0; ks < 2; ks++)
          acc[m][n] = __builtin_amdgcn_mfma_f32_16x16x32_bf16(af[m][ks], bfr[n][ks], acc[m][n], 0, 0, 0);
    __builtin_amdgcn_s_setprio(0);
    __builtin_amdgcn_sched_barrier(0);
    if (t < NT - 2) { asm volatile("s_waitcnt vmcnt(8)" ::: "memory"); }
    else            { asm volatile("s_waitcnt vmcnt(0)" ::: "memory"); }
    __builtin_amdgcn_s_barrier();
    __builtin_amdgcn_sched_barrier(0);
    bc++; if (bc == 3) bc = 0;
  }

  float lv = lam[0];
#pragma unroll
  for (int m = 0; m < 4; m++) {
    int row = bm * 128 + wm * 64 + m * 16 + g * 4;
#pragma unroll
    for (int n = 0; n < 4; n++) {
      int col = bn * 128 + wn * 64 + n * 16 + l15;
      float bb = b1[col] + b2[col];
#pragma unroll
      for (int r = 0; r < 4; r++) {
        size_t o = (size_t)(row + r) * 1024 + col;
        out[o] = acc[m][n][r] + bb + lv * h[o];
      }
    }
  }
}

// ---------------- fused brow ----------------
__global__ __launch_bounds__(512) void brow_all(const bfu* __restrict__ bq, const bfu* __restrict__ bk,
                                                float* __restrict__ brow) {
  __shared__ float csums[8][64];
  int bh = blockIdx.x;
  int wave = threadIdx.x >> 6, lane = threadIdx.x & 63;
  size_t base = ((size_t)bh * 1024 + wave * 128) * 64 + lane;
  float s = 0.f;
  for (int j = 0; j < 128; j++) s += bf2f(bk[base + (size_t)j * 64]);
  csums[wave][lane] = s;
  __syncthreads();
  float p = 0.f;
  for (int cc = 0; cc < wave; cc++) p += csums[cc][lane];
  for (int j = 0; j < 128; j++) {
    p += bf2f(bk[base + (size_t)j * 64]);
    float t = bf2f(bq[base + (size_t)j * 64]) * p;
#pragma unroll
    for (int m2 = 1; m2 < 64; m2 <<= 1) t += __shfl_xor(t, m2);
    if (lane == 0) brow[bh * 1024 + wave * 128 + j] = 0.125f * t;
  }
}

// ================= host =================
extern "C" void kernel_launch(void* const* d_in, const int* in_sizes, int n_in,
                              void* d_out, int out_size, void* d_ws, size_t ws_size,
                              hipStream_t stream) {
  const float* h      = (const float*)d_in[0];
  const float* Wq     = (const float*)d_in[2];
  const float* Wk     = (const float*)d_in[3];
  const float* Wv     = (const float*)d_in[4];
  const float* WqB    = (const float*)d_in[5];
  const float* WkB    = (const float*)d_in[6];
  const float* Wo     = (const float*)d_in[7];
  const float* bo     = (const float*)d_in[8];
  const float* Wffin  = (const float*)d_in[9];
  const float* bffin  = (const float*)d_in[10];
  const float* Wffout = (const float*)d_in[11];
  const float* bffout = (const float*)d_in[12];
  const float* lam    = (const float*)d_in[13];
  const float* l2ns   = (const float*)d_in[14];
  float* out = (float*)d_out;

  char* ws = (char*)d_ws;
  size_t off = 0;
  auto alloc = [&](size_t bytes) { void* p = ws + off; off += bytes; return p; };
  bfu* wt5   = (bfu*)alloc(5ull * 1024 * 1024 * 2);
  bfu* wtfi  = (bfu*)alloc(8192ull * 1024 * 2);
  bfu* wtfoc = (bfu*)alloc(1024ull * 5120 * 2);
  bfu* cosb  = (bfu*)alloc(1024ull * 32 * 2);
  bfu* sinb  = (bfu*)alloc(1024ull * 32 * 2);
  bfu* inner = (bfu*)alloc(4096ull * 1024 * 2);
  bfu* qb    = (bfu*)alloc(64ull * 1024 * 64 * 2);
  bfu* kb    = (bfu*)alloc(64ull * 1024 * 64 * 2);
  bfu* vtb   = (bfu*)alloc(64ull * 1024 * 64 * 2);
  bfu* bqh   = (bfu*)alloc(64ull * 1024 * 64 * 2);
  bfu* bkh   = (bfu*)alloc(64ull * 1024 * 64 * 2);
  float* browb = (float*)alloc(64ull * 1024 * 4);
  bfu* AB    = (bfu*)alloc(4096ull * 5120 * 2);

  // reduced prologue: w5 converts + rope + rmsnorm (9344 blocks)
  PreArgs pa;
  pa.w5[0] = Wq; pa.w5[1] = Wk; pa.w5[2] = Wv; pa.w5[3] = WqB; pa.w5[4] = WkB;
  pa.h = h; pa.wt5 = wt5; pa.cosb = cosb; pa.sinb = sinb; pa.inner = inner;
  prologue_k<<<dim3(9344), 256, 0, stream>>>(pa);

  // fused: proj (blocks 0..1279) + FF/Wo weight converters (1280..14591)
  projconv_k<<<dim3(14592), 256, 0, stream>>>(inner, wt5, qb, kb, vtb, bqh, bkh, cosb, sinb,
                                              Wffin, Wffout, Wo, wtfi, wtfoc);

  brow_all<<<dim3(64), 512, 0, stream>>>(bqh, bkh, browb);

  // fused flash (blocks 0..255) + FF-in (blocks 256..767)
  fused_k<<<dim3(768), 512, 0, stream>>>(qb, kb, vtb, browb, l2ns,
                                         inner, wtfi, AB, bffin);

  // final merged GEMM (128^2, BK=64, 3-stage)
  gemm128f<<<dim3(256), 256, 0, stream>>>(AB, wtfoc, out, bffout, bo, lam, h,
                                          4096, 1024, 5120, 8, 4);
}

// Round 21
// 298.005 us; speedup vs baseline: 1.0842x; 1.0088x over previous
//
#include <hip/hip_runtime.h>
#include <stdint.h>
#include <math.h>

typedef float f32x4 __attribute__((ext_vector_type(4)));
typedef short s16x8 __attribute__((ext_vector_type(8)));
typedef unsigned short bfu;

#define AS1q const __attribute__((address_space(1))) void*
#define AS3q __attribute__((address_space(3))) void*

static __device__ __forceinline__ float bf2f(bfu v) {
  return __uint_as_float(((unsigned int)v) << 16);
}
static __device__ __forceinline__ bfu f2bf(float f) {
  unsigned int u = __float_as_uint(f);
  return (bfu)((u + 0x7fffu + ((u >> 16) & 1u)) >> 16);
}

// ================= prologue (reduced): w5 converts + rope tables + rmsnorm =================
// blocks [0,5120): 5x QKV 1024^2 wconv | [5120,5248): rope | [5248,9344): rmsnorm
struct PreArgs {
  const float* w5[5];
  const float* h;
  bfu* wt5;
  bfu* cosb; bfu* sinb; bfu* inner;
};
__global__ __launch_bounds__(256) void prologue_k(PreArgs a) {
  __shared__ float shmem[32 * 33];
  int id = blockIdx.x;
  if (id < 5120) {
    int z = id >> 10, rem = id & 1023;
    const float* W = a.w5[z];
    bfu* Wt = a.wt5 + ((size_t)z << 20);
    int nb = (rem & 31) << 5, kb = (rem >> 5) << 5;
    float (*t)[33] = reinterpret_cast<float(*)[33]>(shmem);
    int tx = threadIdx.x & 31, ty = threadIdx.x >> 5;
#pragma unroll
    for (int i = 0; i < 4; i++) {
      int r = ty + i * 8;
      t[r][tx] = W[(size_t)(kb + r) * 1024 + nb + tx];
    }
    __syncthreads();
#pragma unroll
    for (int i = 0; i < 4; i++) {
      int r = ty + i * 8;
      Wt[(size_t)(nb + r) * 1024 + kb + tx] = f2bf(t[tx][r]);
    }
  } else if (id < 5248) {
    int idx = (id - 5120) * 256 + threadIdx.x;
    int s = idx >> 5, i = idx & 31;
    float f = powf(1000.0f, -(float)i / 32.0f);
    float fr = (float)s * f;
    a.cosb[idx] = f2bf(cosf(fr));
    a.sinb[idx] = f2bf(sinf(fr));
  } else {
    int row = id - 5248;
    const float* hr = a.h + (size_t)row * 1024;
    f32x4 x = *reinterpret_cast<const f32x4*>(hr + threadIdx.x * 4);
    float ss = x[0] * x[0] + x[1] * x[1] + x[2] * x[2] + x[3] * x[3];
    for (int off = 32; off; off >>= 1) ss += __shfl_down(ss, off);
    int wave = threadIdx.x >> 6, lane = threadIdx.x & 63;
    if (lane == 0) shmem[wave] = ss;
    __syncthreads();
    float tot = shmem[0] + shmem[1] + shmem[2] + shmem[3];
    float r = rsqrtf(tot * (1.0f / 1024.0f) + 1.1920929e-07f);
    bfu* o = a.inner + (size_t)row * 1024 + threadIdx.x * 4;
    o[0] = f2bf(x[0] * r); o[1] = f2bf(x[1] * r);
    o[2] = f2bf(x[2] * r); o[3] = f2bf(x[3] * r);
  }
}

// ============ fused: proj GEMM (blocks 0..1279) + FF/Wo weight converts (1280..14591) ============
__global__ __launch_bounds__(256, 3) void projconv_k(const bfu* __restrict__ A, const bfu* __restrict__ Bt,
                                                     bfu* __restrict__ qb, bfu* __restrict__ kb,
                                                     bfu* __restrict__ vT,
                                                     bfu* __restrict__ bqh, bfu* __restrict__ bkh,
                                                     const bfu* __restrict__ ct, const bfu* __restrict__ st,
                                                     const float* __restrict__ Wffin,
                                                     const float* __restrict__ Wffout,
                                                     const float* __restrict__ Wo,
                                                     bfu* __restrict__ wtfi, bfu* __restrict__ wtfoc) {
  __shared__ __align__(16) char lds[49152];
  int tid = threadIdx.x, w = tid >> 6, lane = tid & 63;
  int g = lane >> 4, l15 = lane & 15;

  if (blockIdx.x >= 1280) {
    int cid = blockIdx.x - 1280;
    const float* W; bfu* Wt; int N, dstride, dofs, mode, nb, kb2;
    if (cid < 8192) {
      W = Wffin; Wt = wtfi; N = 8192; dstride = 1024; dofs = 0; mode = 1;
      nb = (cid & 255) << 5; kb2 = (cid >> 8) << 5;
    } else if (cid < 12288) {
      int id3 = cid - 8192;
      W = Wffout; Wt = wtfoc; N = 1024; dstride = 5120; dofs = 0; mode = 2;
      nb = (id3 & 31) << 5; kb2 = (id3 >> 5) << 5;
    } else {
      int id4 = cid - 12288;
      W = Wo; Wt = wtfoc; N = 1024; dstride = 5120; dofs = 4096; mode = 2;
      nb = (id4 & 31) << 5; kb2 = (id4 >> 5) << 5;
    }
    float (*t)[33] = reinterpret_cast<float(*)[33]>(lds);
    int tx = tid & 31, ty = tid >> 5;
#pragma unroll
    for (int i = 0; i < 4; i++) {
      int r = ty + i * 8;
      t[r][tx] = W[(size_t)(kb2 + r) * N + nb + tx];
    }
    __syncthreads();
#pragma unroll
    for (int i = 0; i < 4; i++) {
      int r = ty + i * 8;
      int n = nb + r;
      int nd = n;
      if (mode == 1) { int j = n & 4095, isg = n >> 12; nd = ((j >> 4) << 5) | (isg << 4) | (j & 15); }
      int k = kb2 + tx;
      int kp = (mode == 2) ? (((k >> 5) << 5) | ((k & 15) << 1) | ((k >> 4) & 1)) : k;
      Wt[(size_t)nd * dstride + dofs + kp] = f2bf(t[tx][r]);
    }
    return;
  }

  const int K = 1024;
  int c = blockIdx.x & 7, rr = blockIdx.x >> 3;
  int bn0 = c * 5;
  int bm = rr / 5, bn = bn0 + rr % 5;
  int wm = w >> 1, wn = w & 1;
  const int NT = 32;

  f32x4 acc[4][4];
#pragma unroll
  for (int m = 0; m < 4; m++)
#pragma unroll
    for (int n = 0; n < 4; n++) acc[m][n] = (f32x4){0.f, 0.f, 0.f, 0.f};

  auto stage = [&](int buf, int t) {
    int k0 = t << 5;
#pragma unroll
    for (int r = 0; r < 2; r++) {
      int L = r * 256 + tid;
      int row = L >> 2, cc = L & 3;
      int kc = cc ^ (row & 3);
      const bfu* srcA = A + (size_t)(bm * 128 + row) * K + k0 + kc * 8;
      char* dstA = lds + buf * 16384 + r * 4096 + w * 1024;
      __builtin_amdgcn_global_load_lds((AS1q)srcA, (AS3q)dstA, 16, 0, 0);
      const bfu* srcB = Bt + (size_t)(bn * 128 + row) * K + k0 + kc * 8;
      char* dstB = lds + buf * 16384 + 8192 + r * 4096 + w * 1024;
      __builtin_amdgcn_global_load_lds((AS1q)srcB, (AS3q)dstB, 16, 0, 0);
    }
  };

  stage(0, 0); stage(1, 1);
  asm volatile("s_waitcnt vmcnt(4)" ::: "memory");
  __builtin_amdgcn_s_barrier();
  __builtin_amdgcn_sched_barrier(0);

  int bc = 0;
  for (int t = 0; t < NT; t++) {
    int bs = bc + 2; if (bs >= 3) bs -= 3;
    if (t + 2 < NT) stage(bs, t + 2);
    const char* la = lds + bc * 16384;
    const char* lb = la + 8192;
    s16x8 af[4], bfr[4];
#pragma unroll
    for (int m = 0; m < 4; m++) {
      int row = wm * 64 + m * 16 + l15;
      af[m] = *reinterpret_cast<const s16x8*>(la + row * 64 + ((g ^ (row & 3)) << 4));
    }
#pragma unroll
    for (int n = 0; n < 4; n++) {
      int row = wn * 64 + n * 16 + l15;
      bfr[n] = *reinterpret_cast<const s16x8*>(lb + row * 64 + ((g ^ (row & 3)) << 4));
    }
    asm volatile("s_waitcnt lgkmcnt(0)" ::: "memory");
    __builtin_amdgcn_sched_barrier(0);
    __builtin_amdgcn_s_setprio(1);
#pragma unroll
    for (int m = 0; m < 4; m++)
#pragma unroll
      for (int n = 0; n < 4; n++)
        acc[m][n] = __builtin_amdgcn_mfma_f32_16x16x32_bf16(af[m], bfr[n], acc[m][n], 0, 0, 0);
    __builtin_amdgcn_s_setprio(0);
    __builtin_amdgcn_sched_barrier(0);
    if (t < NT - 2) { asm volatile("s_waitcnt vmcnt(4)" ::: "memory"); }
    else            { asm volatile("s_waitcnt vmcnt(0)" ::: "memory"); }
    __builtin_amdgcn_s_barrier();
    __builtin_amdgcn_sched_barrier(0);
    bc++; if (bc == 3) bc = 0;
  }

  int which = bn >> 3;               // 0 q | 1 k | 2 v | 3 bq | 4 bk
  int hh = (bn & 7) * 2 + wn;
  if (which == 2) {
    bfu* lv = reinterpret_cast<bfu*>(lds);
#pragma unroll
    for (int m = 0; m < 4; m++) {
#pragma unroll
      for (int r = 0; r < 4; r++) {
        int sl = wm * 64 + m * 16 + g * 4 + r;
#pragma unroll
        for (int j = 0; j < 4; j++) {
          int d = j * 16 + l15;
          lv[(wn * 64 + d) * 136 + sl] = f2bf(acc[m][j][r]);
        }
      }
    }
    __syncthreads();
    int b = bm >> 3, h0 = (bn & 7) * 2;
#pragma unroll
    for (int i = 0; i < 8; i++) {
      int linear = i * 256 + tid;
      int hw = linear >> 10, rem = linear & 1023;
      int d = rem >> 4, sl8 = (rem & 15) << 3;
      s16x8 v8 = *reinterpret_cast<const s16x8*>(&lv[(hw * 64 + d) * 136 + sl8]);
      size_t dstofs = (((size_t)((b << 4) + h0 + hw) << 6) + d) * 1024 + (bm & 7) * 128 + sl8;
      *reinterpret_cast<s16x8*>(vT + dstofs) = v8;
    }
  } else {
#pragma unroll
    for (int m = 0; m < 4; m++) {
#pragma unroll
      for (int r = 0; r < 4; r++) {
        int row = bm * 128 + wm * 64 + m * 16 + g * 4 + r;
        int s = row & 1023, b = row >> 10;
        float a0 = acc[m][0][r], a1 = acc[m][1][r];
        float a2 = acc[m][2][r], a3 = acc[m][3][r];
        float ss = a0 * a0 + a1 * a1 + a2 * a2 + a3 * a3;
        ss += __shfl_xor(ss, 1); ss += __shfl_xor(ss, 2);
        ss += __shfl_xor(ss, 4); ss += __shfl_xor(ss, 8);
        float inv = 1.0f / fmaxf(sqrtf(ss), 1e-12f);
        float xn0 = a0 * inv, xn1 = a1 * inv, xn2 = a2 * inv, xn3 = a3 * inv;
        float c0 = bf2f(ct[(s << 5) + l15]),      s0v = bf2f(st[(s << 5) + l15]);
        float c1 = bf2f(ct[(s << 5) + 16 + l15]), s1v = bf2f(st[(s << 5) + 16 + l15]);
        float o0 = xn0 * c0 + xn2 * s0v;
        float o1 = xn1 * c1 + xn3 * s1v;
        float o2 = xn2 * c0 - xn0 * s0v;
        float o3 = xn3 * c1 - xn1 * s1v;
        unsigned long long pk =
            (unsigned long long)((unsigned int)f2bf(o0) | ((unsigned int)f2bf(o1) << 16)) |
            ((unsigned long long)((unsigned int)f2bf(o2) | ((unsigned int)f2bf(o3) << 16)) << 32);
        size_t base = ((((size_t)((b << 4) + hh) << 10) + s) << 6) + (l15 << 2);
        bfu* dst = (which == 0) ? qb : (which == 1) ? kb : (which == 3) ? bqh : bkh;
        *reinterpret_cast<unsigned long long*>(dst + base) = pk;
      }
    }
  }
}

// ============ fused dispatch: flash (blocks 0..255, 2 sub-blocks/block) + FF-in (256..767) ============
__global__ __launch_bounds__(512, 2) void fused_k(const bfu* __restrict__ q, const bfu* __restrict__ k,
                                                  const bfu* __restrict__ vT,
                                                  const float* __restrict__ brow,
                                                  const float* __restrict__ l2p,
                                                  const bfu* __restrict__ A, const bfu* __restrict__ Bt,
                                                  bfu* __restrict__ AB,
                                                  const float* __restrict__ bias) {
  __shared__ __align__(16) char lds[131072];
  int tid = threadIdx.x, w = tid >> 6, lane = tid & 63;
  int g = lane >> 4, l15 = lane & 15;

  if (blockIdx.x < 256) {
    int fid = blockIdx.x + ((w >> 2) << 8);
    int sub = fid & 255;
    int qt = (fid >> 8) ? 7 - (sub >> 6) : (sub >> 6);
    int bh = sub & 63;
    const size_t bhofs = (size_t)bh << 16;
    int rt0 = qt * 128 + (w & 3) * 32;
    bfu* P = reinterpret_cast<bfu*>(lds) + (size_t)w * (2 * 16 * 72);

    s16x8 aq[2][2];
#pragma unroll
    for (int m = 0; m < 2; m++)
#pragma unroll
      for (int ks = 0; ks < 2; ks++)
        aq[m][ks] = *reinterpret_cast<const s16x8*>(
            q + bhofs + (size_t)(rt0 + m * 16 + l15) * 64 + ks * 32 + g * 8);

    f32x4 O[2][4];
    float mr[2][4], lr[2][4];
#pragma unroll
    for (int m = 0; m < 2; m++)
#pragma unroll
      for (int r = 0; r < 4; r++) { O[m][r] = (f32x4){0.f, 0.f, 0.f, 0.f}; mr[m][r] = -3.0e38f; lr[m][r] = 0.f; }

    s16x8 kA[4][2], kB[4][2];
    auto loadK = [&](s16x8 (&kd)[4][2], int jt) {
#pragma unroll
      for (int nt = 0; nt < 4; nt++)
#pragma unroll
        for (int ks = 0; ks < 2; ks++)
          kd[nt][ks] = *reinterpret_cast<const s16x8*>(
              k + bhofs + (size_t)(jt * 64 + nt * 16 + l15) * 64 + ks * 32 + g * 8);
    };

    int njt = 2 * qt + 2;
    loadK(kA, 0);

    auto body = [&](int jt, s16x8 (&kc)[4][2], s16x8 (&kn)[4][2], bool pf) {
      s16x8 vv[4][2];
#pragma unroll
      for (int nt = 0; nt < 4; nt++)
#pragma unroll
        for (int ks = 0; ks < 2; ks++)
          vv[nt][ks] = *reinterpret_cast<const s16x8*>(
              vT + ((size_t)(bh * 64 + nt * 16 + l15) << 10) + jt * 64 + ks * 32 + g * 8);

      bool act[2] = { jt * 64 <= rt0 + 15, jt * 64 <= rt0 + 31 };
      f32x4 sfr[2][4];
#pragma unroll
      for (int m = 0; m < 2; m++) {
        if (!act[m]) continue;
#pragma unroll
        for (int nt = 0; nt < 4; nt++) {
          sfr[m][nt] = (f32x4){0.f, 0.f, 0.f, 0.f};
#pragma unroll
          for (int ks = 0; ks < 2; ks++)
            sfr[m][nt] = __builtin_amdgcn_mfma_f32_16x16x32_bf16(aq[m][ks], kc[nt][ks], sfr[m][nt], 0, 0, 0);
        }
      }
      if (pf) loadK(kn, jt + 1);

#pragma unroll
      for (int m = 0; m < 2; m++) {
        if (!act[m]) continue;
        int rtm = rt0 + m * 16;
        if (jt * 64 + 63 > rtm) {
#pragma unroll
          for (int ntn = 0; ntn < 4; ntn++)
#pragma unroll
            for (int r = 0; r < 4; r++)
              if (jt * 64 + ntn * 16 + l15 > rtm + g * 4 + r) sfr[m][ntn][r] = -1e30f;
        }
        float alpha[4];
#pragma unroll
        for (int r = 0; r < 4; r++) {
          float v = fmaxf(fmaxf(sfr[m][0][r], sfr[m][1][r]), fmaxf(sfr[m][2][r], sfr[m][3][r]));
#pragma unroll
          for (int m2 = 1; m2 < 16; m2 <<= 1) v = fmaxf(v, __shfl_xor(v, m2));
          float mn = fmaxf(mr[m][r], v);
          alpha[r] = __expf(mr[m][r] - mn);
          mr[m][r] = mn;
        }
#pragma unroll
        for (int r = 0; r < 4; r++) {
          float rs = 0.f;
#pragma unroll
          for (int ntn = 0; ntn < 4; ntn++) {
            float e = __expf(sfr[m][ntn][r] - mr[m][r]);
            rs += e;
            P[(m * 16 + g * 4 + r) * 72 + ntn * 16 + l15] = f2bf(e);
          }
#pragma unroll
          for (int m2 = 1; m2 < 16; m2 <<= 1) rs += __shfl_xor(rs, m2);
          lr[m][r] = lr[m][r] * alpha[r] + rs;
#pragma unroll
          for (int ntn = 0; ntn < 4; ntn++) O[m][ntn][r] *= alpha[r];
        }
      }
      asm volatile("s_waitcnt lgkmcnt(0)" ::: "memory");
      __builtin_amdgcn_sched_barrier(0);
#pragma unroll
      for (int m = 0; m < 2; m++) {
        if (!act[m]) continue;
        s16x8 pa[2];
#pragma unroll
        for (int ks = 0; ks < 2; ks++)
          pa[ks] = *reinterpret_cast<const s16x8*>(&P[(m * 16 + l15) * 72 + ks * 32 + g * 8]);
#pragma unroll
        for (int nt = 0; nt < 4; nt++)
#pragma unroll
          for (int ks = 0; ks < 2; ks++)
            O[m][nt] = __builtin_amdgcn_mfma_f32_16x16x32_bf16(pa[ks], vv[nt][ks], O[m][nt], 0, 0, 0);
      }
    };

    for (int jt = 0; jt < njt; jt += 2) {
      body(jt, kA, kB, true);
      body(jt + 1, kB, kA, jt + 2 < njt);
    }

    float l2ns = l2p[0];
    int b = bh >> 4, hq = bh & 15;
#pragma unroll
    for (int m = 0; m < 2; m++)
#pragma unroll
      for (int r = 0; r < 4; r++) {
        int rowg = rt0 + m * 16 + g * 4 + r;
        float br = brow[bh * 1024 + rowg];
        float sc = l2ns / lr[m][r];
        float v0 = O[m][0][r] * sc + br;
        float v1 = O[m][1][r] * sc + br;
        float v2 = O[m][2][r] * sc + br;
        float v3 = O[m][3][r] * sc + br;
        unsigned int p01 = (unsigned int)f2bf(v0) | ((unsigned int)f2bf(v1) << 16);
        unsigned int p23 = (unsigned int)f2bf(v2) | ((unsigned int)f2bf(v3) << 16);
        size_t base = (size_t)(b * 1024 + rowg) * 5120 + 4096 + hq * 64;
        *reinterpret_cast<unsigned int*>(AB + base + 2 * l15) = p01;
        *reinterpret_cast<unsigned int*>(AB + base + 32 + 2 * l15) = p23;
      }
    return;
  }

  // ================== FF-in: 256x256, BK=64, 2-dbuf, counted vmcnt ==================
  int id0 = blockIdx.x - 256;
  int c = id0 & 7, rr = id0 >> 3;
  int bn0 = (c & 3) * 8, bm0 = (c >> 2) * 8;
  int bm = bm0 + rr / 8, bn = bn0 + rr % 8;
  int wm = w >> 2, wn = w & 3;
  const int K = 1024;
  const int NT = 16, NI = 8;

  f32x4 acc[8][4];
#pragma unroll
  for (int m = 0; m < 8; m++)
#pragma unroll
    for (int n = 0; n < 4; n++) acc[m][n] = (f32x4){0.f, 0.f, 0.f, 0.f};

  s16x8 af[4][2];
  s16x8 bfr[4][2];

  auto stage = [&](int mat, int kt, int hf) {
    if (kt >= NT) return;
    int d = kt & 1;
    const bfu* s0 = (mat == 0) ? A : Bt;
    int rowbase = ((mat == 0) ? bm : bn) * 256 + hf * 128;
    int k0 = kt << 6;
    char* base = lds + d * 65536 + mat * 32768 + hf * 16384;
#pragma unroll
    for (int r = 0; r < 2; r++) {
      int L = r * 512 + tid;
      int row = L >> 3, cc = L & 7;
      int kc = cc ^ (row & 7);
      const bfu* src = s0 + (size_t)(rowbase + row) * K + k0 + kc * 8;
      char* dst = base + r * 8192 + w * 1024;
      __builtin_amdgcn_global_load_lds((AS1q)src, (AS3q)dst, 16, 0, 0);
    }
  };

  auto ldA = [&](int d, int mh) {
    const char* base = lds + d * 65536 + wm * 16384;
#pragma unroll
    for (int mm = 0; mm < 4; mm++) {
      int row = mh * 64 + mm * 16 + l15;
#pragma unroll
      for (int ks = 0; ks < 2; ks++)
        af[mm][ks] = *reinterpret_cast<const s16x8*>(
            base + row * 128 + (((ks * 4 + g) ^ (row & 7)) << 4));
    }
  };
  auto ldB2 = [&](int d, int nh) {
    const char* base = lds + d * 65536 + 32768 + (wn >> 1) * 16384;
#pragma unroll
    for (int nn = 0; nn < 2; nn++) {
      int row = (wn & 1) * 64 + (nh * 2 + nn) * 16 + l15;
#pragma unroll
      for (int ks = 0; ks < 2; ks++)
        bfr[nh * 2 + nn][ks] = *reinterpret_cast<const s16x8*>(
            base + row * 128 + (((ks * 4 + g) ^ (row & 7)) << 4));
    }
  };
  auto mfma_q = [&](int mh, int nh) {
    asm volatile("s_waitcnt lgkmcnt(0)" ::: "memory");
    __builtin_amdgcn_sched_barrier(0);
    __builtin_amdgcn_s_barrier();
    __builtin_amdgcn_s_setprio(1);
#pragma unroll
    for (int mm = 0; mm < 4; mm++)
#pragma unroll
      for (int nn = 0; nn < 2; nn++) {
        int n = nh * 2 + nn, m = mh * 4 + mm;
#pragma unroll
        for (int ks = 0; ks < 2; ks++)
          acc[m][n] = __builtin_amdgcn_mfma_f32_16x16x32_bf16(af[mm][ks], bfr[n][ks], acc[m][n], 0, 0, 0);
      }
    __builtin_amdgcn_s_setprio(0);
    __builtin_amdgcn_sched_barrier(0);
  };

  stage(1, 0, 0); stage(0, 0, 0); stage(0, 0, 1); stage(1, 0, 1);
  stage(1, 1, 0); stage(1, 1, 1);
  asm volatile("s_waitcnt vmcnt(4)" ::: "memory");
  __builtin_amdgcn_s_barrier();
  __builtin_amdgcn_sched_barrier(0);

  for (int i = 0; i < NI; i++) {
    int t0 = 2 * i, t1 = 2 * i + 1;
    bool last = (i == NI - 1);
    ldA(0, 0); ldB2(0, 0);
    stage(0, t1, 0);
    mfma_q(0, 0);
    ldB2(0, 1);
    stage(0, t1, 1);
    mfma_q(0, 1);
    ldA(0, 1);
    stage(1, t0 + 2, 0);
    mfma_q(1, 0);
    stage(1, t0 + 2, 1);
    mfma_q(1, 1);
    if (last) { asm volatile("s_waitcnt vmcnt(0)" ::: "memory"); }
    else      { asm volatile("s_waitcnt vmcnt(4)" ::: "memory"); }
    __builtin_amdgcn_s_barrier();
    __builtin_amdgcn_sched_barrier(0);
    ldA(1, 0); ldB2(1, 0);
    stage(0, t0 + 2, 0);
    mfma_q(0, 0);
    ldB2(1, 1);
    stage(0, t0 + 2, 1);
    mfma_q(0, 1);
    ldA(1, 1);
    stage(1, t1 + 2, 0);
    mfma_q(1, 0);
    stage(1, t1 + 2, 1);
    mfma_q(1, 1);
    asm volatile("s_waitcnt vmcnt(4)" ::: "memory");
    __builtin_amdgcn_s_barrier();
    __builtin_amdgcn_sched_barrier(0);
  }

  int j0 = (bn * 8 + wn * 2) * 16 + l15;
  float bx0 = bias[j0], bg0 = bias[j0 + 4096];
  float bx1 = bias[j0 + 16], bg1 = bias[j0 + 16 + 4096];
  int cb = (bn * 4 + wn) * 32 + 2 * l15;
#pragma unroll
  for (int m = 0; m < 8; m++) {
#pragma unroll
    for (int r = 0; r < 4; r++) {
      int row = bm * 256 + wm * 128 + m * 16 + g * 4 + r;
      float xh0 = acc[m][0][r] + bx0, gt0 = acc[m][1][r] + bg0;
      float xh1 = acc[m][2][r] + bx1, gt1 = acc[m][3][r] + bg1;
      float s0 = gt0 / (1.0f + __expf(-gt0)) * xh0;
      float s1 = gt1 / (1.0f + __expf(-gt1)) * xh1;
      unsigned int pk = (unsigned int)f2bf(s0) | ((unsigned int)f2bf(s1) << 16);
      *reinterpret_cast<unsigned int*>(AB + (size_t)row * 5120 + cb) = pk;
    }
  }
}

// ============ final GEMM: 128x128 tile, BK=64, 3-stage pipeline, 4 waves (R13-proven) ============
__global__ __launch_bounds__(256, 3) void gemm128f(const bfu* __restrict__ A, const bfu* __restrict__ Bt,
                                                   float* __restrict__ out,
                                                   const float* __restrict__ b1,
                                                   const float* __restrict__ b2,
                                                   const float* __restrict__ lam,
                                                   const float* __restrict__ h,
                                                   int M, int N, int K, int rbm, int rbn) {
  __shared__ __align__(16) char lds[98304];
  int nbx = N >> 7;
  int c = blockIdx.x & 7, rr = blockIdx.x >> 3;
  int ca = nbx / rbn;
  int bn0 = (c % ca) * rbn, bm0 = (c / ca) * rbm;
  int bm = bm0 + rr / rbn, bn = bn0 + rr % rbn;
  int tid = threadIdx.x, w = tid >> 6, lane = tid & 63;
  int wm = w >> 1, wn = w & 1;
  int g = lane >> 4, l15 = lane & 15;
  int NT = K >> 6;

  f32x4 acc[4][4];
#pragma unroll
  for (int m = 0; m < 4; m++)
#pragma unroll
    for (int n = 0; n < 4; n++) acc[m][n] = (f32x4){0.f, 0.f, 0.f, 0.f};

  auto stage = [&](int buf, int t) {
    int k0 = t << 6;
#pragma unroll
    for (int r = 0; r < 4; r++) {
      int L = r * 256 + tid;
      int row = L >> 3, cc = L & 7;
      int kc = cc ^ (row & 7);
      const bfu* srcA = A + (size_t)(bm * 128 + row) * K + k0 + kc * 8;
      char* dstA = lds + buf * 32768 + r * 4096 + w * 1024;
      __builtin_amdgcn_global_load_lds((AS1q)srcA, (AS3q)dstA, 16, 0, 0);
    }
#pragma unroll
    for (int r = 0; r < 4; r++) {
      int L = r * 256 + tid;
      int row = L >> 3, cc = L & 7;
      int kc = cc ^ (row & 7);
      const bfu* srcB = Bt + (size_t)(bn * 128 + row) * K + k0 + kc * 8;
      char* dstB = lds + buf * 32768 + 16384 + r * 4096 + w * 1024;
      __builtin_amdgcn_global_load_lds((AS1q)srcB, (AS3q)dstB, 16, 0, 0);
    }
  };

  stage(0, 0); stage(1, 1);
  asm volatile("s_waitcnt vmcnt(8)" ::: "memory");
  __builtin_amdgcn_s_barrier();
  __builtin_amdgcn_sched_barrier(0);

  int bc = 0;
  for (int t = 0; t < NT; t++) {
    int bs = bc + 2; if (bs >= 3) bs -= 3;
    if (t + 2 < NT) stage(bs, t + 2);
    const char* la = lds + bc * 32768;
    const char* lb = la + 16384;
    s16x8 af[4][2], bfr[4][2];
#pragma unroll
    for (int m = 0; m < 4; m++) {
      int row = wm * 64 + m * 16 + l15;
#pragma unroll
      for (int ks = 0; ks < 2; ks++)
        af[m][ks] = *reinterpret_cast<const s16x8*>(
            la + row * 128 + (((ks * 4 + g) ^ (row & 7)) << 4));
    }
#pragma unroll
    for (int n = 0; n < 4; n++) {
      int row = wn * 64 + n * 16 + l15;
#pragma unroll
      for (int ks = 0; ks < 2; ks++)
        bfr[n][ks] = *reinterpret_cast<const s16x8*>(
            lb + row * 128 + (((ks * 4 + g) ^ (row & 7)) << 4));
    }
    asm volatile("s_waitcnt lgkmcnt(0)" ::: "memory");
    __builtin_amdgcn_sched_barrier(0);
    __builtin_amdgcn_s_setprio(1);
#pragma unroll
    for (int m = 0; m < 4; m++)
#pragma unroll
      for (int n = 0; n < 4; n++)
#pragma unroll
        for (int ks = 0; ks < 2; ks++)
          acc[m][n] = __builtin_amdgcn_mfma_f32_16x16x32_bf16(af[m][ks], bfr[n][ks], acc[m][n], 0, 0, 0);
    __builtin_amdgcn_s_setprio(0);
    __builtin_amdgcn_sched_barrier(0);
    if (t < NT - 2) { asm volatile("s_waitcnt vmcnt(8)" ::: "memory"); }
    else            { asm volatile("s_waitcnt vmcnt(0)" ::: "memory"); }
    __builtin_amdgcn_s_barrier();
    __builtin_amdgcn_sched_barrier(0);
    bc++; if (bc == 3) bc = 0;
  }

  float lv = lam[0];
#pragma unroll
  for (int m = 0; m < 4; m++) {
    int row = bm * 128 + wm * 64 + m * 16 + g * 4;
#pragma unroll
    for (int n = 0; n < 4; n++) {
      int col = bn * 128 + wn * 64 + n * 16 + l15;
      float bb = b1[col] + b2[col];
#pragma unroll
      for (int r = 0; r < 4; r++) {
        size_t o = (size_t)(row + r) * 1024 + col;
        out[o] = acc[m][n][r] + bb + lv * h[o];
      }
    }
  }
}

// ---------------- fused brow ----------------
__global__ __launch_bounds__(512) void brow_all(const bfu* __restrict__ bq, const bfu* __restrict__ bk,
                                                float* __restrict__ brow) {
  __shared__ float csums[8][64];
  int bh = blockIdx.x;
  int wave = threadIdx.x >> 6, lane = threadIdx.x & 63;
  size_t base = ((size_t)bh * 1024 + wave * 128) * 64 + lane;
  float s = 0.f;
  for (int j = 0; j < 128; j++) s += bf2f(bk[base + (size_t)j * 64]);
  csums[wave][lane] = s;
  __syncthreads();
  float p = 0.f;
  for (int cc = 0; cc < wave; cc++) p += csums[cc][lane];
  for (int j = 0; j < 128; j++) {
    p += bf2f(bk[base + (size_t)j * 64]);
    float t = bf2f(bq[base + (size_t)j * 64]) * p;
#pragma unroll
    for (int m2 = 1; m2 < 64; m2 <<= 1) t += __shfl_xor(t, m2);
    if (lane == 0) brow[bh * 1024 + wave * 128 + j] = 0.125f * t;
  }
}

// ================= host =================
extern "C" void kernel_launch(void* const* d_in, const int* in_sizes, int n_in,
                              void* d_out, int out_size, void* d_ws, size_t ws_size,
                              hipStream_t stream) {
  const float* h      = (const float*)d_in[0];
  const float* Wq     = (const float*)d_in[2];
  const float* Wk     = (const float*)d_in[3];
  const float* Wv     = (const float*)d_in[4];
  const float* WqB    = (const float*)d_in[5];
  const float* WkB    = (const float*)d_in[6];
  const float* Wo     = (const float*)d_in[7];
  const float* bo     = (const float*)d_in[8];
  const float* Wffin  = (const float*)d_in[9];
  const float* bffin  = (const float*)d_in[10];
  const float* Wffout = (const float*)d_in[11];
  const float* bffout = (const float*)d_in[12];
  const float* lam    = (const float*)d_in[13];
  const float* l2ns   = (const float*)d_in[14];
  float* out = (float*)d_out;

  char* ws = (char*)d_ws;
  size_t off = 0;
  auto alloc = [&](size_t bytes) { void* p = ws + off; off += bytes; return p; };
  bfu* wt5   = (bfu*)alloc(5ull * 1024 * 1024 * 2);
  bfu* wtfi  = (bfu*)alloc(8192ull * 1024 * 2);
  bfu* wtfoc = (bfu*)alloc(1024ull * 5120 * 2);
  bfu* cosb  = (bfu*)alloc(1024ull * 32 * 2);
  bfu* sinb  = (bfu*)alloc(1024ull * 32 * 2);
  bfu* inner = (bfu*)alloc(4096ull * 1024 * 2);
  bfu* qb    = (bfu*)alloc(64ull * 1024 * 64 * 2);
  bfu* kb    = (bfu*)alloc(64ull * 1024 * 64 * 2);
  bfu* vtb   = (bfu*)alloc(64ull * 1024 * 64 * 2);
  bfu* bqh   = (bfu*)alloc(64ull * 1024 * 64 * 2);
  bfu* bkh   = (bfu*)alloc(64ull * 1024 * 64 * 2);
  float* browb = (float*)alloc(64ull * 1024 * 4);
  bfu* AB    = (bfu*)alloc(4096ull * 5120 * 2);

  // reduced prologue: w5 converts + rope + rmsnorm (9344 blocks)
  PreArgs pa;
  pa.w5[0] = Wq; pa.w5[1] = Wk; pa.w5[2] = Wv; pa.w5[3] = WqB; pa.w5[4] = WkB;
  pa.h = h; pa.wt5 = wt5; pa.cosb = cosb; pa.sinb = sinb; pa.inner = inner;
  prologue_k<<<dim3(9344), 256, 0, stream>>>(pa);

  // fused: proj (blocks 0..1279) + FF/Wo weight converters (1280..14591)
  projconv_k<<<dim3(14592), 256, 0, stream>>>(inner, wt5, qb, kb, vtb, bqh, bkh, cosb, sinb,
                                              Wffin, Wffout, Wo, wtfi, wtfoc);

  brow_all<<<dim3(64), 512, 0, stream>>>(bqh, bkh, browb);

  // fused flash (blocks 0..255) + FF-in (blocks 256..767)
  fused_k<<<dim3(768), 512, 0, stream>>>(qb, kb, vtb, browb, l2ns,
                                         inner, wtfi, AB, bffin);

  // final merged GEMM (128^2, BK=64, 3-stage)
  gemm128f<<<dim3(256), 256, 0, stream>>>(AB, wtfoc, out, bffout, bo, lam, h,
                                          4096, 1024, 5120, 8, 4);
}